// Round 15
// baseline (1168.312 us; speedup 1.0000x reference)
//
#include <hip/hip_runtime.h>
#include <math.h>

#define E_EDGES 524288
#define N_NODES 32768
#define N_GRAPHS 64
#define NPG 512

typedef unsigned long long u64;
using bf16x8 = __attribute__((ext_vector_type(8))) short;
using f16x8  = __attribute__((ext_vector_type(8))) _Float16;
using f32x4  = __attribute__((ext_vector_type(4))) float;

__device__ __forceinline__ unsigned short f2bf(float f) {
  unsigned int u = __float_as_uint(f);
  u += 0x7FFFu + ((u >> 16) & 1u);
  return (unsigned short)(u >> 16);
}
__device__ __forceinline__ float b2f(unsigned short s) {
  return __uint_as_float(((unsigned int)s) << 16);
}
// BN coeff from raw sums: s = g/sqrt(var+eps), b = be - m*s
__device__ __forceinline__ void bn_coeff(
    const float* __restrict__ pSum, const float* __restrict__ pSq, float invcnt,
    const float* __restrict__ g, const float* __restrict__ be, int c,
    float& s, float& b)
{
  float m = pSum[c] * invcnt;
  float v = pSq[c] * invcnt - m * m;
  float is = rsqrtf(v + 1e-5f);
  s = g[c] * is;
  b = fmaf(-m, s, be[c]);
}

// ================= CSR build (dst-sorted edge permutation) =================
__global__ __launch_bounds__(256) void hist_kernel(
    const int* __restrict__ dst, int* __restrict__ cnt)
{
  int e = blockIdx.x * 256 + threadIdx.x;
  atomicAdd(&cnt[dst[e]], 1);
}

__global__ __launch_bounds__(1024) void scan_kernel(
    int* __restrict__ cnt, int* __restrict__ row_ptr)
{
  __shared__ int s[1024];
  int t = threadIdx.x;
  int base = t * 32;
  int local[32];
  int acc = 0;
#pragma unroll
  for (int i = 0; i < 32; ++i) { local[i] = acc; acc += cnt[base + i]; }
  s[t] = acc;
  __syncthreads();
  for (int d = 1; d < 1024; d <<= 1) {
    int v = (t >= d) ? s[t - d] : 0;
    __syncthreads();
    s[t] += v;
    __syncthreads();
  }
  int off = t ? s[t - 1] : 0;
#pragma unroll
  for (int i = 0; i < 32; ++i) {
    int p = off + local[i];
    row_ptr[base + i] = p;
    cnt[base + i] = p;
  }
  if (t == 1023) row_ptr[32768] = off + acc;
}

__global__ __launch_bounds__(256) void fill_kernel(
    const int* __restrict__ src, const int* __restrict__ dst,
    int* __restrict__ pos, int* __restrict__ ssrc, int* __restrict__ sdst)
{
  int e = blockIdx.x * 256 + threadIdx.x;
  int d = dst[e];
  int p = atomicAdd(&pos[d], 1);
  ssrc[p] = src[e];
  sdst[p] = d;
}

// ---------------- merged weight transpose kernels ----------------
__global__ __launch_bounds__(256) void wt16_all_kernel(
    const float* __restrict__ W2, _Float16* __restrict__ H2, _Float16* __restrict__ L2,
    const float* __restrict__ W3, _Float16* __restrict__ H3, _Float16* __restrict__ L3)
{
  int b = blockIdx.x;
  const float* W = (b < 16) ? W2 : W3;
  _Float16* H = (b < 16) ? H2 : H3;
  _Float16* L = (b < 16) ? L2 : L3;
  int idx = (b & 15) * 256 + threadIdx.x;
  int n = idx >> 6, k = idx & 63;
  float w = W[k * 64 + n];
  _Float16 hi = (_Float16)w;
  H[idx] = hi;
  L[idx] = (_Float16)(w - (float)hi);
}

__global__ __launch_bounds__(256) void wt_all_kernel(
    const float* __restrict__ g1W, unsigned short* __restrict__ g1H, unsigned short* __restrict__ g1L,
    const float* __restrict__ g2W, unsigned short* __restrict__ g2H, unsigned short* __restrict__ g2L,
    const float* __restrict__ g3W, unsigned short* __restrict__ g3H, unsigned short* __restrict__ g3L,
    const float* __restrict__ lW,  unsigned short* __restrict__ lH,  unsigned short* __restrict__ lL)
{
  int b = blockIdx.x;
  const float* W; unsigned short *H, *L; int kshift, N, base;
  if (b < 16)       { W = g1W; H = g1H; L = g1L; kshift = 6; N = 64;   base = 0; }
  else if (b < 48)  { W = g2W; H = g2H; L = g2L; kshift = 6; N = 128;  base = 16; }
  else if (b < 176) { W = g3W; H = g3H; L = g3L; kshift = 7; N = 256;  base = 48; }
  else              { W = lW;  H = lH;  L = lL;  kshift = 9; N = 1024; base = 176; }
  int idx = (b - base) * 256 + threadIdx.x;
  int n = idx >> kshift;
  int k = idx & ((1 << kshift) - 1);
  float w = W[(u64)k * N + n];
  unsigned short hi = f2bf(w);
  H[idx] = hi;
  L[idx] = f2bf(w - b2f(hi));
}

// ----- EdgeConv layer 1: 4-edge ILP per wave iteration, fp16 out + stats -------
__global__ __launch_bounds__(256) void ec1_kernel(
    const float* __restrict__ x, const int* __restrict__ src, const int* __restrict__ dst,
    const float* __restrict__ W, const float* __restrict__ b,
    _Float16* __restrict__ y, float* __restrict__ sum, float* __restrict__ sq)
{
  __shared__ float Ws[512];
  __shared__ float bs[64];
  __shared__ float red[256];
  int tid = threadIdx.x;
  for (int i = tid; i < 512; i += 256) Ws[i] = W[i];
  if (tid < 64) bs[tid] = b[tid];
  __syncthreads();
  int c = tid & 63;
  int eslot = tid >> 6;
  float ls = 0.f, lq = 0.f;
  const float4* x4 = (const float4*)x;
  int stride = gridDim.x * 16;
  for (int e = blockIdx.x * 16 + eslot * 4; e < E_EDGES; e += stride) {
    int s0 = src[e],     s1 = src[e + 1], s2 = src[e + 2], s3 = src[e + 3];
    int d0 = dst[e],     d1 = dst[e + 1], d2 = dst[e + 2], d3 = dst[e + 3];
    float4 xi0 = x4[d0], xj0 = x4[s0];
    float4 xi1 = x4[d1], xj1 = x4[s1];
    float4 xi2 = x4[d2], xj2 = x4[s2];
    float4 xi3 = x4[d3], xj3 = x4[s3];
#pragma unroll
    for (int g = 0; g < 4; ++g) {
      float4 xi = (g == 0) ? xi0 : (g == 1) ? xi1 : (g == 2) ? xi2 : xi3;
      float4 xj = (g == 0) ? xj0 : (g == 1) ? xj1 : (g == 2) ? xj2 : xj3;
      float m[8] = {xi.x, xi.y, xi.z, xi.w,
                    xj.x - xi.x, xj.y - xi.y, xj.z - xi.z, xj.w - xi.w};
      float acc = bs[c];
#pragma unroll
      for (int k = 0; k < 8; ++k) acc = fmaf(m[k], Ws[k * 64 + c], acc);
      y[(u64)(e + g) * 64 + c] = (_Float16)acc;
      ls += acc; lq += acc * acc;
    }
  }
  red[tid] = ls; __syncthreads();
  if (tid < 64) atomicAdd(&sum[tid], red[tid] + red[tid + 64] + red[tid + 128] + red[tid + 192]);
  __syncthreads();
  red[tid] = lq; __syncthreads();
  if (tid < 64) atomicAdd(&sq[tid], red[tid] + red[tid + 64] + red[tid + 128] + red[tid + 192]);
}

// -------- fp16 MFMA GEMM for EC layers: Y = relu(A*s+b) @ Wt^T + bias ----------
__global__ __launch_bounds__(256) void mfma_gemm_f16_kernel(
    const _Float16* A,
    const float* __restrict__ pSum, const float* __restrict__ pSq, float invcnt,
    const float* __restrict__ g, const float* __restrict__ be,
    const _Float16* __restrict__ WtH, const _Float16* __restrict__ WtL,
    const float* __restrict__ bias,
    _Float16* Y,
    float* __restrict__ sum, float* __restrict__ sq)
{
  __shared__ _Float16 BsH[64][72];
  __shared__ _Float16 BsL[64][72];
  __shared__ _Float16 scL[64];
  __shared__ _Float16 shL[64];
  __shared__ float redY[64];
  __shared__ float redQ[64];
  int tid = threadIdx.x;
  int lane = tid & 63, wid = tid >> 6;
  int row0 = blockIdx.x * 128 + wid * 32;
  int m16 = lane & 15, quad = lane >> 4;

#pragma unroll
  for (int it = 0; it < 2; ++it) {
    int slot = tid + it * 256;
    int n = slot >> 3, cg = slot & 7;
    *(uint4*)&BsH[n][cg * 8] = *(const uint4*)(WtH + n * 64 + cg * 8);
    *(uint4*)&BsL[n][cg * 8] = *(const uint4*)(WtL + n * 64 + cg * 8);
  }
  if (tid < 64) {
    float s, b;
    bn_coeff(pSum, pSq, invcnt, g, be, tid, s, b);
    scL[tid] = (_Float16)s;
    shL[tid] = (_Float16)b;
  }
  __syncthreads();

  f16x8 af[2][2];
#pragma unroll
  for (int rt = 0; rt < 2; ++rt) {
    int grow = row0 + rt * 16 + m16;
    const _Float16* ap = A + (u64)grow * 64 + quad * 8;
#pragma unroll
    for (int ks2 = 0; ks2 < 2; ++ks2) {
      f16x8 a = *(const f16x8*)(ap + ks2 * 32);
      f16x8 s8 = *(const f16x8*)&scL[quad * 8 + ks2 * 32];
      f16x8 h8 = *(const f16x8*)&shL[quad * 8 + ks2 * 32];
      a = a * s8 + h8;
#pragma unroll
      for (int j = 0; j < 8; ++j) a[j] = (a[j] > (_Float16)0) ? a[j] : (_Float16)0;
      af[rt][ks2] = a;
    }
  }

  f32x4 acc[2][4];
#pragma unroll
  for (int i = 0; i < 2; ++i)
#pragma unroll
    for (int j = 0; j < 4; ++j) acc[i][j] = {0.f, 0.f, 0.f, 0.f};

#pragma unroll
  for (int ks2 = 0; ks2 < 2; ++ks2) {
#pragma unroll
    for (int ct = 0; ct < 4; ++ct) {
      f16x8 bh = *(const f16x8*)&BsH[ct * 16 + m16][ks2 * 32 + quad * 8];
      f16x8 bl = *(const f16x8*)&BsL[ct * 16 + m16][ks2 * 32 + quad * 8];
#pragma unroll
      for (int rt = 0; rt < 2; ++rt) {
        acc[rt][ct] = __builtin_amdgcn_mfma_f32_16x16x32_f16(af[rt][ks2], bh, acc[rt][ct], 0, 0, 0);
        acc[rt][ct] = __builtin_amdgcn_mfma_f32_16x16x32_f16(af[rt][ks2], bl, acc[rt][ct], 0, 0, 0);
      }
    }
  }

  float cys[4], cqs[4];
#pragma unroll
  for (int ct = 0; ct < 4; ++ct) {
    int col = ct * 16 + m16;
    float bcol = bias[col];
    float cy = 0.f, cq = 0.f;
#pragma unroll
    for (int rt = 0; rt < 2; ++rt) {
#pragma unroll
      for (int rg = 0; rg < 4; ++rg) {
        int row = row0 + rt * 16 + quad * 4 + rg;
        float v = acc[rt][ct][rg] + bcol;
        Y[(u64)row * 64 + col] = (_Float16)v;
        cy += v; cq += v * v;
      }
    }
    cys[ct] = cy; cqs[ct] = cq;
  }
#pragma unroll
  for (int ct = 0; ct < 4; ++ct) {
    cys[ct] += __shfl_xor(cys[ct], 16, 64); cys[ct] += __shfl_xor(cys[ct], 32, 64);
    cqs[ct] += __shfl_xor(cqs[ct], 16, 64); cqs[ct] += __shfl_xor(cqs[ct], 32, 64);
  }
  __syncthreads();
  if (tid < 64) { redY[tid] = 0.f; redQ[tid] = 0.f; }
  __syncthreads();
  if (quad == 0) {
#pragma unroll
    for (int ct = 0; ct < 4; ++ct) {
      atomicAdd(&redY[ct * 16 + m16], cys[ct]);
      atomicAdd(&redQ[ct * 16 + m16], cqs[ct]);
    }
  }
  __syncthreads();
  if (tid < 64) {
    atomicAdd(&sum[tid], redY[tid]);
    atomicAdd(&sq[tid], redQ[tid]);
  }
}

// ---------------- split-bf16 MFMA GEMM (fp32 A; gin layers) ----------------
__global__ __launch_bounds__(256) void mfma_gemm_kernel(
    const float* A, int lda,
    const float* __restrict__ Add, int ldadd,
    const unsigned short* __restrict__ Wt_hi, const unsigned short* __restrict__ Wt_lo,
    const float* __restrict__ bias,
    float* Y, int ldy,
    float* __restrict__ sum, float* __restrict__ sq,
    int M, int K, int N)
{
  __shared__ unsigned short BsH[64][72];
  __shared__ unsigned short BsL[64][72];
  __shared__ float redY[64];
  __shared__ float redQ[64];
  int tid = threadIdx.x;
  int lane = tid & 63, wid = tid >> 6;
  int row0 = blockIdx.y * 128 + wid * 32;
  int col0 = blockIdx.x * 64;
  int m16 = lane & 15, quad = lane >> 4;

  f32x4 acc[2][4];
#pragma unroll
  for (int i = 0; i < 2; ++i)
#pragma unroll
    for (int j = 0; j < 4; ++j) acc[i][j] = {0.f, 0.f, 0.f, 0.f};

  for (int k0 = 0; k0 < K; k0 += 64) {
    if (k0) __syncthreads();
#pragma unroll
    for (int it = 0; it < 2; ++it) {
      int slot = tid + it * 256;
      int n = slot >> 3, cg = slot & 7;
      u64 off = (u64)(col0 + n) * K + k0 + cg * 8;
      *(uint4*)&BsH[n][cg * 8] = *(const uint4*)(Wt_hi + off);
      *(uint4*)&BsL[n][cg * 8] = *(const uint4*)(Wt_lo + off);
    }
    __syncthreads();

    bf16x8 ah[2][2], al[2][2];
#pragma unroll
    for (int rt = 0; rt < 2; ++rt) {
      int grow = row0 + rt * 16 + m16;
      const float* ap = A + (u64)grow * lda + k0 + quad * 8;
      const float* addp = Add ? (Add + (u64)grow * ldadd + k0 + quad * 8) : nullptr;
#pragma unroll
      for (int ks2 = 0; ks2 < 2; ++ks2) {
        float4 v0 = *(const float4*)(ap + ks2 * 32);
        float4 v1 = *(const float4*)(ap + ks2 * 32 + 4);
        if (Add) {
          float4 a0 = *(const float4*)(addp + ks2 * 32);
          float4 a1 = *(const float4*)(addp + ks2 * 32 + 4);
          v0.x += a0.x; v0.y += a0.y; v0.z += a0.z; v0.w += a0.w;
          v1.x += a1.x; v1.y += a1.y; v1.z += a1.z; v1.w += a1.w;
        }
        float f[8] = {v0.x, v0.y, v0.z, v0.w, v1.x, v1.y, v1.z, v1.w};
        bf16x8 th, tl;
#pragma unroll
        for (int j = 0; j < 8; ++j) {
          unsigned short hi = f2bf(f[j]);
          th[j] = (short)hi;
          tl[j] = (short)f2bf(f[j] - b2f(hi));
        }
        ah[rt][ks2] = th;
        al[rt][ks2] = tl;
      }
    }

#pragma unroll
    for (int ks2 = 0; ks2 < 2; ++ks2) {
#pragma unroll
      for (int ct = 0; ct < 4; ++ct) {
        bf16x8 bh = *(const bf16x8*)&BsH[ct * 16 + m16][ks2 * 32 + quad * 8];
        bf16x8 bl = *(const bf16x8*)&BsL[ct * 16 + m16][ks2 * 32 + quad * 8];
#pragma unroll
        for (int rt = 0; rt < 2; ++rt) {
          acc[rt][ct] = __builtin_amdgcn_mfma_f32_16x16x32_bf16(ah[rt][ks2], bh, acc[rt][ct], 0, 0, 0);
          acc[rt][ct] = __builtin_amdgcn_mfma_f32_16x16x32_bf16(ah[rt][ks2], bl, acc[rt][ct], 0, 0, 0);
          acc[rt][ct] = __builtin_amdgcn_mfma_f32_16x16x32_bf16(al[rt][ks2], bh, acc[rt][ct], 0, 0, 0);
        }
      }
    }
  }

  float cys[4], cqs[4];
#pragma unroll
  for (int ct = 0; ct < 4; ++ct) {
    int col = col0 + ct * 16 + m16;
    float bcol = bias[col];
    float cy = 0.f, cq = 0.f;
#pragma unroll
    for (int rt = 0; rt < 2; ++rt) {
#pragma unroll
      for (int rg = 0; rg < 4; ++rg) {
        int row = row0 + rt * 16 + quad * 4 + rg;
        float v = acc[rt][ct][rg] + bcol;
        Y[(u64)row * ldy + col] = v;
        cy += v; cq += v * v;
      }
    }
    cys[ct] = cy; cqs[ct] = cq;
  }
#pragma unroll
  for (int ct = 0; ct < 4; ++ct) {
    cys[ct] += __shfl_xor(cys[ct], 16, 64); cys[ct] += __shfl_xor(cys[ct], 32, 64);
    cqs[ct] += __shfl_xor(cqs[ct], 16, 64); cqs[ct] += __shfl_xor(cqs[ct], 32, 64);
  }
  __syncthreads();
  if (tid < 64) { redY[tid] = 0.f; redQ[tid] = 0.f; }
  __syncthreads();
  if (quad == 0) {
#pragma unroll
    for (int ct = 0; ct < 4; ++ct) {
      atomicAdd(&redY[ct * 16 + m16], cys[ct]);
      atomicAdd(&redQ[ct * 16 + m16], cqs[ct]);
    }
  }
  __syncthreads();
  if (tid < 64) {
    atomicAdd(&sum[col0 + tid], redY[tid]);
    atomicAdd(&sq[col0 + tid], redQ[tid]);
  }
}

// ------- lin GEMM: single bf16 A plane, W hi/lo, 256-col blocks, fp16 out ------
__global__ __launch_bounds__(256) void mfma_gemm_ps_kernel(
    const unsigned short* __restrict__ Ahi,
    const unsigned short* __restrict__ Wt_hi, const unsigned short* __restrict__ Wt_lo,
    const float* __restrict__ bias,
    _Float16* __restrict__ Y,
    float* __restrict__ sum, float* __restrict__ sq,
    int K, int N)
{
  __shared__ unsigned short BsH[256][72];
  __shared__ unsigned short BsL[256][72];
  __shared__ float redY[256];
  __shared__ float redQ[256];
  int tid = threadIdx.x;
  int lane = tid & 63, wid = tid >> 6;
  int row0 = blockIdx.y * 128 + wid * 32;
  int col0 = blockIdx.x * 256;
  int m16 = lane & 15, quad = lane >> 4;

  f32x4 acc[2][16];
#pragma unroll
  for (int i = 0; i < 2; ++i)
#pragma unroll
    for (int j = 0; j < 16; ++j) acc[i][j] = {0.f, 0.f, 0.f, 0.f};

  for (int k0 = 0; k0 < K; k0 += 64) {
    if (k0) __syncthreads();
#pragma unroll
    for (int it = 0; it < 8; ++it) {
      int slot = tid + it * 256;
      int n = slot >> 3, cg = slot & 7;
      u64 off = (u64)(col0 + n) * K + k0 + cg * 8;
      *(uint4*)&BsH[n][cg * 8] = *(const uint4*)(Wt_hi + off);
      *(uint4*)&BsL[n][cg * 8] = *(const uint4*)(Wt_lo + off);
    }
    __syncthreads();

    bf16x8 ah[2][2];
#pragma unroll
    for (int rt = 0; rt < 2; ++rt) {
      int grow = row0 + rt * 16 + m16;
      u64 abase = (u64)grow * K + k0 + quad * 8;
#pragma unroll
      for (int ks2 = 0; ks2 < 2; ++ks2)
        ah[rt][ks2] = *(const bf16x8*)(Ahi + abase + ks2 * 32);
    }

#pragma unroll
    for (int ks2 = 0; ks2 < 2; ++ks2) {
#pragma unroll
      for (int ct = 0; ct < 16; ++ct) {
        bf16x8 bh = *(const bf16x8*)&BsH[ct * 16 + m16][ks2 * 32 + quad * 8];
        bf16x8 bl = *(const bf16x8*)&BsL[ct * 16 + m16][ks2 * 32 + quad * 8];
#pragma unroll
        for (int rt = 0; rt < 2; ++rt) {
          acc[rt][ct] = __builtin_amdgcn_mfma_f32_16x16x32_bf16(ah[rt][ks2], bh, acc[rt][ct], 0, 0, 0);
          acc[rt][ct] = __builtin_amdgcn_mfma_f32_16x16x32_bf16(ah[rt][ks2], bl, acc[rt][ct], 0, 0, 0);
        }
      }
    }
  }

  float cys[16], cqs[16];
#pragma unroll
  for (int ct = 0; ct < 16; ++ct) {
    int col = col0 + ct * 16 + m16;
    float bcol = bias[col];
    float cy = 0.f, cq = 0.f;
#pragma unroll
    for (int rt = 0; rt < 2; ++rt) {
#pragma unroll
      for (int rg = 0; rg < 4; ++rg) {
        int row = row0 + rt * 16 + quad * 4 + rg;
        float v = acc[rt][ct][rg] + bcol;
        Y[(u64)row * N + col] = (_Float16)v;
        cy += v; cq += v * v;
      }
    }
    cys[ct] = cy; cqs[ct] = cq;
  }
#pragma unroll
  for (int ct = 0; ct < 16; ++ct) {
    cys[ct] += __shfl_xor(cys[ct], 16, 64); cys[ct] += __shfl_xor(cys[ct], 32, 64);
    cqs[ct] += __shfl_xor(cqs[ct], 16, 64); cqs[ct] += __shfl_xor(cqs[ct], 32, 64);
  }
  __syncthreads();
  redY[tid] = 0.f; redQ[tid] = 0.f;
  __syncthreads();
  if (quad == 0) {
#pragma unroll
    for (int ct = 0; ct < 16; ++ct) {
      atomicAdd(&redY[ct * 16 + m16], cys[ct]);
      atomicAdd(&redQ[ct * 16 + m16], cqs[ct]);
    }
  }
  __syncthreads();
  atomicAdd(&sum[col0 + tid], redY[tid]);
  atomicAdd(&sq[col0 + tid], redQ[tid]);
}

// ---------------- head GEMM: M=64 rows, row per block; optional pre-BN ----------
__global__ __launch_bounds__(256) void head_gemm_kernel(
    const float* __restrict__ A, int K,
    const float* __restrict__ pSum, const float* __restrict__ pSq, float invcnt,
    const float* __restrict__ g, const float* __restrict__ be,
    const float* __restrict__ W, const float* __restrict__ bias,
    float* __restrict__ Y, int Cout,
    float* __restrict__ sum, float* __restrict__ sq)
{
  __shared__ float As[2048];
  int r = blockIdx.y;
  int tid = threadIdx.x;
  for (int k = tid; k < K; k += 256) {
    float v = A[(u64)r * K + k];
    if (pSum) {
      float s, b;
      bn_coeff(pSum, pSq, invcnt, g, be, k, s, b);
      v = fmaxf(fmaf(v, s, b), 0.f);
    }
    As[k] = v;
  }
  __syncthreads();
  int c = blockIdx.x * 256 + tid;
  if (c >= Cout) return;
  float a0 = 0.f, a1 = 0.f, a2 = 0.f, a3 = 0.f;
  for (int k = 0; k < K; k += 4) {
    a0 = fmaf(As[k + 0], W[(u64)(k + 0) * Cout + c], a0);
    a1 = fmaf(As[k + 1], W[(u64)(k + 1) * Cout + c], a1);
    a2 = fmaf(As[k + 2], W[(u64)(k + 2) * Cout + c], a2);
    a3 = fmaf(As[k + 3], W[(u64)(k + 3) * Cout + c], a3);
  }
  float acc = bias[c] + ((a0 + a1) + (a2 + a3));
  Y[(u64)r * Cout + c] = acc;
  if (sum) { atomicAdd(&sum[c], acc); atomicAdd(&sq[c], acc * acc); }
}

// -------- stats-only pass: t = relu(z*s1+b1), accumulate sum/sq of t -----------
__global__ __launch_bounds__(256) void act_stats_kernel(
    const float* __restrict__ z,
    const float* __restrict__ pSum, const float* __restrict__ pSq, float invcnt,
    const float* __restrict__ g, const float* __restrict__ be,
    float* __restrict__ sum, float* __restrict__ sq, int total, int cmask)
{
  __shared__ float red[256];
  int tid = threadIdx.x;
  int c = tid & cmask;
  float s, b;
  bn_coeff(pSum, pSq, invcnt, g, be, c, s, b);
  float ls = 0.f, lq = 0.f;
  for (int idx = blockIdx.x * 256 + tid; idx < total; idx += gridDim.x * 256) {
    float v = fmaxf(fmaf(z[idx], s, b), 0.f);
    ls += v; lq += v * v;
  }
  red[tid] = ls; __syncthreads();
  if (tid <= cmask) {
    float t = 0.f;
    for (int k = tid; k < 256; k += cmask + 1) t += red[k];
    atomicAdd(&sum[tid], t);
  }
  __syncthreads();
  red[tid] = lq; __syncthreads();
  if (tid <= cmask) {
    float t = 0.f;
    for (int k = tid; k < 256; k += cmask + 1) t += red[k];
    atomicAdd(&sq[tid], t);
  }
}

// ------ recompute t from z, apply outer affine, write h + bf16 hi plane --------
__global__ __launch_bounds__(256) void apply_bn_kernel(
    const float* __restrict__ z,
    const float* __restrict__ iSum, const float* __restrict__ iSq, float invcnt,
    const float* __restrict__ ig, const float* __restrict__ ibe,
    const float* __restrict__ oSum, const float* __restrict__ oSq,
    const float* __restrict__ og, const float* __restrict__ obe,
    float* __restrict__ h, unsigned short* __restrict__ hspH,
    int off, int cshift, int cmask, int total)
{
  int tid = threadIdx.x;
  int c = tid & cmask;
  float s1, b1, s2, b2;
  bn_coeff(iSum, iSq, invcnt, ig, ibe, c, s1, b1);
  bn_coeff(oSum, oSq, invcnt, og, obe, c, s2, b2);
  for (int idx = blockIdx.x * 256 + tid; idx < total; idx += gridDim.x * 256) {
    int r = idx >> cshift;
    float t = fmaxf(fmaf(z[idx], s1, b1), 0.f);
    float v = fmaf(t, s2, b2);
    u64 o = (u64)r * 512 + off + (idx & cmask);
    h[o] = v;
    hspH[o] = f2bf(v);
  }
}

// ------------- EdgeConv segment_max via CSR + bf16 hi plane ----------------
__global__ __launch_bounds__(256) void x0max_csr_kernel(
    const _Float16* __restrict__ y3,
    const float* __restrict__ pSum, const float* __restrict__ pSq, float invcnt,
    const float* __restrict__ g, const float* __restrict__ be,
    const int* __restrict__ row_ptr, float* __restrict__ h,
    unsigned short* __restrict__ hspH)
{
  int n = blockIdx.x * 4 + (threadIdx.x >> 6);
  int lane = threadIdx.x & 63;
  int b = row_ptr[n], e = row_ptr[n + 1];
  float s, bb;
  bn_coeff(pSum, pSq, invcnt, g, be, lane, s, bb);
  float mx = 0.f;
  for (int i = b; i < e; ++i) {
    float v = fmaxf(fmaf((float)y3[(u64)i * 64 + lane], s, bb), 0.f);
    mx = fmaxf(mx, v);
  }
  u64 o = (u64)n * 512 + lane;
  h[o] = mx;
  hspH[o] = f2bf(mx);
}

// ------------- GIN neighbor-sum via CSR gather (wave per node, coalesced) ------
template<int COLS>
__global__ __launch_bounds__(256) void gather_add_kernel(
    const float* __restrict__ h, int off,
    const int* __restrict__ row_ptr, const int* __restrict__ ssrc,
    float* __restrict__ agg)
{
  int n = blockIdx.x * 4 + (threadIdx.x >> 6);
  int lane = threadIdx.x & 63;
  int b = row_ptr[n], e = row_ptr[n + 1];
  float a0 = 0.f, a1 = 0.f;
  for (int i = b; i < e; ++i) {
    const float* p = h + (u64)ssrc[i] * 512 + off + lane;
    a0 += p[0];
    if (COLS > 64) a1 += p[64];
  }
  float* q = agg + (u64)n * COLS + lane;
  q[0] = a0;
  if (COLS > 64) q[64] = a1;
}

// ---------------- graph pooling (hl fp16) ----------------
__global__ __launch_bounds__(256) void pool_kernel(
    const _Float16* __restrict__ hl,
    const float* __restrict__ pSum, const float* __restrict__ pSq, float invcnt,
    const float* __restrict__ g, const float* __restrict__ be,
    float* __restrict__ o)
{
  int gidx = blockIdx.x;
  int c = blockIdx.y * 256 + threadIdx.x;
  float s, b;
  bn_coeff(pSum, pSq, invcnt, g, be, c, s, b);
  const _Float16* p = hl + (u64)gidx * NPG * 1024 + c;
  float mx = 0.f, sm = 0.f;
  for (int n = 0; n < NPG; ++n) {
    float v = fmaxf(fmaf((float)p[(u64)n * 1024], s, b), 0.f);
    mx = fmaxf(mx, v);
    sm += v;
  }
  o[gidx * 2048 + c] = mx;
  o[gidx * 2048 + 1024 + c] = sm * (1.f / NPG);
}

// ---------------- log_softmax over 40 cols ----------------
__global__ void lsm_kernel(const float* __restrict__ logits, float* __restrict__ out)
{
  int r = blockIdx.x;
  int c = threadIdx.x;
  float v = (c < 40) ? logits[r * 40 + c] : -INFINITY;
  float m = v;
  for (int off = 32; off; off >>= 1) m = fmaxf(m, __shfl_xor(m, off, 64));
  float e = (c < 40) ? expf(v - m) : 0.f;
  float s = e;
  for (int off = 32; off; off >>= 1) s += __shfl_xor(s, off, 64);
  if (c < 40) out[r * 40 + c] = (v - m) - logf(s);
}

extern "C" void kernel_launch(void* const* d_in, const int* in_sizes, int n_in,
                              void* d_out, int out_size, void* d_ws, size_t ws_size,
                              hipStream_t stream)
{
  const float* x    = (const float*)d_in[0];
  const int*   ei   = (const int*)d_in[1];
  const int*   srcI = ei;
  const int*   dstI = ei + E_EDGES;
  const float* ecW1 = (const float*)d_in[3];
  const float* ecb1 = (const float*)d_in[4];
  const float* ecg1 = (const float*)d_in[5];
  const float* ecbe1= (const float*)d_in[6];
  const float* ecW2 = (const float*)d_in[7];
  const float* ecb2 = (const float*)d_in[8];
  const float* ecg2 = (const float*)d_in[9];
  const float* ecbe2= (const float*)d_in[10];
  const float* ecW3 = (const float*)d_in[11];
  const float* ecb3 = (const float*)d_in[12];
  const float* ecg3 = (const float*)d_in[13];
  const float* ecbe3= (const float*)d_in[14];
  const float* g1W  = (const float*)d_in[15];
  const float* g1b  = (const float*)d_in[16];
  const float* g1g  = (const float*)d_in[17];
  const float* g1be = (const float*)d_in[18];
  const float* g2W  = (const float*)d_in[19];
  const float* g2b  = (const float*)d_in[20];
  const float* g2g  = (const float*)d_in[21];
  const float* g2be = (const float*)d_in[22];
  const float* g3W  = (const float*)d_in[23];
  const float* g3b  = (const float*)d_in[24];
  const float* g3g  = (const float*)d_in[25];
  const float* g3be = (const float*)d_in[26];
  const float* bn1g = (const float*)d_in[27];
  const float* bn1be= (const float*)d_in[28];
  const float* bn2g = (const float*)d_in[29];
  const float* bn2be= (const float*)d_in[30];
  const float* bn3g = (const float*)d_in[31];
  const float* bn3be= (const float*)d_in[32];
  const float* linW = (const float*)d_in[33];
  const float* linb = (const float*)d_in[34];
  const float* ling = (const float*)d_in[35];
  const float* linbe= (const float*)d_in[36];
  const float* h1W  = (const float*)d_in[37];
  const float* h1b  = (const float*)d_in[38];
  const float* h1g  = (const float*)d_in[39];
  const float* h1be = (const float*)d_in[40];
  const float* h2W  = (const float*)d_in[41];
  const float* h2b  = (const float*)d_in[42];
  const float* h2g  = (const float*)d_in[43];
  const float* h2be = (const float*)d_in[44];
  const float* outW = (const float*)d_in[45];
  const float* outb = (const float*)d_in[46];

  char* ws = (char*)d_ws;
  const size_t MB = 1024ull * 1024ull;
  // ---- stats area [0, 96 KiB): 12 slots of (sum 4K + sq 4K) ----
#define S(i) ((float*)(ws + (size_t)(i) * 8192))
#define Q(i) ((float*)(ws + (size_t)(i) * 8192 + 4096))
  // ---- small buffers [128 KiB, 1 MiB) ----
  float* o_     = (float*)(ws + 131072);
  float* yh1    = (float*)(ws + 131072 + 524288);
  float* yh2    = (float*)(ws + 131072 + 524288 + 131072);
  float* logits = (float*)(ws + 131072 + 524288 + 131072 + 65536);
  // ---- weights [1 MiB, 4 MiB) ----
  _Float16* ec2WtH16 = (_Float16*)(ws + 1 * MB);
  _Float16* ec2WtL16 = (_Float16*)(ws + 1 * MB + 8192);
  _Float16* ec3WtH16 = (_Float16*)(ws + 1 * MB + 16384);
  _Float16* ec3WtL16 = (_Float16*)(ws + 1 * MB + 24576);
  unsigned short* g1WtH  = (unsigned short*)(ws + 1 * MB + 32768);
  unsigned short* g1WtL  = (unsigned short*)(ws + 1 * MB + 40960);
  unsigned short* g2WtH  = (unsigned short*)(ws + 1 * MB + 49152);
  unsigned short* g2WtL  = (unsigned short*)(ws + 1 * MB + 65536);
  unsigned short* g3WtH  = (unsigned short*)(ws + 1 * MB + 81920);
  unsigned short* g3WtL  = (unsigned short*)(ws + 1 * MB + 147456);
  unsigned short* linWtH = (unsigned short*)(ws + 1 * MB + 212992);
  unsigned short* linWtL = (unsigned short*)(ws + 1 * MB + 212992 + 1048576);
  // ---- big region [4 MiB, 132 MiB) ----
  _Float16* y  = (_Float16*)(ws + 4 * MB);     // [E,64] fp16 (dead after x0max)
  float* ytemp = (float*)(ws + 4 * MB);        // GIN z, <=32 MiB
  float* agg   = (float*)(ws + 36 * MB);       // GIN agg, <=32 MiB
  unsigned short* hspH = (unsigned short*)(ws + 68 * MB);   // [N,512] bf16 hi
  _Float16* hl = (_Float16*)(ws + 4 * MB);     // [N,1024] fp16 during lin/pool
  // ---- h region [132 MiB, 196 MiB): [N,512] fp32 ----
  float* h = (float*)(ws + 132 * MB);
  // ---- CSR region [196 MiB, 201 MiB) ----
  int* row_ptr = (int*)(ws + 196 * MB);
  int* cnt     = (int*)(ws + 196 * MB + 140000);
  int* ssrc    = (int*)(ws + 197 * MB);
  int* sdst    = (int*)(ws + 199 * MB);

  const float invE = 1.f / E_EDGES;
  const float invN = 1.f / N_NODES;
  const float invB = 1.f / N_GRAPHS;

  hipMemsetAsync((void*)ws, 0, 12 * 8192, stream);
  hipMemsetAsync((void*)cnt, 0, 32768 * 4, stream);

  // ---------------- CSR build ----------------
  hist_kernel<<<2048, 256, 0, stream>>>(dstI, cnt);
  scan_kernel<<<1, 1024, 0, stream>>>(cnt, row_ptr);
  fill_kernel<<<2048, 256, 0, stream>>>(srcI, dstI, cnt, ssrc, sdst);

  // ---------------- weight prep ----------------
  wt16_all_kernel<<<32, 256, 0, stream>>>(ecW2, ec2WtH16, ec2WtL16, ecW3, ec3WtH16, ec3WtL16);
  wt_all_kernel<<<2224, 256, 0, stream>>>(g1W, g1WtH, g1WtL, g2W, g2WtH, g2WtL,
                                          g3W, g3WtH, g3WtL, linW, linWtH, linWtL);

  // ---------------- EdgeConv (fp16 y, in-place) ----------------
  ec1_kernel<<<1024, 256, 0, stream>>>(x, ssrc, sdst, ecW1, ecb1, y, S(0), Q(0));
  mfma_gemm_f16_kernel<<<E_EDGES / 128, 256, 0, stream>>>(
      y, S(0), Q(0), invE, ecg1, ecbe1, ec2WtH16, ec2WtL16, ecb2, y, S(1), Q(1));
  mfma_gemm_f16_kernel<<<E_EDGES / 128, 256, 0, stream>>>(
      y, S(1), Q(1), invE, ecg2, ecbe2, ec3WtH16, ec3WtL16, ecb3, y, S(2), Q(2));
  x0max_csr_kernel<<<N_NODES / 4, 256, 0, stream>>>(
      y, S(2), Q(2), invE, ecg3, ecbe3, row_ptr, h, hspH);

  // ---------------- GIN 1 ----------------
  gather_add_kernel<64><<<N_NODES / 4, 256, 0, stream>>>(h, 0, row_ptr, ssrc, agg);
  mfma_gemm_kernel<<<dim3(1, N_NODES / 128), 256, 0, stream>>>(
      h, 512, agg, 64, g1WtH, g1WtL, g1b, ytemp, 64, S(3), Q(3), N_NODES, 64, 64);
  act_stats_kernel<<<512, 256, 0, stream>>>(
      ytemp, S(3), Q(3), invN, g1g, g1be, S(4), Q(4), N_NODES * 64, 63);
  apply_bn_kernel<<<1024, 256, 0, stream>>>(
      ytemp, S(3), Q(3), invN, g1g, g1be, S(4), Q(4), bn1g, bn1be,
      h, hspH, 64, 6, 63, N_NODES * 64);

  // ---------------- GIN 2 ----------------
  gather_add_kernel<64><<<N_NODES / 4, 256, 0, stream>>>(h, 64, row_ptr, ssrc, agg);
  mfma_gemm_kernel<<<dim3(2, N_NODES / 128), 256, 0, stream>>>(
      h + 64, 512, agg, 64, g2WtH, g2WtL, g2b, ytemp, 128, S(5), Q(5), N_NODES, 64, 128);
  act_stats_kernel<<<512, 256, 0, stream>>>(
      ytemp, S(5), Q(5), invN, g2g, g2be, S(6), Q(6), N_NODES * 128, 127);
  apply_bn_kernel<<<1024, 256, 0, stream>>>(
      ytemp, S(5), Q(5), invN, g2g, g2be, S(6), Q(6), bn2g, bn2be,
      h, hspH, 128, 7, 127, N_NODES * 128);

  // ---------------- GIN 3 ----------------
  gather_add_kernel<128><<<N_NODES / 4, 256, 0, stream>>>(h, 128, row_ptr, ssrc, agg);
  mfma_gemm_kernel<<<dim3(4, N_NODES / 128), 256, 0, stream>>>(
      h + 128, 512, agg, 128, g3WtH, g3WtL, g3b, ytemp, 256, S(7), Q(7), N_NODES, 128, 256);
  act_stats_kernel<<<512, 256, 0, stream>>>(
      ytemp, S(7), Q(7), invN, g3g, g3be, S(8), Q(8), N_NODES * 256, 255);
  apply_bn_kernel<<<1024, 256, 0, stream>>>(
      ytemp, S(7), Q(7), invN, g3g, g3be, S(8), Q(8), bn3g, bn3be,
      h, hspH, 256, 8, 255, N_NODES * 256);

  // ---------------- lin (256-col blocks) + pool ----------------
  mfma_gemm_ps_kernel<<<dim3(4, N_NODES / 128), 256, 0, stream>>>(
      hspH, linWtH, linWtL, linb, hl, S(9), Q(9), 512, 1024);
  pool_kernel<<<dim3(64, 4), 256, 0, stream>>>(hl, S(9), Q(9), invN, ling, linbe, o_);

  // ---------------- head ----------------
  head_gemm_kernel<<<dim3(2, 64), 256, 0, stream>>>(
      o_, 2048, nullptr, nullptr, 0.f, nullptr, nullptr, h1W, h1b, yh1, 512, S(10), Q(10));
  head_gemm_kernel<<<dim3(1, 64), 256, 0, stream>>>(
      yh1, 512, S(10), Q(10), invB, h1g, h1be, h2W, h2b, yh2, 256, S(11), Q(11));
  head_gemm_kernel<<<dim3(1, 64), 256, 0, stream>>>(
      yh2, 256, S(11), Q(11), invB, h2g, h2be, outW, outb, logits, 40, nullptr, nullptr);
  lsm_kernel<<<64, 64, 0, stream>>>(logits, (float*)d_out);
#undef S
#undef Q
}

// Round 16
// 1138.769 us; speedup vs baseline: 1.0259x; 1.0259x over previous
//
#include <hip/hip_runtime.h>
#include <math.h>

#define E_EDGES 524288
#define N_NODES 32768
#define N_GRAPHS 64
#define NPG 512

typedef unsigned long long u64;
using bf16x8 = __attribute__((ext_vector_type(8))) short;
using f16x8  = __attribute__((ext_vector_type(8))) _Float16;
using f32x4  = __attribute__((ext_vector_type(4))) float;

__device__ __forceinline__ unsigned short f2bf(float f) {
  unsigned int u = __float_as_uint(f);
  u += 0x7FFFu + ((u >> 16) & 1u);
  return (unsigned short)(u >> 16);
}
__device__ __forceinline__ float b2f(unsigned short s) {
  return __uint_as_float(((unsigned int)s) << 16);
}
// BN coeff from raw sums: s = g/sqrt(var+eps), b = be - m*s
__device__ __forceinline__ void bn_coeff(
    const float* __restrict__ pSum, const float* __restrict__ pSq, float invcnt,
    const float* __restrict__ g, const float* __restrict__ be, int c,
    float& s, float& b)
{
  float m = pSum[c] * invcnt;
  float v = pSq[c] * invcnt - m * m;
  float is = rsqrtf(v + 1e-5f);
  s = g[c] * is;
  b = fmaf(-m, s, be[c]);
}

// ================= CSR build (dst-sorted edge permutation) =================
__global__ __launch_bounds__(256) void hist_kernel(
    const int* __restrict__ dst, int* __restrict__ cnt)
{
  int e = blockIdx.x * 256 + threadIdx.x;
  atomicAdd(&cnt[dst[e]], 1);
}

__global__ __launch_bounds__(1024) void scan_kernel(
    int* __restrict__ cnt, int* __restrict__ row_ptr)
{
  __shared__ int s[1024];
  int t = threadIdx.x;
  int base = t * 32;
  int local[32];
  int acc = 0;
#pragma unroll
  for (int i = 0; i < 32; ++i) { local[i] = acc; acc += cnt[base + i]; }
  s[t] = acc;
  __syncthreads();
  for (int d = 1; d < 1024; d <<= 1) {
    int v = (t >= d) ? s[t - d] : 0;
    __syncthreads();
    s[t] += v;
    __syncthreads();
  }
  int off = t ? s[t - 1] : 0;
#pragma unroll
  for (int i = 0; i < 32; ++i) {
    int p = off + local[i];
    row_ptr[base + i] = p;
    cnt[base + i] = p;
  }
  if (t == 1023) row_ptr[32768] = off + acc;
}

__global__ __launch_bounds__(256) void fill_kernel(
    const int* __restrict__ src, const int* __restrict__ dst,
    int* __restrict__ pos, int* __restrict__ ssrc, int* __restrict__ sdst)
{
  int e = blockIdx.x * 256 + threadIdx.x;
  int d = dst[e];
  int p = atomicAdd(&pos[d], 1);
  ssrc[p] = src[e];
  sdst[p] = d;
}

// ---------------- merged weight transpose kernels ----------------
__global__ __launch_bounds__(256) void wt16_all_kernel(
    const float* __restrict__ W2, _Float16* __restrict__ H2, _Float16* __restrict__ L2,
    const float* __restrict__ W3, _Float16* __restrict__ H3, _Float16* __restrict__ L3)
{
  int b = blockIdx.x;
  const float* W = (b < 16) ? W2 : W3;
  _Float16* H = (b < 16) ? H2 : H3;
  _Float16* L = (b < 16) ? L2 : L3;
  int idx = (b & 15) * 256 + threadIdx.x;
  int n = idx >> 6, k = idx & 63;
  float w = W[k * 64 + n];
  _Float16 hi = (_Float16)w;
  H[idx] = hi;
  L[idx] = (_Float16)(w - (float)hi);
}

__global__ __launch_bounds__(256) void wt_all_kernel(
    const float* __restrict__ g1W, unsigned short* __restrict__ g1H, unsigned short* __restrict__ g1L,
    const float* __restrict__ g2W, unsigned short* __restrict__ g2H, unsigned short* __restrict__ g2L,
    const float* __restrict__ g3W, unsigned short* __restrict__ g3H, unsigned short* __restrict__ g3L,
    const float* __restrict__ lW,  unsigned short* __restrict__ lH,  unsigned short* __restrict__ lL)
{
  int b = blockIdx.x;
  const float* W; unsigned short *H, *L; int kshift, N, base;
  if (b < 16)       { W = g1W; H = g1H; L = g1L; kshift = 6; N = 64;   base = 0; }
  else if (b < 48)  { W = g2W; H = g2H; L = g2L; kshift = 6; N = 128;  base = 16; }
  else if (b < 176) { W = g3W; H = g3H; L = g3L; kshift = 7; N = 256;  base = 48; }
  else              { W = lW;  H = lH;  L = lL;  kshift = 9; N = 1024; base = 176; }
  int idx = (b - base) * 256 + threadIdx.x;
  int n = idx >> kshift;
  int k = idx & ((1 << kshift) - 1);
  float w = W[(u64)k * N + n];
  unsigned short hi = f2bf(w);
  H[idx] = hi;
  L[idx] = f2bf(w - b2f(hi));
}

// ----- EdgeConv layer 1: 4-edge ILP per wave iteration, fp16 out + stats -------
__global__ __launch_bounds__(256) void ec1_kernel(
    const float* __restrict__ x, const int* __restrict__ src, const int* __restrict__ dst,
    const float* __restrict__ W, const float* __restrict__ b,
    _Float16* __restrict__ y, float* __restrict__ sum, float* __restrict__ sq)
{
  __shared__ float Ws[512];
  __shared__ float bs[64];
  __shared__ float red[256];
  int tid = threadIdx.x;
  for (int i = tid; i < 512; i += 256) Ws[i] = W[i];
  if (tid < 64) bs[tid] = b[tid];
  __syncthreads();
  int c = tid & 63;
  int eslot = tid >> 6;
  float ls = 0.f, lq = 0.f;
  const float4* x4 = (const float4*)x;
  int stride = gridDim.x * 16;
  for (int e = blockIdx.x * 16 + eslot * 4; e < E_EDGES; e += stride) {
    int s0 = src[e],     s1 = src[e + 1], s2 = src[e + 2], s3 = src[e + 3];
    int d0 = dst[e],     d1 = dst[e + 1], d2 = dst[e + 2], d3 = dst[e + 3];
    float4 xi0 = x4[d0], xj0 = x4[s0];
    float4 xi1 = x4[d1], xj1 = x4[s1];
    float4 xi2 = x4[d2], xj2 = x4[s2];
    float4 xi3 = x4[d3], xj3 = x4[s3];
#pragma unroll
    for (int g = 0; g < 4; ++g) {
      float4 xi = (g == 0) ? xi0 : (g == 1) ? xi1 : (g == 2) ? xi2 : xi3;
      float4 xj = (g == 0) ? xj0 : (g == 1) ? xj1 : (g == 2) ? xj2 : xj3;
      float m[8] = {xi.x, xi.y, xi.z, xi.w,
                    xj.x - xi.x, xj.y - xi.y, xj.z - xi.z, xj.w - xi.w};
      float acc = bs[c];
#pragma unroll
      for (int k = 0; k < 8; ++k) acc = fmaf(m[k], Ws[k * 64 + c], acc);
      y[(u64)(e + g) * 64 + c] = (_Float16)acc;
      ls += acc; lq += acc * acc;
    }
  }
  red[tid] = ls; __syncthreads();
  if (tid < 64) atomicAdd(&sum[tid], red[tid] + red[tid + 64] + red[tid + 128] + red[tid + 192]);
  __syncthreads();
  red[tid] = lq; __syncthreads();
  if (tid < 64) atomicAdd(&sq[tid], red[tid] + red[tid + 64] + red[tid + 128] + red[tid + 192]);
}

// -------- fp16 MFMA GEMM for EC layers: Y = relu(A*s+b) @ Wt^T + bias ----------
__global__ __launch_bounds__(256) void mfma_gemm_f16_kernel(
    const _Float16* A,
    const float* __restrict__ pSum, const float* __restrict__ pSq, float invcnt,
    const float* __restrict__ g, const float* __restrict__ be,
    const _Float16* __restrict__ WtH, const _Float16* __restrict__ WtL,
    const float* __restrict__ bias,
    _Float16* Y,
    float* __restrict__ sum, float* __restrict__ sq)
{
  __shared__ _Float16 BsH[64][72];
  __shared__ _Float16 BsL[64][72];
  __shared__ _Float16 scL[64];
  __shared__ _Float16 shL[64];
  __shared__ float redY[64];
  __shared__ float redQ[64];
  int tid = threadIdx.x;
  int lane = tid & 63, wid = tid >> 6;
  int row0 = blockIdx.x * 128 + wid * 32;
  int m16 = lane & 15, quad = lane >> 4;

#pragma unroll
  for (int it = 0; it < 2; ++it) {
    int slot = tid + it * 256;
    int n = slot >> 3, cg = slot & 7;
    *(uint4*)&BsH[n][cg * 8] = *(const uint4*)(WtH + n * 64 + cg * 8);
    *(uint4*)&BsL[n][cg * 8] = *(const uint4*)(WtL + n * 64 + cg * 8);
  }
  if (tid < 64) {
    float s, b;
    bn_coeff(pSum, pSq, invcnt, g, be, tid, s, b);
    scL[tid] = (_Float16)s;
    shL[tid] = (_Float16)b;
  }
  __syncthreads();

  f16x8 af[2][2];
#pragma unroll
  for (int rt = 0; rt < 2; ++rt) {
    int grow = row0 + rt * 16 + m16;
    const _Float16* ap = A + (u64)grow * 64 + quad * 8;
#pragma unroll
    for (int ks2 = 0; ks2 < 2; ++ks2) {
      f16x8 a = *(const f16x8*)(ap + ks2 * 32);
      f16x8 s8 = *(const f16x8*)&scL[quad * 8 + ks2 * 32];
      f16x8 h8 = *(const f16x8*)&shL[quad * 8 + ks2 * 32];
      a = a * s8 + h8;
#pragma unroll
      for (int j = 0; j < 8; ++j) a[j] = (a[j] > (_Float16)0) ? a[j] : (_Float16)0;
      af[rt][ks2] = a;
    }
  }

  f32x4 acc[2][4];
#pragma unroll
  for (int i = 0; i < 2; ++i)
#pragma unroll
    for (int j = 0; j < 4; ++j) acc[i][j] = {0.f, 0.f, 0.f, 0.f};

#pragma unroll
  for (int ks2 = 0; ks2 < 2; ++ks2) {
#pragma unroll
    for (int ct = 0; ct < 4; ++ct) {
      f16x8 bh = *(const f16x8*)&BsH[ct * 16 + m16][ks2 * 32 + quad * 8];
      f16x8 bl = *(const f16x8*)&BsL[ct * 16 + m16][ks2 * 32 + quad * 8];
#pragma unroll
      for (int rt = 0; rt < 2; ++rt) {
        acc[rt][ct] = __builtin_amdgcn_mfma_f32_16x16x32_f16(af[rt][ks2], bh, acc[rt][ct], 0, 0, 0);
        acc[rt][ct] = __builtin_amdgcn_mfma_f32_16x16x32_f16(af[rt][ks2], bl, acc[rt][ct], 0, 0, 0);
      }
    }
  }

  float cys[4], cqs[4];
#pragma unroll
  for (int ct = 0; ct < 4; ++ct) {
    int col = ct * 16 + m16;
    float bcol = bias[col];
    float cy = 0.f, cq = 0.f;
#pragma unroll
    for (int rt = 0; rt < 2; ++rt) {
#pragma unroll
      for (int rg = 0; rg < 4; ++rg) {
        int row = row0 + rt * 16 + quad * 4 + rg;
        float v = acc[rt][ct][rg] + bcol;
        Y[(u64)row * 64 + col] = (_Float16)v;
        cy += v; cq += v * v;
      }
    }
    cys[ct] = cy; cqs[ct] = cq;
  }
#pragma unroll
  for (int ct = 0; ct < 4; ++ct) {
    cys[ct] += __shfl_xor(cys[ct], 16, 64); cys[ct] += __shfl_xor(cys[ct], 32, 64);
    cqs[ct] += __shfl_xor(cqs[ct], 16, 64); cqs[ct] += __shfl_xor(cqs[ct], 32, 64);
  }
  __syncthreads();
  if (tid < 64) { redY[tid] = 0.f; redQ[tid] = 0.f; }
  __syncthreads();
  if (quad == 0) {
#pragma unroll
    for (int ct = 0; ct < 4; ++ct) {
      atomicAdd(&redY[ct * 16 + m16], cys[ct]);
      atomicAdd(&redQ[ct * 16 + m16], cqs[ct]);
    }
  }
  __syncthreads();
  if (tid < 64) {
    atomicAdd(&sum[tid], redY[tid]);
    atomicAdd(&sq[tid], redQ[tid]);
  }
}

// ---------------- split-bf16 MFMA GEMM (fp32 A; gin layers) ----------------
__global__ __launch_bounds__(256) void mfma_gemm_kernel(
    const float* A, int lda,
    const float* __restrict__ Add, int ldadd,
    const unsigned short* __restrict__ Wt_hi, const unsigned short* __restrict__ Wt_lo,
    const float* __restrict__ bias,
    float* Y, int ldy,
    float* __restrict__ sum, float* __restrict__ sq,
    int M, int K, int N)
{
  __shared__ unsigned short BsH[64][72];
  __shared__ unsigned short BsL[64][72];
  __shared__ float redY[64];
  __shared__ float redQ[64];
  int tid = threadIdx.x;
  int lane = tid & 63, wid = tid >> 6;
  int row0 = blockIdx.y * 128 + wid * 32;
  int col0 = blockIdx.x * 64;
  int m16 = lane & 15, quad = lane >> 4;

  f32x4 acc[2][4];
#pragma unroll
  for (int i = 0; i < 2; ++i)
#pragma unroll
    for (int j = 0; j < 4; ++j) acc[i][j] = {0.f, 0.f, 0.f, 0.f};

  for (int k0 = 0; k0 < K; k0 += 64) {
    if (k0) __syncthreads();
#pragma unroll
    for (int it = 0; it < 2; ++it) {
      int slot = tid + it * 256;
      int n = slot >> 3, cg = slot & 7;
      u64 off = (u64)(col0 + n) * K + k0 + cg * 8;
      *(uint4*)&BsH[n][cg * 8] = *(const uint4*)(Wt_hi + off);
      *(uint4*)&BsL[n][cg * 8] = *(const uint4*)(Wt_lo + off);
    }
    __syncthreads();

    bf16x8 ah[2][2], al[2][2];
#pragma unroll
    for (int rt = 0; rt < 2; ++rt) {
      int grow = row0 + rt * 16 + m16;
      const float* ap = A + (u64)grow * lda + k0 + quad * 8;
      const float* addp = Add ? (Add + (u64)grow * ldadd + k0 + quad * 8) : nullptr;
#pragma unroll
      for (int ks2 = 0; ks2 < 2; ++ks2) {
        float4 v0 = *(const float4*)(ap + ks2 * 32);
        float4 v1 = *(const float4*)(ap + ks2 * 32 + 4);
        if (Add) {
          float4 a0 = *(const float4*)(addp + ks2 * 32);
          float4 a1 = *(const float4*)(addp + ks2 * 32 + 4);
          v0.x += a0.x; v0.y += a0.y; v0.z += a0.z; v0.w += a0.w;
          v1.x += a1.x; v1.y += a1.y; v1.z += a1.z; v1.w += a1.w;
        }
        float f[8] = {v0.x, v0.y, v0.z, v0.w, v1.x, v1.y, v1.z, v1.w};
        bf16x8 th, tl;
#pragma unroll
        for (int j = 0; j < 8; ++j) {
          unsigned short hi = f2bf(f[j]);
          th[j] = (short)hi;
          tl[j] = (short)f2bf(f[j] - b2f(hi));
        }
        ah[rt][ks2] = th;
        al[rt][ks2] = tl;
      }
    }

#pragma unroll
    for (int ks2 = 0; ks2 < 2; ++ks2) {
#pragma unroll
      for (int ct = 0; ct < 4; ++ct) {
        bf16x8 bh = *(const bf16x8*)&BsH[ct * 16 + m16][ks2 * 32 + quad * 8];
        bf16x8 bl = *(const bf16x8*)&BsL[ct * 16 + m16][ks2 * 32 + quad * 8];
#pragma unroll
        for (int rt = 0; rt < 2; ++rt) {
          acc[rt][ct] = __builtin_amdgcn_mfma_f32_16x16x32_bf16(ah[rt][ks2], bh, acc[rt][ct], 0, 0, 0);
          acc[rt][ct] = __builtin_amdgcn_mfma_f32_16x16x32_bf16(ah[rt][ks2], bl, acc[rt][ct], 0, 0, 0);
          acc[rt][ct] = __builtin_amdgcn_mfma_f32_16x16x32_bf16(al[rt][ks2], bh, acc[rt][ct], 0, 0, 0);
        }
      }
    }
  }

  float cys[4], cqs[4];
#pragma unroll
  for (int ct = 0; ct < 4; ++ct) {
    int col = col0 + ct * 16 + m16;
    float bcol = bias[col];
    float cy = 0.f, cq = 0.f;
#pragma unroll
    for (int rt = 0; rt < 2; ++rt) {
#pragma unroll
      for (int rg = 0; rg < 4; ++rg) {
        int row = row0 + rt * 16 + quad * 4 + rg;
        float v = acc[rt][ct][rg] + bcol;
        Y[(u64)row * ldy + col] = v;
        cy += v; cq += v * v;
      }
    }
    cys[ct] = cy; cqs[ct] = cq;
  }
#pragma unroll
  for (int ct = 0; ct < 4; ++ct) {
    cys[ct] += __shfl_xor(cys[ct], 16, 64); cys[ct] += __shfl_xor(cys[ct], 32, 64);
    cqs[ct] += __shfl_xor(cqs[ct], 16, 64); cqs[ct] += __shfl_xor(cqs[ct], 32, 64);
  }
  __syncthreads();
  if (tid < 64) { redY[tid] = 0.f; redQ[tid] = 0.f; }
  __syncthreads();
  if (quad == 0) {
#pragma unroll
    for (int ct = 0; ct < 4; ++ct) {
      atomicAdd(&redY[ct * 16 + m16], cys[ct]);
      atomicAdd(&redQ[ct * 16 + m16], cqs[ct]);
    }
  }
  __syncthreads();
  if (tid < 64) {
    atomicAdd(&sum[col0 + tid], redY[tid]);
    atomicAdd(&sq[col0 + tid], redQ[tid]);
  }
}

// ------- lin GEMM: single bf16 A plane, W hi/lo, 128-col blocks, fp16 out ------
__global__ __launch_bounds__(256) void mfma_gemm_ps_kernel(
    const unsigned short* __restrict__ Ahi,
    const unsigned short* __restrict__ Wt_hi, const unsigned short* __restrict__ Wt_lo,
    const float* __restrict__ bias,
    _Float16* __restrict__ Y,
    float* __restrict__ sum, float* __restrict__ sq,
    int K, int N)
{
  __shared__ unsigned short BsH[128][72];
  __shared__ unsigned short BsL[128][72];
  __shared__ float redY[128];
  __shared__ float redQ[128];
  int tid = threadIdx.x;
  int lane = tid & 63, wid = tid >> 6;
  int row0 = blockIdx.y * 128 + wid * 32;
  int col0 = blockIdx.x * 128;
  int m16 = lane & 15, quad = lane >> 4;

  f32x4 acc[2][8];
#pragma unroll
  for (int i = 0; i < 2; ++i)
#pragma unroll
    for (int j = 0; j < 8; ++j) acc[i][j] = {0.f, 0.f, 0.f, 0.f};

  for (int k0 = 0; k0 < K; k0 += 64) {
    if (k0) __syncthreads();
#pragma unroll
    for (int it = 0; it < 4; ++it) {
      int slot = tid + it * 256;
      int n = slot >> 3, cg = slot & 7;
      u64 off = (u64)(col0 + n) * K + k0 + cg * 8;
      *(uint4*)&BsH[n][cg * 8] = *(const uint4*)(Wt_hi + off);
      *(uint4*)&BsL[n][cg * 8] = *(const uint4*)(Wt_lo + off);
    }
    __syncthreads();

    bf16x8 ah[2][2];
#pragma unroll
    for (int rt = 0; rt < 2; ++rt) {
      int grow = row0 + rt * 16 + m16;
      u64 abase = (u64)grow * K + k0 + quad * 8;
#pragma unroll
      for (int ks2 = 0; ks2 < 2; ++ks2)
        ah[rt][ks2] = *(const bf16x8*)(Ahi + abase + ks2 * 32);
    }

#pragma unroll
    for (int ks2 = 0; ks2 < 2; ++ks2) {
#pragma unroll
      for (int ct = 0; ct < 8; ++ct) {
        bf16x8 bh = *(const bf16x8*)&BsH[ct * 16 + m16][ks2 * 32 + quad * 8];
        bf16x8 bl = *(const bf16x8*)&BsL[ct * 16 + m16][ks2 * 32 + quad * 8];
#pragma unroll
        for (int rt = 0; rt < 2; ++rt) {
          acc[rt][ct] = __builtin_amdgcn_mfma_f32_16x16x32_bf16(ah[rt][ks2], bh, acc[rt][ct], 0, 0, 0);
          acc[rt][ct] = __builtin_amdgcn_mfma_f32_16x16x32_bf16(ah[rt][ks2], bl, acc[rt][ct], 0, 0, 0);
        }
      }
    }
  }

  float cys[8], cqs[8];
#pragma unroll
  for (int ct = 0; ct < 8; ++ct) {
    int col = col0 + ct * 16 + m16;
    float bcol = bias[col];
    float cy = 0.f, cq = 0.f;
#pragma unroll
    for (int rt = 0; rt < 2; ++rt) {
#pragma unroll
      for (int rg = 0; rg < 4; ++rg) {
        int row = row0 + rt * 16 + quad * 4 + rg;
        float v = acc[rt][ct][rg] + bcol;
        Y[(u64)row * N + col] = (_Float16)v;
        cy += v; cq += v * v;
      }
    }
    cys[ct] = cy; cqs[ct] = cq;
  }
#pragma unroll
  for (int ct = 0; ct < 8; ++ct) {
    cys[ct] += __shfl_xor(cys[ct], 16, 64); cys[ct] += __shfl_xor(cys[ct], 32, 64);
    cqs[ct] += __shfl_xor(cqs[ct], 16, 64); cqs[ct] += __shfl_xor(cqs[ct], 32, 64);
  }
  __syncthreads();
  if (tid < 128) { redY[tid] = 0.f; redQ[tid] = 0.f; }
  __syncthreads();
  if (quad == 0) {
#pragma unroll
    for (int ct = 0; ct < 8; ++ct) {
      atomicAdd(&redY[ct * 16 + m16], cys[ct]);
      atomicAdd(&redQ[ct * 16 + m16], cqs[ct]);
    }
  }
  __syncthreads();
  if (tid < 128) {
    atomicAdd(&sum[col0 + tid], redY[tid]);
    atomicAdd(&sq[col0 + tid], redQ[tid]);
  }
}

// ---------------- head GEMM: M=64 rows, row per block; optional pre-BN ----------
__global__ __launch_bounds__(256) void head_gemm_kernel(
    const float* __restrict__ A, int K,
    const float* __restrict__ pSum, const float* __restrict__ pSq, float invcnt,
    const float* __restrict__ g, const float* __restrict__ be,
    const float* __restrict__ W, const float* __restrict__ bias,
    float* __restrict__ Y, int Cout,
    float* __restrict__ sum, float* __restrict__ sq)
{
  __shared__ float As[2048];
  int r = blockIdx.y;
  int tid = threadIdx.x;
  for (int k = tid; k < K; k += 256) {
    float v = A[(u64)r * K + k];
    if (pSum) {
      float s, b;
      bn_coeff(pSum, pSq, invcnt, g, be, k, s, b);
      v = fmaxf(fmaf(v, s, b), 0.f);
    }
    As[k] = v;
  }
  __syncthreads();
  int c = blockIdx.x * 256 + tid;
  if (c >= Cout) return;
  float a0 = 0.f, a1 = 0.f, a2 = 0.f, a3 = 0.f;
  for (int k = 0; k < K; k += 4) {
    a0 = fmaf(As[k + 0], W[(u64)(k + 0) * Cout + c], a0);
    a1 = fmaf(As[k + 1], W[(u64)(k + 1) * Cout + c], a1);
    a2 = fmaf(As[k + 2], W[(u64)(k + 2) * Cout + c], a2);
    a3 = fmaf(As[k + 3], W[(u64)(k + 3) * Cout + c], a3);
  }
  float acc = bias[c] + ((a0 + a1) + (a2 + a3));
  Y[(u64)r * Cout + c] = acc;
  if (sum) { atomicAdd(&sum[c], acc); atomicAdd(&sq[c], acc * acc); }
}

// -------- stats-only pass: t = relu(z*s1+b1), accumulate sum/sq of t -----------
__global__ __launch_bounds__(256) void act_stats_kernel(
    const float* __restrict__ z,
    const float* __restrict__ pSum, const float* __restrict__ pSq, float invcnt,
    const float* __restrict__ g, const float* __restrict__ be,
    float* __restrict__ sum, float* __restrict__ sq, int total, int cmask)
{
  __shared__ float red[256];
  int tid = threadIdx.x;
  int c = tid & cmask;
  float s, b;
  bn_coeff(pSum, pSq, invcnt, g, be, c, s, b);
  float ls = 0.f, lq = 0.f;
  for (int idx = blockIdx.x * 256 + tid; idx < total; idx += gridDim.x * 256) {
    float v = fmaxf(fmaf(z[idx], s, b), 0.f);
    ls += v; lq += v * v;
  }
  red[tid] = ls; __syncthreads();
  if (tid <= cmask) {
    float t = 0.f;
    for (int k = tid; k < 256; k += cmask + 1) t += red[k];
    atomicAdd(&sum[tid], t);
  }
  __syncthreads();
  red[tid] = lq; __syncthreads();
  if (tid <= cmask) {
    float t = 0.f;
    for (int k = tid; k < 256; k += cmask + 1) t += red[k];
    atomicAdd(&sq[tid], t);
  }
}

// ------ recompute t from z, apply outer affine, write h + bf16 hi plane --------
__global__ __launch_bounds__(256) void apply_bn_kernel(
    const float* __restrict__ z,
    const float* __restrict__ iSum, const float* __restrict__ iSq, float invcnt,
    const float* __restrict__ ig, const float* __restrict__ ibe,
    const float* __restrict__ oSum, const float* __restrict__ oSq,
    const float* __restrict__ og, const float* __restrict__ obe,
    float* __restrict__ h, unsigned short* __restrict__ hspH,
    int off, int cshift, int cmask, int total)
{
  int tid = threadIdx.x;
  int c = tid & cmask;
  float s1, b1, s2, b2;
  bn_coeff(iSum, iSq, invcnt, ig, ibe, c, s1, b1);
  bn_coeff(oSum, oSq, invcnt, og, obe, c, s2, b2);
  for (int idx = blockIdx.x * 256 + tid; idx < total; idx += gridDim.x * 256) {
    int r = idx >> cshift;
    float t = fmaxf(fmaf(z[idx], s1, b1), 0.f);
    float v = fmaf(t, s2, b2);
    u64 o = (u64)r * 512 + off + (idx & cmask);
    h[o] = v;
    hspH[o] = f2bf(v);
  }
}

// ------------- EdgeConv segment_max via CSR + bf16 hi plane ----------------
__global__ __launch_bounds__(256) void x0max_csr_kernel(
    const _Float16* __restrict__ y3,
    const float* __restrict__ pSum, const float* __restrict__ pSq, float invcnt,
    const float* __restrict__ g, const float* __restrict__ be,
    const int* __restrict__ row_ptr, float* __restrict__ h,
    unsigned short* __restrict__ hspH)
{
  int n = blockIdx.x * 4 + (threadIdx.x >> 6);
  int lane = threadIdx.x & 63;
  int b = row_ptr[n], e = row_ptr[n + 1];
  float s, bb;
  bn_coeff(pSum, pSq, invcnt, g, be, lane, s, bb);
  float mx = 0.f;
  for (int i = b; i < e; ++i) {
    float v = fmaxf(fmaf((float)y3[(u64)i * 64 + lane], s, bb), 0.f);
    mx = fmaxf(mx, v);
  }
  u64 o = (u64)n * 512 + lane;
  h[o] = mx;
  hspH[o] = f2bf(mx);
}

// ------------- GIN neighbor-sum via CSR gather (wave per node, coalesced) ------
template<int COLS>
__global__ __launch_bounds__(256) void gather_add_kernel(
    const float* __restrict__ h, int off,
    const int* __restrict__ row_ptr, const int* __restrict__ ssrc,
    float* __restrict__ agg)
{
  int n = blockIdx.x * 4 + (threadIdx.x >> 6);
  int lane = threadIdx.x & 63;
  int b = row_ptr[n], e = row_ptr[n + 1];
  float a0 = 0.f, a1 = 0.f;
  for (int i = b; i < e; ++i) {
    const float* p = h + (u64)ssrc[i] * 512 + off + lane;
    a0 += p[0];
    if (COLS > 64) a1 += p[64];
  }
  float* q = agg + (u64)n * COLS + lane;
  q[0] = a0;
  if (COLS > 64) q[64] = a1;
}

// ---------------- graph pooling (hl fp16) ----------------
__global__ __launch_bounds__(256) void pool_kernel(
    const _Float16* __restrict__ hl,
    const float* __restrict__ pSum, const float* __restrict__ pSq, float invcnt,
    const float* __restrict__ g, const float* __restrict__ be,
    float* __restrict__ o)
{
  int gidx = blockIdx.x;
  int c = blockIdx.y * 256 + threadIdx.x;
  float s, b;
  bn_coeff(pSum, pSq, invcnt, g, be, c, s, b);
  const _Float16* p = hl + (u64)gidx * NPG * 1024 + c;
  float mx = 0.f, sm = 0.f;
  for (int n = 0; n < NPG; ++n) {
    float v = fmaxf(fmaf((float)p[(u64)n * 1024], s, b), 0.f);
    mx = fmaxf(mx, v);
    sm += v;
  }
  o[gidx * 2048 + c] = mx;
  o[gidx * 2048 + 1024 + c] = sm * (1.f / NPG);
}

// ---------------- log_softmax over 40 cols ----------------
__global__ void lsm_kernel(const float* __restrict__ logits, float* __restrict__ out)
{
  int r = blockIdx.x;
  int c = threadIdx.x;
  float v = (c < 40) ? logits[r * 40 + c] : -INFINITY;
  float m = v;
  for (int off = 32; off; off >>= 1) m = fmaxf(m, __shfl_xor(m, off, 64));
  float e = (c < 40) ? expf(v - m) : 0.f;
  float s = e;
  for (int off = 32; off; off >>= 1) s += __shfl_xor(s, off, 64);
  if (c < 40) out[r * 40 + c] = (v - m) - logf(s);
}

extern "C" void kernel_launch(void* const* d_in, const int* in_sizes, int n_in,
                              void* d_out, int out_size, void* d_ws, size_t ws_size,
                              hipStream_t stream)
{
  const float* x    = (const float*)d_in[0];
  const int*   ei   = (const int*)d_in[1];
  const int*   srcI = ei;
  const int*   dstI = ei + E_EDGES;
  const float* ecW1 = (const float*)d_in[3];
  const float* ecb1 = (const float*)d_in[4];
  const float* ecg1 = (const float*)d_in[5];
  const float* ecbe1= (const float*)d_in[6];
  const float* ecW2 = (const float*)d_in[7];
  const float* ecb2 = (const float*)d_in[8];
  const float* ecg2 = (const float*)d_in[9];
  const float* ecbe2= (const float*)d_in[10];
  const float* ecW3 = (const float*)d_in[11];
  const float* ecb3 = (const float*)d_in[12];
  const float* ecg3 = (const float*)d_in[13];
  const float* ecbe3= (const float*)d_in[14];
  const float* g1W  = (const float*)d_in[15];
  const float* g1b  = (const float*)d_in[16];
  const float* g1g  = (const float*)d_in[17];
  const float* g1be = (const float*)d_in[18];
  const float* g2W  = (const float*)d_in[19];
  const float* g2b  = (const float*)d_in[20];
  const float* g2g  = (const float*)d_in[21];
  const float* g2be = (const float*)d_in[22];
  const float* g3W  = (const float*)d_in[23];
  const float* g3b  = (const float*)d_in[24];
  const float* g3g  = (const float*)d_in[25];
  const float* g3be = (const float*)d_in[26];
  const float* bn1g = (const float*)d_in[27];
  const float* bn1be= (const float*)d_in[28];
  const float* bn2g = (const float*)d_in[29];
  const float* bn2be= (const float*)d_in[30];
  const float* bn3g = (const float*)d_in[31];
  const float* bn3be= (const float*)d_in[32];
  const float* linW = (const float*)d_in[33];
  const float* linb = (const float*)d_in[34];
  const float* ling = (const float*)d_in[35];
  const float* linbe= (const float*)d_in[36];
  const float* h1W  = (const float*)d_in[37];
  const float* h1b  = (const float*)d_in[38];
  const float* h1g  = (const float*)d_in[39];
  const float* h1be = (const float*)d_in[40];
  const float* h2W  = (const float*)d_in[41];
  const float* h2b  = (const float*)d_in[42];
  const float* h2g  = (const float*)d_in[43];
  const float* h2be = (const float*)d_in[44];
  const float* outW = (const float*)d_in[45];
  const float* outb = (const float*)d_in[46];

  char* ws = (char*)d_ws;
  const size_t MB = 1024ull * 1024ull;
  // ---- stats area [0, 96 KiB): 12 slots of (sum 4K + sq 4K) ----
#define S(i) ((float*)(ws + (size_t)(i) * 8192))
#define Q(i) ((float*)(ws + (size_t)(i) * 8192 + 4096))
  // ---- small buffers [128 KiB, 1 MiB) ----
  float* o_     = (float*)(ws + 131072);
  float* yh1    = (float*)(ws + 131072 + 524288);
  float* yh2    = (float*)(ws + 131072 + 524288 + 131072);
  float* logits = (float*)(ws + 131072 + 524288 + 131072 + 65536);
  // ---- weights [1 MiB, 4 MiB) ----
  _Float16* ec2WtH16 = (_Float16*)(ws + 1 * MB);
  _Float16* ec2WtL16 = (_Float16*)(ws + 1 * MB + 8192);
  _Float16* ec3WtH16 = (_Float16*)(ws + 1 * MB + 16384);
  _Float16* ec3WtL16 = (_Float16*)(ws + 1 * MB + 24576);
  unsigned short* g1WtH  = (unsigned short*)(ws + 1 * MB + 32768);
  unsigned short* g1WtL  = (unsigned short*)(ws + 1 * MB + 40960);
  unsigned short* g2WtH  = (unsigned short*)(ws + 1 * MB + 49152);
  unsigned short* g2WtL  = (unsigned short*)(ws + 1 * MB + 65536);
  unsigned short* g3WtH  = (unsigned short*)(ws + 1 * MB + 81920);
  unsigned short* g3WtL  = (unsigned short*)(ws + 1 * MB + 147456);
  unsigned short* linWtH = (unsigned short*)(ws + 1 * MB + 212992);
  unsigned short* linWtL = (unsigned short*)(ws + 1 * MB + 212992 + 1048576);
  // ---- big region [4 MiB, 132 MiB) ----
  _Float16* y  = (_Float16*)(ws + 4 * MB);     // [E,64] fp16 (dead after x0max)
  float* ytemp = (float*)(ws + 4 * MB);        // GIN z, <=32 MiB
  float* agg   = (float*)(ws + 36 * MB);       // GIN agg, <=32 MiB
  unsigned short* hspH = (unsigned short*)(ws + 68 * MB);   // [N,512] bf16 hi
  _Float16* hl = (_Float16*)(ws + 4 * MB);     // [N,1024] fp16 during lin/pool
  // ---- h region [132 MiB, 196 MiB): [N,512] fp32 ----
  float* h = (float*)(ws + 132 * MB);
  // ---- CSR region [196 MiB, 201 MiB) ----
  int* row_ptr = (int*)(ws + 196 * MB);
  int* cnt     = (int*)(ws + 196 * MB + 140000);
  int* ssrc    = (int*)(ws + 197 * MB);
  int* sdst    = (int*)(ws + 199 * MB);

  const float invE = 1.f / E_EDGES;
  const float invN = 1.f / N_NODES;
  const float invB = 1.f / N_GRAPHS;

  hipMemsetAsync((void*)ws, 0, 12 * 8192, stream);
  hipMemsetAsync((void*)cnt, 0, 32768 * 4, stream);

  // ---------------- CSR build ----------------
  hist_kernel<<<2048, 256, 0, stream>>>(dstI, cnt);
  scan_kernel<<<1, 1024, 0, stream>>>(cnt, row_ptr);
  fill_kernel<<<2048, 256, 0, stream>>>(srcI, dstI, cnt, ssrc, sdst);

  // ---------------- weight prep ----------------
  wt16_all_kernel<<<32, 256, 0, stream>>>(ecW2, ec2WtH16, ec2WtL16, ecW3, ec3WtH16, ec3WtL16);
  wt_all_kernel<<<2224, 256, 0, stream>>>(g1W, g1WtH, g1WtL, g2W, g2WtH, g2WtL,
                                          g3W, g3WtH, g3WtL, linW, linWtH, linWtL);

  // ---------------- EdgeConv (fp16 y, in-place) ----------------
  ec1_kernel<<<1024, 256, 0, stream>>>(x, ssrc, sdst, ecW1, ecb1, y, S(0), Q(0));
  mfma_gemm_f16_kernel<<<E_EDGES / 128, 256, 0, stream>>>(
      y, S(0), Q(0), invE, ecg1, ecbe1, ec2WtH16, ec2WtL16, ecb2, y, S(1), Q(1));
  mfma_gemm_f16_kernel<<<E_EDGES / 128, 256, 0, stream>>>(
      y, S(1), Q(1), invE, ecg2, ecbe2, ec3WtH16, ec3WtL16, ecb3, y, S(2), Q(2));
  x0max_csr_kernel<<<N_NODES / 4, 256, 0, stream>>>(
      y, S(2), Q(2), invE, ecg3, ecbe3, row_ptr, h, hspH);

  // ---------------- GIN 1 ----------------
  gather_add_kernel<64><<<N_NODES / 4, 256, 0, stream>>>(h, 0, row_ptr, ssrc, agg);
  mfma_gemm_kernel<<<dim3(1, N_NODES / 128), 256, 0, stream>>>(
      h, 512, agg, 64, g1WtH, g1WtL, g1b, ytemp, 64, S(3), Q(3), N_NODES, 64, 64);
  act_stats_kernel<<<512, 256, 0, stream>>>(
      ytemp, S(3), Q(3), invN, g1g, g1be, S(4), Q(4), N_NODES * 64, 63);
  apply_bn_kernel<<<1024, 256, 0, stream>>>(
      ytemp, S(3), Q(3), invN, g1g, g1be, S(4), Q(4), bn1g, bn1be,
      h, hspH, 64, 6, 63, N_NODES * 64);

  // ---------------- GIN 2 ----------------
  gather_add_kernel<64><<<N_NODES / 4, 256, 0, stream>>>(h, 64, row_ptr, ssrc, agg);
  mfma_gemm_kernel<<<dim3(2, N_NODES / 128), 256, 0, stream>>>(
      h + 64, 512, agg, 64, g2WtH, g2WtL, g2b, ytemp, 128, S(5), Q(5), N_NODES, 64, 128);
  act_stats_kernel<<<512, 256, 0, stream>>>(
      ytemp, S(5), Q(5), invN, g2g, g2be, S(6), Q(6), N_NODES * 128, 127);
  apply_bn_kernel<<<1024, 256, 0, stream>>>(
      ytemp, S(5), Q(5), invN, g2g, g2be, S(6), Q(6), bn2g, bn2be,
      h, hspH, 128, 7, 127, N_NODES * 128);

  // ---------------- GIN 3 ----------------
  gather_add_kernel<128><<<N_NODES / 4, 256, 0, stream>>>(h, 128, row_ptr, ssrc, agg);
  mfma_gemm_kernel<<<dim3(4, N_NODES / 128), 256, 0, stream>>>(
      h + 128, 512, agg, 128, g3WtH, g3WtL, g3b, ytemp, 256, S(7), Q(7), N_NODES, 128, 256);
  act_stats_kernel<<<512, 256, 0, stream>>>(
      ytemp, S(7), Q(7), invN, g3g, g3be, S(8), Q(8), N_NODES * 256, 255);
  apply_bn_kernel<<<1024, 256, 0, stream>>>(
      ytemp, S(7), Q(7), invN, g3g, g3be, S(8), Q(8), bn3g, bn3be,
      h, hspH, 256, 8, 255, N_NODES * 256);

  // ---------------- lin (128-col blocks) + pool ----------------
  mfma_gemm_ps_kernel<<<dim3(8, N_NODES / 128), 256, 0, stream>>>(
      hspH, linWtH, linWtL, linb, hl, S(9), Q(9), 512, 1024);
  pool_kernel<<<dim3(64, 4), 256, 0, stream>>>(hl, S(9), Q(9), invN, ling, linbe, o_);

  // ---------------- head ----------------
  head_gemm_kernel<<<dim3(2, 64), 256, 0, stream>>>(
      o_, 2048, nullptr, nullptr, 0.f, nullptr, nullptr, h1W, h1b, yh1, 512, S(10), Q(10));
  head_gemm_kernel<<<dim3(1, 64), 256, 0, stream>>>(
      yh1, 512, S(10), Q(10), invB, h1g, h1be, h2W, h2b, yh2, 256, S(11), Q(11));
  head_gemm_kernel<<<dim3(1, 64), 256, 0, stream>>>(
      yh2, 256, S(11), Q(11), invB, h2g, h2be, outW, outb, logits, 40, nullptr, nullptr);
  lsm_kernel<<<64, 64, 0, stream>>>(logits, (float*)d_out);
#undef S
#undef Q
}

// Round 17
// 1115.211 us; speedup vs baseline: 1.0476x; 1.0211x over previous
//
#include <hip/hip_runtime.h>
#include <math.h>

#define E_EDGES 524288
#define N_NODES 32768
#define N_GRAPHS 64
#define NPG 512

typedef unsigned long long u64;
using bf16x8 = __attribute__((ext_vector_type(8))) short;
using f16x8  = __attribute__((ext_vector_type(8))) _Float16;
using f32x4  = __attribute__((ext_vector_type(4))) float;

__device__ __forceinline__ unsigned short f2bf(float f) {
  unsigned int u = __float_as_uint(f);
  u += 0x7FFFu + ((u >> 16) & 1u);
  return (unsigned short)(u >> 16);
}
__device__ __forceinline__ float b2f(unsigned short s) {
  return __uint_as_float(((unsigned int)s) << 16);
}
// BN coeff from raw sums: s = g/sqrt(var+eps), b = be - m*s
__device__ __forceinline__ void bn_coeff(
    const float* __restrict__ pSum, const float* __restrict__ pSq, float invcnt,
    const float* __restrict__ g, const float* __restrict__ be, int c,
    float& s, float& b)
{
  float m = pSum[c] * invcnt;
  float v = pSq[c] * invcnt - m * m;
  float is = rsqrtf(v + 1e-5f);
  s = g[c] * is;
  b = fmaf(-m, s, be[c]);
}

// ================= CSR build (dst-sorted edge permutation) =================
__global__ __launch_bounds__(256) void hist_kernel(
    const int* __restrict__ dst, int* __restrict__ cnt)
{
  int e = blockIdx.x * 256 + threadIdx.x;
  atomicAdd(&cnt[dst[e]], 1);
}

__global__ __launch_bounds__(1024) void scan_kernel(
    int* __restrict__ cnt, int* __restrict__ row_ptr)
{
  __shared__ int s[1024];
  int t = threadIdx.x;
  int base = t * 32;
  int local[32];
  int acc = 0;
#pragma unroll
  for (int i = 0; i < 32; ++i) { local[i] = acc; acc += cnt[base + i]; }
  s[t] = acc;
  __syncthreads();
  for (int d = 1; d < 1024; d <<= 1) {
    int v = (t >= d) ? s[t - d] : 0;
    __syncthreads();
    s[t] += v;
    __syncthreads();
  }
  int off = t ? s[t - 1] : 0;
#pragma unroll
  for (int i = 0; i < 32; ++i) {
    int p = off + local[i];
    row_ptr[base + i] = p;
    cnt[base + i] = p;
  }
  if (t == 1023) row_ptr[32768] = off + acc;
}

__global__ __launch_bounds__(256) void fill_kernel(
    const int* __restrict__ src, const int* __restrict__ dst,
    int* __restrict__ pos, int* __restrict__ ssrc, int* __restrict__ sdst)
{
  int e = blockIdx.x * 256 + threadIdx.x;
  int d = dst[e];
  int p = atomicAdd(&pos[d], 1);
  ssrc[p] = src[e];
  sdst[p] = d;
}

// ---------------- merged weight transpose kernels ----------------
__global__ __launch_bounds__(256) void wt16_all_kernel(
    const float* __restrict__ W2, _Float16* __restrict__ H2, _Float16* __restrict__ L2,
    const float* __restrict__ W3, _Float16* __restrict__ H3, _Float16* __restrict__ L3)
{
  int b = blockIdx.x;
  const float* W = (b < 16) ? W2 : W3;
  _Float16* H = (b < 16) ? H2 : H3;
  _Float16* L = (b < 16) ? L2 : L3;
  int idx = (b & 15) * 256 + threadIdx.x;
  int n = idx >> 6, k = idx & 63;
  float w = W[k * 64 + n];
  _Float16 hi = (_Float16)w;
  H[idx] = hi;
  L[idx] = (_Float16)(w - (float)hi);
}

__global__ __launch_bounds__(256) void wt_all_kernel(
    const float* __restrict__ g1W, unsigned short* __restrict__ g1H, unsigned short* __restrict__ g1L,
    const float* __restrict__ g2W, unsigned short* __restrict__ g2H, unsigned short* __restrict__ g2L,
    const float* __restrict__ g3W, unsigned short* __restrict__ g3H, unsigned short* __restrict__ g3L,
    const float* __restrict__ lW,  unsigned short* __restrict__ lH,  unsigned short* __restrict__ lL)
{
  int b = blockIdx.x;
  const float* W; unsigned short *H, *L; int kshift, N, base;
  if (b < 16)       { W = g1W; H = g1H; L = g1L; kshift = 6; N = 64;   base = 0; }
  else if (b < 48)  { W = g2W; H = g2H; L = g2L; kshift = 6; N = 128;  base = 16; }
  else if (b < 176) { W = g3W; H = g3H; L = g3L; kshift = 7; N = 256;  base = 48; }
  else              { W = lW;  H = lH;  L = lL;  kshift = 9; N = 1024; base = 176; }
  int idx = (b - base) * 256 + threadIdx.x;
  int n = idx >> kshift;
  int k = idx & ((1 << kshift) - 1);
  float w = W[(u64)k * N + n];
  unsigned short hi = f2bf(w);
  H[idx] = hi;
  L[idx] = f2bf(w - b2f(hi));
}

// ----- EdgeConv layer 1: 4-edge ILP per wave iteration, fp16 out + stats -------
__global__ __launch_bounds__(256) void ec1_kernel(
    const float* __restrict__ x, const int* __restrict__ src, const int* __restrict__ dst,
    const float* __restrict__ W, const float* __restrict__ b,
    _Float16* __restrict__ y, float* __restrict__ sum, float* __restrict__ sq)
{
  __shared__ float Ws[512];
  __shared__ float bs[64];
  __shared__ float red[256];
  int tid = threadIdx.x;
  for (int i = tid; i < 512; i += 256) Ws[i] = W[i];
  if (tid < 64) bs[tid] = b[tid];
  __syncthreads();
  int c = tid & 63;
  int eslot = tid >> 6;
  float ls = 0.f, lq = 0.f;
  const float4* x4 = (const float4*)x;
  int stride = gridDim.x * 16;
  for (int e = blockIdx.x * 16 + eslot * 4; e < E_EDGES; e += stride) {
    int s0 = src[e],     s1 = src[e + 1], s2 = src[e + 2], s3 = src[e + 3];
    int d0 = dst[e],     d1 = dst[e + 1], d2 = dst[e + 2], d3 = dst[e + 3];
    float4 xi0 = x4[d0], xj0 = x4[s0];
    float4 xi1 = x4[d1], xj1 = x4[s1];
    float4 xi2 = x4[d2], xj2 = x4[s2];
    float4 xi3 = x4[d3], xj3 = x4[s3];
#pragma unroll
    for (int g = 0; g < 4; ++g) {
      float4 xi = (g == 0) ? xi0 : (g == 1) ? xi1 : (g == 2) ? xi2 : xi3;
      float4 xj = (g == 0) ? xj0 : (g == 1) ? xj1 : (g == 2) ? xj2 : xj3;
      float m[8] = {xi.x, xi.y, xi.z, xi.w,
                    xj.x - xi.x, xj.y - xi.y, xj.z - xi.z, xj.w - xi.w};
      float acc = bs[c];
#pragma unroll
      for (int k = 0; k < 8; ++k) acc = fmaf(m[k], Ws[k * 64 + c], acc);
      y[(u64)(e + g) * 64 + c] = (_Float16)acc;
      ls += acc; lq += acc * acc;
    }
  }
  red[tid] = ls; __syncthreads();
  if (tid < 64) atomicAdd(&sum[tid], red[tid] + red[tid + 64] + red[tid + 128] + red[tid + 192]);
  __syncthreads();
  red[tid] = lq; __syncthreads();
  if (tid < 64) atomicAdd(&sq[tid], red[tid] + red[tid + 64] + red[tid + 128] + red[tid + 192]);
}

// -------- fp16 MFMA GEMM for EC layers: Y = relu(A*s+b) @ Wt^T + bias ----------
__global__ __launch_bounds__(256) void mfma_gemm_f16_kernel(
    const _Float16* A,
    const float* __restrict__ pSum, const float* __restrict__ pSq, float invcnt,
    const float* __restrict__ g, const float* __restrict__ be,
    const _Float16* __restrict__ WtH, const _Float16* __restrict__ WtL,
    const float* __restrict__ bias,
    _Float16* Y,
    float* __restrict__ sum, float* __restrict__ sq)
{
  __shared__ _Float16 BsH[64][72];
  __shared__ _Float16 BsL[64][72];
  __shared__ _Float16 scL[64];
  __shared__ _Float16 shL[64];
  __shared__ float redY[64];
  __shared__ float redQ[64];
  int tid = threadIdx.x;
  int lane = tid & 63, wid = tid >> 6;
  int row0 = blockIdx.x * 128 + wid * 32;
  int m16 = lane & 15, quad = lane >> 4;

#pragma unroll
  for (int it = 0; it < 2; ++it) {
    int slot = tid + it * 256;
    int n = slot >> 3, cg = slot & 7;
    *(uint4*)&BsH[n][cg * 8] = *(const uint4*)(WtH + n * 64 + cg * 8);
    *(uint4*)&BsL[n][cg * 8] = *(const uint4*)(WtL + n * 64 + cg * 8);
  }
  if (tid < 64) {
    float s, b;
    bn_coeff(pSum, pSq, invcnt, g, be, tid, s, b);
    scL[tid] = (_Float16)s;
    shL[tid] = (_Float16)b;
  }
  __syncthreads();

  f16x8 af[2][2];
#pragma unroll
  for (int rt = 0; rt < 2; ++rt) {
    int grow = row0 + rt * 16 + m16;
    const _Float16* ap = A + (u64)grow * 64 + quad * 8;
#pragma unroll
    for (int ks2 = 0; ks2 < 2; ++ks2) {
      f16x8 a = *(const f16x8*)(ap + ks2 * 32);
      f16x8 s8 = *(const f16x8*)&scL[quad * 8 + ks2 * 32];
      f16x8 h8 = *(const f16x8*)&shL[quad * 8 + ks2 * 32];
      a = a * s8 + h8;
#pragma unroll
      for (int j = 0; j < 8; ++j) a[j] = (a[j] > (_Float16)0) ? a[j] : (_Float16)0;
      af[rt][ks2] = a;
    }
  }

  f32x4 acc[2][4];
#pragma unroll
  for (int i = 0; i < 2; ++i)
#pragma unroll
    for (int j = 0; j < 4; ++j) acc[i][j] = {0.f, 0.f, 0.f, 0.f};

#pragma unroll
  for (int ks2 = 0; ks2 < 2; ++ks2) {
#pragma unroll
    for (int ct = 0; ct < 4; ++ct) {
      f16x8 bh = *(const f16x8*)&BsH[ct * 16 + m16][ks2 * 32 + quad * 8];
      f16x8 bl = *(const f16x8*)&BsL[ct * 16 + m16][ks2 * 32 + quad * 8];
#pragma unroll
      for (int rt = 0; rt < 2; ++rt) {
        acc[rt][ct] = __builtin_amdgcn_mfma_f32_16x16x32_f16(af[rt][ks2], bh, acc[rt][ct], 0, 0, 0);
        acc[rt][ct] = __builtin_amdgcn_mfma_f32_16x16x32_f16(af[rt][ks2], bl, acc[rt][ct], 0, 0, 0);
      }
    }
  }

  float cys[4], cqs[4];
#pragma unroll
  for (int ct = 0; ct < 4; ++ct) {
    int col = ct * 16 + m16;
    float bcol = bias[col];
    float cy = 0.f, cq = 0.f;
#pragma unroll
    for (int rt = 0; rt < 2; ++rt) {
#pragma unroll
      for (int rg = 0; rg < 4; ++rg) {
        int row = row0 + rt * 16 + quad * 4 + rg;
        float v = acc[rt][ct][rg] + bcol;
        Y[(u64)row * 64 + col] = (_Float16)v;
        cy += v; cq += v * v;
      }
    }
    cys[ct] = cy; cqs[ct] = cq;
  }
#pragma unroll
  for (int ct = 0; ct < 4; ++ct) {
    cys[ct] += __shfl_xor(cys[ct], 16, 64); cys[ct] += __shfl_xor(cys[ct], 32, 64);
    cqs[ct] += __shfl_xor(cqs[ct], 16, 64); cqs[ct] += __shfl_xor(cqs[ct], 32, 64);
  }
  __syncthreads();
  if (tid < 64) { redY[tid] = 0.f; redQ[tid] = 0.f; }
  __syncthreads();
  if (quad == 0) {
#pragma unroll
    for (int ct = 0; ct < 4; ++ct) {
      atomicAdd(&redY[ct * 16 + m16], cys[ct]);
      atomicAdd(&redQ[ct * 16 + m16], cqs[ct]);
    }
  }
  __syncthreads();
  if (tid < 64) {
    atomicAdd(&sum[tid], redY[tid]);
    atomicAdd(&sq[tid], redQ[tid]);
  }
}

// ---------------- split-bf16 MFMA GEMM (fp32 A; gin layers) ----------------
__global__ __launch_bounds__(256) void mfma_gemm_kernel(
    const float* A, int lda,
    const float* __restrict__ Add, int ldadd,
    const unsigned short* __restrict__ Wt_hi, const unsigned short* __restrict__ Wt_lo,
    const float* __restrict__ bias,
    float* Y, int ldy,
    float* __restrict__ sum, float* __restrict__ sq,
    int M, int K, int N)
{
  __shared__ unsigned short BsH[64][72];
  __shared__ unsigned short BsL[64][72];
  __shared__ float redY[64];
  __shared__ float redQ[64];
  int tid = threadIdx.x;
  int lane = tid & 63, wid = tid >> 6;
  int row0 = blockIdx.y * 128 + wid * 32;
  int col0 = blockIdx.x * 64;
  int m16 = lane & 15, quad = lane >> 4;

  f32x4 acc[2][4];
#pragma unroll
  for (int i = 0; i < 2; ++i)
#pragma unroll
    for (int j = 0; j < 4; ++j) acc[i][j] = {0.f, 0.f, 0.f, 0.f};

  for (int k0 = 0; k0 < K; k0 += 64) {
    if (k0) __syncthreads();
#pragma unroll
    for (int it = 0; it < 2; ++it) {
      int slot = tid + it * 256;
      int n = slot >> 3, cg = slot & 7;
      u64 off = (u64)(col0 + n) * K + k0 + cg * 8;
      *(uint4*)&BsH[n][cg * 8] = *(const uint4*)(Wt_hi + off);
      *(uint4*)&BsL[n][cg * 8] = *(const uint4*)(Wt_lo + off);
    }
    __syncthreads();

    bf16x8 ah[2][2], al[2][2];
#pragma unroll
    for (int rt = 0; rt < 2; ++rt) {
      int grow = row0 + rt * 16 + m16;
      const float* ap = A + (u64)grow * lda + k0 + quad * 8;
      const float* addp = Add ? (Add + (u64)grow * ldadd + k0 + quad * 8) : nullptr;
#pragma unroll
      for (int ks2 = 0; ks2 < 2; ++ks2) {
        float4 v0 = *(const float4*)(ap + ks2 * 32);
        float4 v1 = *(const float4*)(ap + ks2 * 32 + 4);
        if (Add) {
          float4 a0 = *(const float4*)(addp + ks2 * 32);
          float4 a1 = *(const float4*)(addp + ks2 * 32 + 4);
          v0.x += a0.x; v0.y += a0.y; v0.z += a0.z; v0.w += a0.w;
          v1.x += a1.x; v1.y += a1.y; v1.z += a1.z; v1.w += a1.w;
        }
        float f[8] = {v0.x, v0.y, v0.z, v0.w, v1.x, v1.y, v1.z, v1.w};
        bf16x8 th, tl;
#pragma unroll
        for (int j = 0; j < 8; ++j) {
          unsigned short hi = f2bf(f[j]);
          th[j] = (short)hi;
          tl[j] = (short)f2bf(f[j] - b2f(hi));
        }
        ah[rt][ks2] = th;
        al[rt][ks2] = tl;
      }
    }

#pragma unroll
    for (int ks2 = 0; ks2 < 2; ++ks2) {
#pragma unroll
      for (int ct = 0; ct < 4; ++ct) {
        bf16x8 bh = *(const bf16x8*)&BsH[ct * 16 + m16][ks2 * 32 + quad * 8];
        bf16x8 bl = *(const bf16x8*)&BsL[ct * 16 + m16][ks2 * 32 + quad * 8];
#pragma unroll
        for (int rt = 0; rt < 2; ++rt) {
          acc[rt][ct] = __builtin_amdgcn_mfma_f32_16x16x32_bf16(ah[rt][ks2], bh, acc[rt][ct], 0, 0, 0);
          acc[rt][ct] = __builtin_amdgcn_mfma_f32_16x16x32_bf16(ah[rt][ks2], bl, acc[rt][ct], 0, 0, 0);
          acc[rt][ct] = __builtin_amdgcn_mfma_f32_16x16x32_bf16(al[rt][ks2], bh, acc[rt][ct], 0, 0, 0);
        }
      }
    }
  }

  float cys[4], cqs[4];
#pragma unroll
  for (int ct = 0; ct < 4; ++ct) {
    int col = col0 + ct * 16 + m16;
    float bcol = bias[col];
    float cy = 0.f, cq = 0.f;
#pragma unroll
    for (int rt = 0; rt < 2; ++rt) {
#pragma unroll
      for (int rg = 0; rg < 4; ++rg) {
        int row = row0 + rt * 16 + quad * 4 + rg;
        float v = acc[rt][ct][rg] + bcol;
        Y[(u64)row * ldy + col] = v;
        cy += v; cq += v * v;
      }
    }
    cys[ct] = cy; cqs[ct] = cq;
  }
#pragma unroll
  for (int ct = 0; ct < 4; ++ct) {
    cys[ct] += __shfl_xor(cys[ct], 16, 64); cys[ct] += __shfl_xor(cys[ct], 32, 64);
    cqs[ct] += __shfl_xor(cqs[ct], 16, 64); cqs[ct] += __shfl_xor(cqs[ct], 32, 64);
  }
  __syncthreads();
  if (tid < 64) { redY[tid] = 0.f; redQ[tid] = 0.f; }
  __syncthreads();
  if (quad == 0) {
#pragma unroll
    for (int ct = 0; ct < 4; ++ct) {
      atomicAdd(&redY[ct * 16 + m16], cys[ct]);
      atomicAdd(&redQ[ct * 16 + m16], cqs[ct]);
    }
  }
  __syncthreads();
  if (tid < 64) {
    atomicAdd(&sum[col0 + tid], redY[tid]);
    atomicAdd(&sq[col0 + tid], redQ[tid]);
  }
}

// ------- lin GEMM: bf16 A plane x bf16 W (single plane), 128-col, fp16 out -----
__global__ __launch_bounds__(256) void mfma_gemm_ps_kernel(
    const unsigned short* __restrict__ Ahi,
    const unsigned short* __restrict__ Wt_hi,
    const float* __restrict__ bias,
    _Float16* __restrict__ Y,
    float* __restrict__ sum, float* __restrict__ sq,
    int K, int N)
{
  __shared__ unsigned short BsH[128][72];
  __shared__ float redY[128];
  __shared__ float redQ[128];
  int tid = threadIdx.x;
  int lane = tid & 63, wid = tid >> 6;
  int row0 = blockIdx.y * 128 + wid * 32;
  int col0 = blockIdx.x * 128;
  int m16 = lane & 15, quad = lane >> 4;

  f32x4 acc[2][8];
#pragma unroll
  for (int i = 0; i < 2; ++i)
#pragma unroll
    for (int j = 0; j < 8; ++j) acc[i][j] = {0.f, 0.f, 0.f, 0.f};

  for (int k0 = 0; k0 < K; k0 += 64) {
    if (k0) __syncthreads();
#pragma unroll
    for (int it = 0; it < 4; ++it) {
      int slot = tid + it * 256;
      int n = slot >> 3, cg = slot & 7;
      u64 off = (u64)(col0 + n) * K + k0 + cg * 8;
      *(uint4*)&BsH[n][cg * 8] = *(const uint4*)(Wt_hi + off);
    }
    __syncthreads();

    bf16x8 ah[2][2];
#pragma unroll
    for (int rt = 0; rt < 2; ++rt) {
      int grow = row0 + rt * 16 + m16;
      u64 abase = (u64)grow * K + k0 + quad * 8;
#pragma unroll
      for (int ks2 = 0; ks2 < 2; ++ks2)
        ah[rt][ks2] = *(const bf16x8*)(Ahi + abase + ks2 * 32);
    }

#pragma unroll
    for (int ks2 = 0; ks2 < 2; ++ks2) {
#pragma unroll
      for (int ct = 0; ct < 8; ++ct) {
        bf16x8 bh = *(const bf16x8*)&BsH[ct * 16 + m16][ks2 * 32 + quad * 8];
#pragma unroll
        for (int rt = 0; rt < 2; ++rt) {
          acc[rt][ct] = __builtin_amdgcn_mfma_f32_16x16x32_bf16(ah[rt][ks2], bh, acc[rt][ct], 0, 0, 0);
        }
      }
    }
  }

  float cys[8], cqs[8];
#pragma unroll
  for (int ct = 0; ct < 8; ++ct) {
    int col = col0 + ct * 16 + m16;
    float bcol = bias[col];
    float cy = 0.f, cq = 0.f;
#pragma unroll
    for (int rt = 0; rt < 2; ++rt) {
#pragma unroll
      for (int rg = 0; rg < 4; ++rg) {
        int row = row0 + rt * 16 + quad * 4 + rg;
        float v = acc[rt][ct][rg] + bcol;
        Y[(u64)row * N + col] = (_Float16)v;
        cy += v; cq += v * v;
      }
    }
    cys[ct] = cy; cqs[ct] = cq;
  }
#pragma unroll
  for (int ct = 0; ct < 8; ++ct) {
    cys[ct] += __shfl_xor(cys[ct], 16, 64); cys[ct] += __shfl_xor(cys[ct], 32, 64);
    cqs[ct] += __shfl_xor(cqs[ct], 16, 64); cqs[ct] += __shfl_xor(cqs[ct], 32, 64);
  }
  __syncthreads();
  if (tid < 128) { redY[tid] = 0.f; redQ[tid] = 0.f; }
  __syncthreads();
  if (quad == 0) {
#pragma unroll
    for (int ct = 0; ct < 8; ++ct) {
      atomicAdd(&redY[ct * 16 + m16], cys[ct]);
      atomicAdd(&redQ[ct * 16 + m16], cqs[ct]);
    }
  }
  __syncthreads();
  if (tid < 128) {
    atomicAdd(&sum[col0 + tid], redY[tid]);
    atomicAdd(&sq[col0 + tid], redQ[tid]);
  }
}

// ---------------- head GEMM: M=64 rows, row per block; optional pre-BN ----------
__global__ __launch_bounds__(256) void head_gemm_kernel(
    const float* __restrict__ A, int K,
    const float* __restrict__ pSum, const float* __restrict__ pSq, float invcnt,
    const float* __restrict__ g, const float* __restrict__ be,
    const float* __restrict__ W, const float* __restrict__ bias,
    float* __restrict__ Y, int Cout,
    float* __restrict__ sum, float* __restrict__ sq)
{
  __shared__ float As[2048];
  int r = blockIdx.y;
  int tid = threadIdx.x;
  for (int k = tid; k < K; k += 256) {
    float v = A[(u64)r * K + k];
    if (pSum) {
      float s, b;
      bn_coeff(pSum, pSq, invcnt, g, be, k, s, b);
      v = fmaxf(fmaf(v, s, b), 0.f);
    }
    As[k] = v;
  }
  __syncthreads();
  int c = blockIdx.x * 256 + tid;
  if (c >= Cout) return;
  float a0 = 0.f, a1 = 0.f, a2 = 0.f, a3 = 0.f;
  for (int k = 0; k < K; k += 4) {
    a0 = fmaf(As[k + 0], W[(u64)(k + 0) * Cout + c], a0);
    a1 = fmaf(As[k + 1], W[(u64)(k + 1) * Cout + c], a1);
    a2 = fmaf(As[k + 2], W[(u64)(k + 2) * Cout + c], a2);
    a3 = fmaf(As[k + 3], W[(u64)(k + 3) * Cout + c], a3);
  }
  float acc = bias[c] + ((a0 + a1) + (a2 + a3));
  Y[(u64)r * Cout + c] = acc;
  if (sum) { atomicAdd(&sum[c], acc); atomicAdd(&sq[c], acc * acc); }
}

// -------- stats-only pass: t = relu(z*s1+b1), accumulate sum/sq of t -----------
__global__ __launch_bounds__(256) void act_stats_kernel(
    const float* __restrict__ z,
    const float* __restrict__ pSum, const float* __restrict__ pSq, float invcnt,
    const float* __restrict__ g, const float* __restrict__ be,
    float* __restrict__ sum, float* __restrict__ sq, int total, int cmask)
{
  __shared__ float red[256];
  int tid = threadIdx.x;
  int c = tid & cmask;
  float s, b;
  bn_coeff(pSum, pSq, invcnt, g, be, c, s, b);
  float ls = 0.f, lq = 0.f;
  for (int idx = blockIdx.x * 256 + tid; idx < total; idx += gridDim.x * 256) {
    float v = fmaxf(fmaf(z[idx], s, b), 0.f);
    ls += v; lq += v * v;
  }
  red[tid] = ls; __syncthreads();
  if (tid <= cmask) {
    float t = 0.f;
    for (int k = tid; k < 256; k += cmask + 1) t += red[k];
    atomicAdd(&sum[tid], t);
  }
  __syncthreads();
  red[tid] = lq; __syncthreads();
  if (tid <= cmask) {
    float t = 0.f;
    for (int k = tid; k < 256; k += cmask + 1) t += red[k];
    atomicAdd(&sq[tid], t);
  }
}

// ------ recompute t from z, apply outer affine, write h + bf16 hi plane --------
__global__ __launch_bounds__(256) void apply_bn_kernel(
    const float* __restrict__ z,
    const float* __restrict__ iSum, const float* __restrict__ iSq, float invcnt,
    const float* __restrict__ ig, const float* __restrict__ ibe,
    const float* __restrict__ oSum, const float* __restrict__ oSq,
    const float* __restrict__ og, const float* __restrict__ obe,
    float* __restrict__ h, unsigned short* __restrict__ hspH,
    int off, int cshift, int cmask, int total)
{
  int tid = threadIdx.x;
  int c = tid & cmask;
  float s1, b1, s2, b2;
  bn_coeff(iSum, iSq, invcnt, ig, ibe, c, s1, b1);
  bn_coeff(oSum, oSq, invcnt, og, obe, c, s2, b2);
  for (int idx = blockIdx.x * 256 + tid; idx < total; idx += gridDim.x * 256) {
    int r = idx >> cshift;
    float t = fmaxf(fmaf(z[idx], s1, b1), 0.f);
    float v = fmaf(t, s2, b2);
    u64 o = (u64)r * 512 + off + (idx & cmask);
    h[o] = v;
    hspH[o] = f2bf(v);
  }
}

// ------------- EdgeConv segment_max via CSR + bf16 hi plane ----------------
__global__ __launch_bounds__(256) void x0max_csr_kernel(
    const _Float16* __restrict__ y3,
    const float* __restrict__ pSum, const float* __restrict__ pSq, float invcnt,
    const float* __restrict__ g, const float* __restrict__ be,
    const int* __restrict__ row_ptr, float* __restrict__ h,
    unsigned short* __restrict__ hspH)
{
  int n = blockIdx.x * 4 + (threadIdx.x >> 6);
  int lane = threadIdx.x & 63;
  int b = row_ptr[n], e = row_ptr[n + 1];
  float s, bb;
  bn_coeff(pSum, pSq, invcnt, g, be, lane, s, bb);
  float mx = 0.f;
  for (int i = b; i < e; ++i) {
    float v = fmaxf(fmaf((float)y3[(u64)i * 64 + lane], s, bb), 0.f);
    mx = fmaxf(mx, v);
  }
  u64 o = (u64)n * 512 + lane;
  h[o] = mx;
  hspH[o] = f2bf(mx);
}

// ------------- GIN neighbor-sum via CSR gather (wave per node, coalesced) ------
template<int COLS>
__global__ __launch_bounds__(256) void gather_add_kernel(
    const float* __restrict__ h, int off,
    const int* __restrict__ row_ptr, const int* __restrict__ ssrc,
    float* __restrict__ agg)
{
  int n = blockIdx.x * 4 + (threadIdx.x >> 6);
  int lane = threadIdx.x & 63;
  int b = row_ptr[n], e = row_ptr[n + 1];
  float a0 = 0.f, a1 = 0.f;
  for (int i = b; i < e; ++i) {
    const float* p = h + (u64)ssrc[i] * 512 + off + lane;
    a0 += p[0];
    if (COLS > 64) a1 += p[64];
  }
  float* q = agg + (u64)n * COLS + lane;
  q[0] = a0;
  if (COLS > 64) q[64] = a1;
}

// ---------------- graph pooling (hl fp16) ----------------
__global__ __launch_bounds__(256) void pool_kernel(
    const _Float16* __restrict__ hl,
    const float* __restrict__ pSum, const float* __restrict__ pSq, float invcnt,
    const float* __restrict__ g, const float* __restrict__ be,
    float* __restrict__ o)
{
  int gidx = blockIdx.x;
  int c = blockIdx.y * 256 + threadIdx.x;
  float s, b;
  bn_coeff(pSum, pSq, invcnt, g, be, c, s, b);
  const _Float16* p = hl + (u64)gidx * NPG * 1024 + c;
  float mx = 0.f, sm = 0.f;
  for (int n = 0; n < NPG; ++n) {
    float v = fmaxf(fmaf((float)p[(u64)n * 1024], s, b), 0.f);
    mx = fmaxf(mx, v);
    sm += v;
  }
  o[gidx * 2048 + c] = mx;
  o[gidx * 2048 + 1024 + c] = sm * (1.f / NPG);
}

// ---------------- log_softmax over 40 cols ----------------
__global__ void lsm_kernel(const float* __restrict__ logits, float* __restrict__ out)
{
  int r = blockIdx.x;
  int c = threadIdx.x;
  float v = (c < 40) ? logits[r * 40 + c] : -INFINITY;
  float m = v;
  for (int off = 32; off; off >>= 1) m = fmaxf(m, __shfl_xor(m, off, 64));
  float e = (c < 40) ? expf(v - m) : 0.f;
  float s = e;
  for (int off = 32; off; off >>= 1) s += __shfl_xor(s, off, 64);
  if (c < 40) out[r * 40 + c] = (v - m) - logf(s);
}

extern "C" void kernel_launch(void* const* d_in, const int* in_sizes, int n_in,
                              void* d_out, int out_size, void* d_ws, size_t ws_size,
                              hipStream_t stream)
{
  const float* x    = (const float*)d_in[0];
  const int*   ei   = (const int*)d_in[1];
  const int*   srcI = ei;
  const int*   dstI = ei + E_EDGES;
  const float* ecW1 = (const float*)d_in[3];
  const float* ecb1 = (const float*)d_in[4];
  const float* ecg1 = (const float*)d_in[5];
  const float* ecbe1= (const float*)d_in[6];
  const float* ecW2 = (const float*)d_in[7];
  const float* ecb2 = (const float*)d_in[8];
  const float* ecg2 = (const float*)d_in[9];
  const float* ecbe2= (const float*)d_in[10];
  const float* ecW3 = (const float*)d_in[11];
  const float* ecb3 = (const float*)d_in[12];
  const float* ecg3 = (const float*)d_in[13];
  const float* ecbe3= (const float*)d_in[14];
  const float* g1W  = (const float*)d_in[15];
  const float* g1b  = (const float*)d_in[16];
  const float* g1g  = (const float*)d_in[17];
  const float* g1be = (const float*)d_in[18];
  const float* g2W  = (const float*)d_in[19];
  const float* g2b  = (const float*)d_in[20];
  const float* g2g  = (const float*)d_in[21];
  const float* g2be = (const float*)d_in[22];
  const float* g3W  = (const float*)d_in[23];
  const float* g3b  = (const float*)d_in[24];
  const float* g3g  = (const float*)d_in[25];
  const float* g3be = (const float*)d_in[26];
  const float* bn1g = (const float*)d_in[27];
  const float* bn1be= (const float*)d_in[28];
  const float* bn2g = (const float*)d_in[29];
  const float* bn2be= (const float*)d_in[30];
  const float* bn3g = (const float*)d_in[31];
  const float* bn3be= (const float*)d_in[32];
  const float* linW = (const float*)d_in[33];
  const float* linb = (const float*)d_in[34];
  const float* ling = (const float*)d_in[35];
  const float* linbe= (const float*)d_in[36];
  const float* h1W  = (const float*)d_in[37];
  const float* h1b  = (const float*)d_in[38];
  const float* h1g  = (const float*)d_in[39];
  const float* h1be = (const float*)d_in[40];
  const float* h2W  = (const float*)d_in[41];
  const float* h2b  = (const float*)d_in[42];
  const float* h2g  = (const float*)d_in[43];
  const float* h2be = (const float*)d_in[44];
  const float* outW = (const float*)d_in[45];
  const float* outb = (const float*)d_in[46];

  char* ws = (char*)d_ws;
  const size_t MB = 1024ull * 1024ull;
  // ---- stats area [0, 96 KiB): 12 slots of (sum 4K + sq 4K) ----
#define S(i) ((float*)(ws + (size_t)(i) * 8192))
#define Q(i) ((float*)(ws + (size_t)(i) * 8192 + 4096))
  // ---- small buffers [128 KiB, 1 MiB) ----
  float* o_     = (float*)(ws + 131072);
  float* yh1    = (float*)(ws + 131072 + 524288);
  float* yh2    = (float*)(ws + 131072 + 524288 + 131072);
  float* logits = (float*)(ws + 131072 + 524288 + 131072 + 65536);
  // ---- weights [1 MiB, 4 MiB) ----
  _Float16* ec2WtH16 = (_Float16*)(ws + 1 * MB);
  _Float16* ec2WtL16 = (_Float16*)(ws + 1 * MB + 8192);
  _Float16* ec3WtH16 = (_Float16*)(ws + 1 * MB + 16384);
  _Float16* ec3WtL16 = (_Float16*)(ws + 1 * MB + 24576);
  unsigned short* g1WtH  = (unsigned short*)(ws + 1 * MB + 32768);
  unsigned short* g1WtL  = (unsigned short*)(ws + 1 * MB + 40960);
  unsigned short* g2WtH  = (unsigned short*)(ws + 1 * MB + 49152);
  unsigned short* g2WtL  = (unsigned short*)(ws + 1 * MB + 65536);
  unsigned short* g3WtH  = (unsigned short*)(ws + 1 * MB + 81920);
  unsigned short* g3WtL  = (unsigned short*)(ws + 1 * MB + 147456);
  unsigned short* linWtH = (unsigned short*)(ws + 1 * MB + 212992);
  unsigned short* linWtL = (unsigned short*)(ws + 1 * MB + 212992 + 1048576);
  // ---- big region [4 MiB, 132 MiB) ----
  _Float16* y  = (_Float16*)(ws + 4 * MB);     // [E,64] fp16 (dead after x0max)
  float* ytemp = (float*)(ws + 4 * MB);        // GIN z, <=32 MiB
  float* agg   = (float*)(ws + 36 * MB);       // GIN agg, <=32 MiB
  unsigned short* hspH = (unsigned short*)(ws + 68 * MB);   // [N,512] bf16 hi
  _Float16* hl = (_Float16*)(ws + 4 * MB);     // [N,1024] fp16 during lin/pool
  // ---- h region [132 MiB, 196 MiB): [N,512] fp32 ----
  float* h = (float*)(ws + 132 * MB);
  // ---- CSR region [196 MiB, 201 MiB) ----
  int* row_ptr = (int*)(ws + 196 * MB);
  int* cnt     = (int*)(ws + 196 * MB + 140000);
  int* ssrc    = (int*)(ws + 197 * MB);
  int* sdst    = (int*)(ws + 199 * MB);

  const float invE = 1.f / E_EDGES;
  const float invN = 1.f / N_NODES;
  const float invB = 1.f / N_GRAPHS;

  hipMemsetAsync((void*)ws, 0, 12 * 8192, stream);
  hipMemsetAsync((void*)cnt, 0, 32768 * 4, stream);

  // ---------------- CSR build ----------------
  hist_kernel<<<2048, 256, 0, stream>>>(dstI, cnt);
  scan_kernel<<<1, 1024, 0, stream>>>(cnt, row_ptr);
  fill_kernel<<<2048, 256, 0, stream>>>(srcI, dstI, cnt, ssrc, sdst);

  // ---------------- weight prep ----------------
  wt16_all_kernel<<<32, 256, 0, stream>>>(ecW2, ec2WtH16, ec2WtL16, ecW3, ec3WtH16, ec3WtL16);
  wt_all_kernel<<<2224, 256, 0, stream>>>(g1W, g1WtH, g1WtL, g2W, g2WtH, g2WtL,
                                          g3W, g3WtH, g3WtL, linW, linWtH, linWtL);

  // ---------------- EdgeConv (fp16 y, in-place) ----------------
  ec1_kernel<<<1024, 256, 0, stream>>>(x, ssrc, sdst, ecW1, ecb1, y, S(0), Q(0));
  mfma_gemm_f16_kernel<<<E_EDGES / 128, 256, 0, stream>>>(
      y, S(0), Q(0), invE, ecg1, ecbe1, ec2WtH16, ec2WtL16, ecb2, y, S(1), Q(1));
  mfma_gemm_f16_kernel<<<E_EDGES / 128, 256, 0, stream>>>(
      y, S(1), Q(1), invE, ecg2, ecbe2, ec3WtH16, ec3WtL16, ecb3, y, S(2), Q(2));
  x0max_csr_kernel<<<N_NODES / 4, 256, 0, stream>>>(
      y, S(2), Q(2), invE, ecg3, ecbe3, row_ptr, h, hspH);

  // ---------------- GIN 1 ----------------
  gather_add_kernel<64><<<N_NODES / 4, 256, 0, stream>>>(h, 0, row_ptr, ssrc, agg);
  mfma_gemm_kernel<<<dim3(1, N_NODES / 128), 256, 0, stream>>>(
      h, 512, agg, 64, g1WtH, g1WtL, g1b, ytemp, 64, S(3), Q(3), N_NODES, 64, 64);
  act_stats_kernel<<<512, 256, 0, stream>>>(
      ytemp, S(3), Q(3), invN, g1g, g1be, S(4), Q(4), N_NODES * 64, 63);
  apply_bn_kernel<<<1024, 256, 0, stream>>>(
      ytemp, S(3), Q(3), invN, g1g, g1be, S(4), Q(4), bn1g, bn1be,
      h, hspH, 64, 6, 63, N_NODES * 64);

  // ---------------- GIN 2 ----------------
  gather_add_kernel<64><<<N_NODES / 4, 256, 0, stream>>>(h, 64, row_ptr, ssrc, agg);
  mfma_gemm_kernel<<<dim3(2, N_NODES / 128), 256, 0, stream>>>(
      h + 64, 512, agg, 64, g2WtH, g2WtL, g2b, ytemp, 128, S(5), Q(5), N_NODES, 64, 128);
  act_stats_kernel<<<512, 256, 0, stream>>>(
      ytemp, S(5), Q(5), invN, g2g, g2be, S(6), Q(6), N_NODES * 128, 127);
  apply_bn_kernel<<<1024, 256, 0, stream>>>(
      ytemp, S(5), Q(5), invN, g2g, g2be, S(6), Q(6), bn2g, bn2be,
      h, hspH, 128, 7, 127, N_NODES * 128);

  // ---------------- GIN 3 ----------------
  gather_add_kernel<128><<<N_NODES / 4, 256, 0, stream>>>(h, 128, row_ptr, ssrc, agg);
  mfma_gemm_kernel<<<dim3(4, N_NODES / 128), 256, 0, stream>>>(
      h + 128, 512, agg, 128, g3WtH, g3WtL, g3b, ytemp, 256, S(7), Q(7), N_NODES, 128, 256);
  act_stats_kernel<<<512, 256, 0, stream>>>(
      ytemp, S(7), Q(7), invN, g3g, g3be, S(8), Q(8), N_NODES * 256, 255);
  apply_bn_kernel<<<1024, 256, 0, stream>>>(
      ytemp, S(7), Q(7), invN, g3g, g3be, S(8), Q(8), bn3g, bn3be,
      h, hspH, 256, 8, 255, N_NODES * 256);

  // ---------------- lin (single-plane W) + pool ----------------
  mfma_gemm_ps_kernel<<<dim3(8, N_NODES / 128), 256, 0, stream>>>(
      hspH, linWtH, linb, hl, S(9), Q(9), 512, 1024);
  pool_kernel<<<dim3(64, 4), 256, 0, stream>>>(hl, S(9), Q(9), invN, ling, linbe, o_);

  // ---------------- head ----------------
  head_gemm_kernel<<<dim3(2, 64), 256, 0, stream>>>(
      o_, 2048, nullptr, nullptr, 0.f, nullptr, nullptr, h1W, h1b, yh1, 512, S(10), Q(10));
  head_gemm_kernel<<<dim3(1, 64), 256, 0, stream>>>(
      yh1, 512, S(10), Q(10), invB, h1g, h1be, h2W, h2b, yh2, 256, S(11), Q(11));
  head_gemm_kernel<<<dim3(1, 64), 256, 0, stream>>>(
      yh2, 256, S(11), Q(11), invB, h2g, h2be, outW, outb, logits, 40, nullptr, nullptr);
  lsm_kernel<<<64, 64, 0, stream>>>(logits, (float*)d_out);
#undef S
#undef Q
}

// Round 18
// 1041.020 us; speedup vs baseline: 1.1223x; 1.0713x over previous
//
#include <hip/hip_runtime.h>
#include <math.h>

#define E_EDGES 524288
#define N_NODES 32768
#define N_GRAPHS 64
#define NPG 512

typedef unsigned long long u64;
using bf16x8 = __attribute__((ext_vector_type(8))) short;
using f16x8  = __attribute__((ext_vector_type(8))) _Float16;
using f32x4  = __attribute__((ext_vector_type(4))) float;

__device__ __forceinline__ unsigned short f2bf(float f) {
  unsigned int u = __float_as_uint(f);
  u += 0x7FFFu + ((u >> 16) & 1u);
  return (unsigned short)(u >> 16);
}
__device__ __forceinline__ float b2f(unsigned short s) {
  return __uint_as_float(((unsigned int)s) << 16);
}
// BN coeff from raw sums: s = g/sqrt(var+eps), b = be - m*s
__device__ __forceinline__ void bn_coeff(
    const float* __restrict__ pSum, const float* __restrict__ pSq, float invcnt,
    const float* __restrict__ g, const float* __restrict__ be, int c,
    float& s, float& b)
{
  float m = pSum[c] * invcnt;
  float v = pSq[c] * invcnt - m * m;
  float is = rsqrtf(v + 1e-5f);
  s = g[c] * is;
  b = fmaf(-m, s, be[c]);
}

// ================= CSR build (dst-sorted edge permutation) =================
__global__ __launch_bounds__(256) void hist_kernel(
    const int* __restrict__ dst, int* __restrict__ cnt)
{
  int e = blockIdx.x * 256 + threadIdx.x;
  atomicAdd(&cnt[dst[e]], 1);
}

__global__ __launch_bounds__(1024) void scan_kernel(
    int* __restrict__ cnt, int* __restrict__ row_ptr)
{
  __shared__ int s[1024];
  int t = threadIdx.x;
  int base = t * 32;
  int local[32];
  int acc = 0;
#pragma unroll
  for (int i = 0; i < 32; ++i) { local[i] = acc; acc += cnt[base + i]; }
  s[t] = acc;
  __syncthreads();
  for (int d = 1; d < 1024; d <<= 1) {
    int v = (t >= d) ? s[t - d] : 0;
    __syncthreads();
    s[t] += v;
    __syncthreads();
  }
  int off = t ? s[t - 1] : 0;
#pragma unroll
  for (int i = 0; i < 32; ++i) {
    int p = off + local[i];
    row_ptr[base + i] = p;
    cnt[base + i] = p;
  }
  if (t == 1023) row_ptr[32768] = off + acc;
}

__global__ __launch_bounds__(256) void fill_kernel(
    const int* __restrict__ src, const int* __restrict__ dst,
    int* __restrict__ pos, int* __restrict__ ssrc, int* __restrict__ sdst)
{
  int e = blockIdx.x * 256 + threadIdx.x;
  int d = dst[e];
  int p = atomicAdd(&pos[d], 1);
  ssrc[p] = src[e];
  sdst[p] = d;
}

// ---------------- merged weight transpose kernels ----------------
__global__ __launch_bounds__(256) void wt16_all_kernel(
    const float* __restrict__ W2, _Float16* __restrict__ H2, _Float16* __restrict__ L2,
    const float* __restrict__ W3, _Float16* __restrict__ H3, _Float16* __restrict__ L3)
{
  int b = blockIdx.x;
  const float* W = (b < 16) ? W2 : W3;
  _Float16* H = (b < 16) ? H2 : H3;
  _Float16* L = (b < 16) ? L2 : L3;
  int idx = (b & 15) * 256 + threadIdx.x;
  int n = idx >> 6, k = idx & 63;
  float w = W[k * 64 + n];
  _Float16 hi = (_Float16)w;
  H[idx] = hi;
  L[idx] = (_Float16)(w - (float)hi);
}

__global__ __launch_bounds__(256) void wt_all_kernel(
    const float* __restrict__ g1W, unsigned short* __restrict__ g1H, unsigned short* __restrict__ g1L,
    const float* __restrict__ g2W, unsigned short* __restrict__ g2H, unsigned short* __restrict__ g2L,
    const float* __restrict__ g3W, unsigned short* __restrict__ g3H, unsigned short* __restrict__ g3L,
    const float* __restrict__ lW,  unsigned short* __restrict__ lH,  unsigned short* __restrict__ lL)
{
  int b = blockIdx.x;
  const float* W; unsigned short *H, *L; int kshift, N, base;
  if (b < 16)       { W = g1W; H = g1H; L = g1L; kshift = 6; N = 64;   base = 0; }
  else if (b < 48)  { W = g2W; H = g2H; L = g2L; kshift = 6; N = 128;  base = 16; }
  else if (b < 176) { W = g3W; H = g3H; L = g3L; kshift = 7; N = 256;  base = 48; }
  else              { W = lW;  H = lH;  L = lL;  kshift = 9; N = 1024; base = 176; }
  int idx = (b - base) * 256 + threadIdx.x;
  int n = idx >> kshift;
  int k = idx & ((1 << kshift) - 1);
  float w = W[(u64)k * N + n];
  unsigned short hi = f2bf(w);
  H[idx] = hi;
  L[idx] = f2bf(w - b2f(hi));
}

// ----- EdgeConv layer 1: 4-edge ILP per wave iteration, fp16 out + stats -------
__global__ __launch_bounds__(256) void ec1_kernel(
    const float* __restrict__ x, const int* __restrict__ src, const int* __restrict__ dst,
    const float* __restrict__ W, const float* __restrict__ b,
    _Float16* __restrict__ y, float* __restrict__ sum, float* __restrict__ sq)
{
  __shared__ float Ws[512];
  __shared__ float bs[64];
  __shared__ float red[256];
  int tid = threadIdx.x;
  for (int i = tid; i < 512; i += 256) Ws[i] = W[i];
  if (tid < 64) bs[tid] = b[tid];
  __syncthreads();
  int c = tid & 63;
  int eslot = tid >> 6;
  float ls = 0.f, lq = 0.f;
  const float4* x4 = (const float4*)x;
  int stride = gridDim.x * 16;
  for (int e = blockIdx.x * 16 + eslot * 4; e < E_EDGES; e += stride) {
    int s0 = src[e],     s1 = src[e + 1], s2 = src[e + 2], s3 = src[e + 3];
    int d0 = dst[e],     d1 = dst[e + 1], d2 = dst[e + 2], d3 = dst[e + 3];
    float4 xi0 = x4[d0], xj0 = x4[s0];
    float4 xi1 = x4[d1], xj1 = x4[s1];
    float4 xi2 = x4[d2], xj2 = x4[s2];
    float4 xi3 = x4[d3], xj3 = x4[s3];
#pragma unroll
    for (int g = 0; g < 4; ++g) {
      float4 xi = (g == 0) ? xi0 : (g == 1) ? xi1 : (g == 2) ? xi2 : xi3;
      float4 xj = (g == 0) ? xj0 : (g == 1) ? xj1 : (g == 2) ? xj2 : xj3;
      float m[8] = {xi.x, xi.y, xi.z, xi.w,
                    xj.x - xi.x, xj.y - xi.y, xj.z - xi.z, xj.w - xi.w};
      float acc = bs[c];
#pragma unroll
      for (int k = 0; k < 8; ++k) acc = fmaf(m[k], Ws[k * 64 + c], acc);
      y[(u64)(e + g) * 64 + c] = (_Float16)acc;
      ls += acc; lq += acc * acc;
    }
  }
  red[tid] = ls; __syncthreads();
  if (tid < 64) atomicAdd(&sum[tid], red[tid] + red[tid + 64] + red[tid + 128] + red[tid + 192]);
  __syncthreads();
  red[tid] = lq; __syncthreads();
  if (tid < 64) atomicAdd(&sq[tid], red[tid] + red[tid + 64] + red[tid + 128] + red[tid + 192]);
}

// -------- fp16 MFMA GEMM for EC layers: Y = relu(A*s+b) @ Wt^T + bias ----------
__global__ __launch_bounds__(256) void mfma_gemm_f16_kernel(
    const _Float16* A,
    const float* __restrict__ pSum, const float* __restrict__ pSq, float invcnt,
    const float* __restrict__ g, const float* __restrict__ be,
    const _Float16* __restrict__ WtH, const _Float16* __restrict__ WtL,
    const float* __restrict__ bias,
    _Float16* Y,
    float* __restrict__ sum, float* __restrict__ sq)
{
  __shared__ _Float16 BsH[64][72];
  __shared__ _Float16 BsL[64][72];
  __shared__ _Float16 scL[64];
  __shared__ _Float16 shL[64];
  __shared__ float redY[64];
  __shared__ float redQ[64];
  int tid = threadIdx.x;
  int lane = tid & 63, wid = tid >> 6;
  int row0 = blockIdx.x * 128 + wid * 32;
  int m16 = lane & 15, quad = lane >> 4;

#pragma unroll
  for (int it = 0; it < 2; ++it) {
    int slot = tid + it * 256;
    int n = slot >> 3, cg = slot & 7;
    *(uint4*)&BsH[n][cg * 8] = *(const uint4*)(WtH + n * 64 + cg * 8);
    *(uint4*)&BsL[n][cg * 8] = *(const uint4*)(WtL + n * 64 + cg * 8);
  }
  if (tid < 64) {
    float s, b;
    bn_coeff(pSum, pSq, invcnt, g, be, tid, s, b);
    scL[tid] = (_Float16)s;
    shL[tid] = (_Float16)b;
  }
  __syncthreads();

  f16x8 af[2][2];
#pragma unroll
  for (int rt = 0; rt < 2; ++rt) {
    int grow = row0 + rt * 16 + m16;
    const _Float16* ap = A + (u64)grow * 64 + quad * 8;
#pragma unroll
    for (int ks2 = 0; ks2 < 2; ++ks2) {
      f16x8 a = *(const f16x8*)(ap + ks2 * 32);
      f16x8 s8 = *(const f16x8*)&scL[quad * 8 + ks2 * 32];
      f16x8 h8 = *(const f16x8*)&shL[quad * 8 + ks2 * 32];
      a = a * s8 + h8;
#pragma unroll
      for (int j = 0; j < 8; ++j) a[j] = (a[j] > (_Float16)0) ? a[j] : (_Float16)0;
      af[rt][ks2] = a;
    }
  }

  f32x4 acc[2][4];
#pragma unroll
  for (int i = 0; i < 2; ++i)
#pragma unroll
    for (int j = 0; j < 4; ++j) acc[i][j] = {0.f, 0.f, 0.f, 0.f};

#pragma unroll
  for (int ks2 = 0; ks2 < 2; ++ks2) {
#pragma unroll
    for (int ct = 0; ct < 4; ++ct) {
      f16x8 bh = *(const f16x8*)&BsH[ct * 16 + m16][ks2 * 32 + quad * 8];
      f16x8 bl = *(const f16x8*)&BsL[ct * 16 + m16][ks2 * 32 + quad * 8];
#pragma unroll
      for (int rt = 0; rt < 2; ++rt) {
        acc[rt][ct] = __builtin_amdgcn_mfma_f32_16x16x32_f16(af[rt][ks2], bh, acc[rt][ct], 0, 0, 0);
        acc[rt][ct] = __builtin_amdgcn_mfma_f32_16x16x32_f16(af[rt][ks2], bl, acc[rt][ct], 0, 0, 0);
      }
    }
  }

  float cys[4], cqs[4];
#pragma unroll
  for (int ct = 0; ct < 4; ++ct) {
    int col = ct * 16 + m16;
    float bcol = bias[col];
    float cy = 0.f, cq = 0.f;
#pragma unroll
    for (int rt = 0; rt < 2; ++rt) {
#pragma unroll
      for (int rg = 0; rg < 4; ++rg) {
        int row = row0 + rt * 16 + quad * 4 + rg;
        float v = acc[rt][ct][rg] + bcol;
        Y[(u64)row * 64 + col] = (_Float16)v;
        cy += v; cq += v * v;
      }
    }
    cys[ct] = cy; cqs[ct] = cq;
  }
#pragma unroll
  for (int ct = 0; ct < 4; ++ct) {
    cys[ct] += __shfl_xor(cys[ct], 16, 64); cys[ct] += __shfl_xor(cys[ct], 32, 64);
    cqs[ct] += __shfl_xor(cqs[ct], 16, 64); cqs[ct] += __shfl_xor(cqs[ct], 32, 64);
  }
  __syncthreads();
  if (tid < 64) { redY[tid] = 0.f; redQ[tid] = 0.f; }
  __syncthreads();
  if (quad == 0) {
#pragma unroll
    for (int ct = 0; ct < 4; ++ct) {
      atomicAdd(&redY[ct * 16 + m16], cys[ct]);
      atomicAdd(&redQ[ct * 16 + m16], cqs[ct]);
    }
  }
  __syncthreads();
  if (tid < 64) {
    atomicAdd(&sum[tid], redY[tid]);
    atomicAdd(&sq[tid], redQ[tid]);
  }
}

// ---------------- split-bf16 MFMA GEMM (fp32 A; gin layers) ----------------
__global__ __launch_bounds__(256) void mfma_gemm_kernel(
    const float* A, int lda,
    const float* __restrict__ Add, int ldadd,
    const unsigned short* __restrict__ Wt_hi, const unsigned short* __restrict__ Wt_lo,
    const float* __restrict__ bias,
    float* Y, int ldy,
    float* __restrict__ sum, float* __restrict__ sq,
    int M, int K, int N)
{
  __shared__ unsigned short BsH[64][72];
  __shared__ unsigned short BsL[64][72];
  __shared__ float redY[64];
  __shared__ float redQ[64];
  int tid = threadIdx.x;
  int lane = tid & 63, wid = tid >> 6;
  int row0 = blockIdx.y * 128 + wid * 32;
  int col0 = blockIdx.x * 64;
  int m16 = lane & 15, quad = lane >> 4;

  f32x4 acc[2][4];
#pragma unroll
  for (int i = 0; i < 2; ++i)
#pragma unroll
    for (int j = 0; j < 4; ++j) acc[i][j] = {0.f, 0.f, 0.f, 0.f};

  for (int k0 = 0; k0 < K; k0 += 64) {
    if (k0) __syncthreads();
#pragma unroll
    for (int it = 0; it < 2; ++it) {
      int slot = tid + it * 256;
      int n = slot >> 3, cg = slot & 7;
      u64 off = (u64)(col0 + n) * K + k0 + cg * 8;
      *(uint4*)&BsH[n][cg * 8] = *(const uint4*)(Wt_hi + off);
      *(uint4*)&BsL[n][cg * 8] = *(const uint4*)(Wt_lo + off);
    }
    __syncthreads();

    bf16x8 ah[2][2], al[2][2];
#pragma unroll
    for (int rt = 0; rt < 2; ++rt) {
      int grow = row0 + rt * 16 + m16;
      const float* ap = A + (u64)grow * lda + k0 + quad * 8;
      const float* addp = Add ? (Add + (u64)grow * ldadd + k0 + quad * 8) : nullptr;
#pragma unroll
      for (int ks2 = 0; ks2 < 2; ++ks2) {
        float4 v0 = *(const float4*)(ap + ks2 * 32);
        float4 v1 = *(const float4*)(ap + ks2 * 32 + 4);
        if (Add) {
          float4 a0 = *(const float4*)(addp + ks2 * 32);
          float4 a1 = *(const float4*)(addp + ks2 * 32 + 4);
          v0.x += a0.x; v0.y += a0.y; v0.z += a0.z; v0.w += a0.w;
          v1.x += a1.x; v1.y += a1.y; v1.z += a1.z; v1.w += a1.w;
        }
        float f[8] = {v0.x, v0.y, v0.z, v0.w, v1.x, v1.y, v1.z, v1.w};
        bf16x8 th, tl;
#pragma unroll
        for (int j = 0; j < 8; ++j) {
          unsigned short hi = f2bf(f[j]);
          th[j] = (short)hi;
          tl[j] = (short)f2bf(f[j] - b2f(hi));
        }
        ah[rt][ks2] = th;
        al[rt][ks2] = tl;
      }
    }

#pragma unroll
    for (int ks2 = 0; ks2 < 2; ++ks2) {
#pragma unroll
      for (int ct = 0; ct < 4; ++ct) {
        bf16x8 bh = *(const bf16x8*)&BsH[ct * 16 + m16][ks2 * 32 + quad * 8];
        bf16x8 bl = *(const bf16x8*)&BsL[ct * 16 + m16][ks2 * 32 + quad * 8];
#pragma unroll
        for (int rt = 0; rt < 2; ++rt) {
          acc[rt][ct] = __builtin_amdgcn_mfma_f32_16x16x32_bf16(ah[rt][ks2], bh, acc[rt][ct], 0, 0, 0);
          acc[rt][ct] = __builtin_amdgcn_mfma_f32_16x16x32_bf16(ah[rt][ks2], bl, acc[rt][ct], 0, 0, 0);
          acc[rt][ct] = __builtin_amdgcn_mfma_f32_16x16x32_bf16(al[rt][ks2], bh, acc[rt][ct], 0, 0, 0);
        }
      }
    }
  }

  float cys[4], cqs[4];
#pragma unroll
  for (int ct = 0; ct < 4; ++ct) {
    int col = col0 + ct * 16 + m16;
    float bcol = bias[col];
    float cy = 0.f, cq = 0.f;
#pragma unroll
    for (int rt = 0; rt < 2; ++rt) {
#pragma unroll
      for (int rg = 0; rg < 4; ++rg) {
        int row = row0 + rt * 16 + quad * 4 + rg;
        float v = acc[rt][ct][rg] + bcol;
        Y[(u64)row * ldy + col] = v;
        cy += v; cq += v * v;
      }
    }
    cys[ct] = cy; cqs[ct] = cq;
  }
#pragma unroll
  for (int ct = 0; ct < 4; ++ct) {
    cys[ct] += __shfl_xor(cys[ct], 16, 64); cys[ct] += __shfl_xor(cys[ct], 32, 64);
    cqs[ct] += __shfl_xor(cqs[ct], 16, 64); cqs[ct] += __shfl_xor(cqs[ct], 32, 64);
  }
  __syncthreads();
  if (tid < 64) { redY[tid] = 0.f; redQ[tid] = 0.f; }
  __syncthreads();
  if (quad == 0) {
#pragma unroll
    for (int ct = 0; ct < 4; ++ct) {
      atomicAdd(&redY[ct * 16 + m16], cys[ct]);
      atomicAdd(&redQ[ct * 16 + m16], cqs[ct]);
    }
  }
  __syncthreads();
  if (tid < 64) {
    atomicAdd(&sum[col0 + tid], redY[tid]);
    atomicAdd(&sq[col0 + tid], redQ[tid]);
  }
}

// ------- lin GEMM: bf16 A plane x bf16 W (single plane), 128-col, fp16 out -----
__global__ __launch_bounds__(256) void mfma_gemm_ps_kernel(
    const unsigned short* __restrict__ Ahi,
    const unsigned short* __restrict__ Wt_hi,
    const float* __restrict__ bias,
    _Float16* __restrict__ Y,
    float* __restrict__ sum, float* __restrict__ sq,
    int K, int N)
{
  __shared__ unsigned short BsH[128][72];
  __shared__ float redY[128];
  __shared__ float redQ[128];
  int tid = threadIdx.x;
  int lane = tid & 63, wid = tid >> 6;
  int row0 = blockIdx.y * 128 + wid * 32;
  int col0 = blockIdx.x * 128;
  int m16 = lane & 15, quad = lane >> 4;

  f32x4 acc[2][8];
#pragma unroll
  for (int i = 0; i < 2; ++i)
#pragma unroll
    for (int j = 0; j < 8; ++j) acc[i][j] = {0.f, 0.f, 0.f, 0.f};

  for (int k0 = 0; k0 < K; k0 += 64) {
    if (k0) __syncthreads();
#pragma unroll
    for (int it = 0; it < 4; ++it) {
      int slot = tid + it * 256;
      int n = slot >> 3, cg = slot & 7;
      u64 off = (u64)(col0 + n) * K + k0 + cg * 8;
      *(uint4*)&BsH[n][cg * 8] = *(const uint4*)(Wt_hi + off);
    }
    __syncthreads();

    bf16x8 ah[2][2];
#pragma unroll
    for (int rt = 0; rt < 2; ++rt) {
      int grow = row0 + rt * 16 + m16;
      u64 abase = (u64)grow * K + k0 + quad * 8;
#pragma unroll
      for (int ks2 = 0; ks2 < 2; ++ks2)
        ah[rt][ks2] = *(const bf16x8*)(Ahi + abase + ks2 * 32);
    }

#pragma unroll
    for (int ks2 = 0; ks2 < 2; ++ks2) {
#pragma unroll
      for (int ct = 0; ct < 8; ++ct) {
        bf16x8 bh = *(const bf16x8*)&BsH[ct * 16 + m16][ks2 * 32 + quad * 8];
#pragma unroll
        for (int rt = 0; rt < 2; ++rt) {
          acc[rt][ct] = __builtin_amdgcn_mfma_f32_16x16x32_bf16(ah[rt][ks2], bh, acc[rt][ct], 0, 0, 0);
        }
      }
    }
  }

  float cys[8], cqs[8];
#pragma unroll
  for (int ct = 0; ct < 8; ++ct) {
    int col = col0 + ct * 16 + m16;
    float bcol = bias[col];
    float cy = 0.f, cq = 0.f;
#pragma unroll
    for (int rt = 0; rt < 2; ++rt) {
#pragma unroll
      for (int rg = 0; rg < 4; ++rg) {
        int row = row0 + rt * 16 + quad * 4 + rg;
        float v = acc[rt][ct][rg] + bcol;
        Y[(u64)row * N + col] = (_Float16)v;
        cy += v; cq += v * v;
      }
    }
    cys[ct] = cy; cqs[ct] = cq;
  }
#pragma unroll
  for (int ct = 0; ct < 8; ++ct) {
    cys[ct] += __shfl_xor(cys[ct], 16, 64); cys[ct] += __shfl_xor(cys[ct], 32, 64);
    cqs[ct] += __shfl_xor(cqs[ct], 16, 64); cqs[ct] += __shfl_xor(cqs[ct], 32, 64);
  }
  __syncthreads();
  if (tid < 128) { redY[tid] = 0.f; redQ[tid] = 0.f; }
  __syncthreads();
  if (quad == 0) {
#pragma unroll
    for (int ct = 0; ct < 8; ++ct) {
      atomicAdd(&redY[ct * 16 + m16], cys[ct]);
      atomicAdd(&redQ[ct * 16 + m16], cqs[ct]);
    }
  }
  __syncthreads();
  if (tid < 128) {
    atomicAdd(&sum[col0 + tid], redY[tid]);
    atomicAdd(&sq[col0 + tid], redQ[tid]);
  }
}

// ---- head GEMM: K-split 4 ways; grid (ceil(Cout/64), 64 rows); 256 thr --------
__global__ __launch_bounds__(256) void head_gemm_kernel(
    const float* __restrict__ A, int K,
    const float* __restrict__ pSum, const float* __restrict__ pSq, float invcnt,
    const float* __restrict__ g, const float* __restrict__ be,
    const float* __restrict__ W, const float* __restrict__ bias,
    float* __restrict__ Y, int Cout,
    float* __restrict__ sum, float* __restrict__ sq)
{
  __shared__ float As[2048];
  __shared__ float part[4][64];
  int r = blockIdx.y;
  int tid = threadIdx.x;
  for (int k = tid; k < K; k += 256) {
    float v = A[(u64)r * K + k];
    if (pSum) {
      float s, b;
      bn_coeff(pSum, pSq, invcnt, g, be, k, s, b);
      v = fmaxf(fmaf(v, s, b), 0.f);
    }
    As[k] = v;
  }
  __syncthreads();
  int lane = tid & 63;
  int kc = tid >> 6;                    // k-chunk 0..3
  int c = blockIdx.x * 64 + lane;
  int kq = K >> 2;
  int kb = kc * kq, ke = kb + kq;
  float a0 = 0.f, a1 = 0.f, a2 = 0.f, a3 = 0.f;
  if (c < Cout) {
    for (int k = kb; k < ke; k += 4) {
      a0 = fmaf(As[k + 0], W[(u64)(k + 0) * Cout + c], a0);
      a1 = fmaf(As[k + 1], W[(u64)(k + 1) * Cout + c], a1);
      a2 = fmaf(As[k + 2], W[(u64)(k + 2) * Cout + c], a2);
      a3 = fmaf(As[k + 3], W[(u64)(k + 3) * Cout + c], a3);
    }
  }
  part[kc][lane] = (a0 + a1) + (a2 + a3);
  __syncthreads();
  if (tid < 64) {
    int cc = blockIdx.x * 64 + tid;
    if (cc < Cout) {
      float acc = bias[cc] + ((part[0][tid] + part[1][tid]) + (part[2][tid] + part[3][tid]));
      Y[(u64)r * Cout + cc] = acc;
      if (sum) { atomicAdd(&sum[cc], acc); atomicAdd(&sq[cc], acc * acc); }
    }
  }
}

// -------- stats-only pass: t = relu(z*s1+b1), accumulate sum/sq of t -----------
__global__ __launch_bounds__(256) void act_stats_kernel(
    const float* __restrict__ z,
    const float* __restrict__ pSum, const float* __restrict__ pSq, float invcnt,
    const float* __restrict__ g, const float* __restrict__ be,
    float* __restrict__ sum, float* __restrict__ sq, int total, int cmask)
{
  __shared__ float red[256];
  int tid = threadIdx.x;
  int c = tid & cmask;
  float s, b;
  bn_coeff(pSum, pSq, invcnt, g, be, c, s, b);
  float ls = 0.f, lq = 0.f;
  for (int idx = blockIdx.x * 256 + tid; idx < total; idx += gridDim.x * 256) {
    float v = fmaxf(fmaf(z[idx], s, b), 0.f);
    ls += v; lq += v * v;
  }
  red[tid] = ls; __syncthreads();
  if (tid <= cmask) {
    float t = 0.f;
    for (int k = tid; k < 256; k += cmask + 1) t += red[k];
    atomicAdd(&sum[tid], t);
  }
  __syncthreads();
  red[tid] = lq; __syncthreads();
  if (tid <= cmask) {
    float t = 0.f;
    for (int k = tid; k < 256; k += cmask + 1) t += red[k];
    atomicAdd(&sq[tid], t);
  }
}

// ------ recompute t from z, apply outer affine, write h + bf16 hi plane --------
__global__ __launch_bounds__(256) void apply_bn_kernel(
    const float* __restrict__ z,
    const float* __restrict__ iSum, const float* __restrict__ iSq, float invcnt,
    const float* __restrict__ ig, const float* __restrict__ ibe,
    const float* __restrict__ oSum, const float* __restrict__ oSq,
    const float* __restrict__ og, const float* __restrict__ obe,
    float* __restrict__ h, unsigned short* __restrict__ hspH,
    int off, int cshift, int cmask, int total)
{
  int tid = threadIdx.x;
  int c = tid & cmask;
  float s1, b1, s2, b2;
  bn_coeff(iSum, iSq, invcnt, ig, ibe, c, s1, b1);
  bn_coeff(oSum, oSq, invcnt, og, obe, c, s2, b2);
  for (int idx = blockIdx.x * 256 + tid; idx < total; idx += gridDim.x * 256) {
    int r = idx >> cshift;
    float t = fmaxf(fmaf(z[idx], s1, b1), 0.f);
    float v = fmaf(t, s2, b2);
    u64 o = (u64)r * 512 + off + (idx & cmask);
    h[o] = v;
    hspH[o] = f2bf(v);
  }
}

// ------------- EdgeConv segment_max via CSR + bf16 hi plane ----------------
__global__ __launch_bounds__(256) void x0max_csr_kernel(
    const _Float16* __restrict__ y3,
    const float* __restrict__ pSum, const float* __restrict__ pSq, float invcnt,
    const float* __restrict__ g, const float* __restrict__ be,
    const int* __restrict__ row_ptr, float* __restrict__ h,
    unsigned short* __restrict__ hspH)
{
  int n = blockIdx.x * 4 + (threadIdx.x >> 6);
  int lane = threadIdx.x & 63;
  int b = row_ptr[n], e = row_ptr[n + 1];
  float s, bb;
  bn_coeff(pSum, pSq, invcnt, g, be, lane, s, bb);
  float mx = 0.f;
  for (int i = b; i < e; ++i) {
    float v = fmaxf(fmaf((float)y3[(u64)i * 64 + lane], s, bb), 0.f);
    mx = fmaxf(mx, v);
  }
  u64 o = (u64)n * 512 + lane;
  h[o] = mx;
  hspH[o] = f2bf(mx);
}

// ------------- GIN neighbor-sum via CSR gather (wave per node, coalesced) ------
template<int COLS>
__global__ __launch_bounds__(256) void gather_add_kernel(
    const float* __restrict__ h, int off,
    const int* __restrict__ row_ptr, const int* __restrict__ ssrc,
    float* __restrict__ agg)
{
  int n = blockIdx.x * 4 + (threadIdx.x >> 6);
  int lane = threadIdx.x & 63;
  int b = row_ptr[n], e = row_ptr[n + 1];
  float a0 = 0.f, a1 = 0.f;
  for (int i = b; i < e; ++i) {
    const float* p = h + (u64)ssrc[i] * 512 + off + lane;
    a0 += p[0];
    if (COLS > 64) a1 += p[64];
  }
  float* q = agg + (u64)n * COLS + lane;
  q[0] = a0;
  if (COLS > 64) q[64] = a1;
}

// ---------------- graph pooling (hl fp16) ----------------
__global__ __launch_bounds__(256) void pool_kernel(
    const _Float16* __restrict__ hl,
    const float* __restrict__ pSum, const float* __restrict__ pSq, float invcnt,
    const float* __restrict__ g, const float* __restrict__ be,
    float* __restrict__ o)
{
  int gidx = blockIdx.x;
  int c = blockIdx.y * 256 + threadIdx.x;
  float s, b;
  bn_coeff(pSum, pSq, invcnt, g, be, c, s, b);
  const _Float16* p = hl + (u64)gidx * NPG * 1024 + c;
  float mx = 0.f, sm = 0.f;
  for (int n = 0; n < NPG; ++n) {
    float v = fmaxf(fmaf((float)p[(u64)n * 1024], s, b), 0.f);
    mx = fmaxf(mx, v);
    sm += v;
  }
  o[gidx * 2048 + c] = mx;
  o[gidx * 2048 + 1024 + c] = sm * (1.f / NPG);
}

// ---------------- log_softmax over 40 cols ----------------
__global__ void lsm_kernel(const float* __restrict__ logits, float* __restrict__ out)
{
  int r = blockIdx.x;
  int c = threadIdx.x;
  float v = (c < 40) ? logits[r * 40 + c] : -INFINITY;
  float m = v;
  for (int off = 32; off; off >>= 1) m = fmaxf(m, __shfl_xor(m, off, 64));
  float e = (c < 40) ? expf(v - m) : 0.f;
  float s = e;
  for (int off = 32; off; off >>= 1) s += __shfl_xor(s, off, 64);
  if (c < 40) out[r * 40 + c] = (v - m) - logf(s);
}

extern "C" void kernel_launch(void* const* d_in, const int* in_sizes, int n_in,
                              void* d_out, int out_size, void* d_ws, size_t ws_size,
                              hipStream_t stream)
{
  const float* x    = (const float*)d_in[0];
  const int*   ei   = (const int*)d_in[1];
  const int*   srcI = ei;
  const int*   dstI = ei + E_EDGES;
  const float* ecW1 = (const float*)d_in[3];
  const float* ecb1 = (const float*)d_in[4];
  const float* ecg1 = (const float*)d_in[5];
  const float* ecbe1= (const float*)d_in[6];
  const float* ecW2 = (const float*)d_in[7];
  const float* ecb2 = (const float*)d_in[8];
  const float* ecg2 = (const float*)d_in[9];
  const float* ecbe2= (const float*)d_in[10];
  const float* ecW3 = (const float*)d_in[11];
  const float* ecb3 = (const float*)d_in[12];
  const float* ecg3 = (const float*)d_in[13];
  const float* ecbe3= (const float*)d_in[14];
  const float* g1W  = (const float*)d_in[15];
  const float* g1b  = (const float*)d_in[16];
  const float* g1g  = (const float*)d_in[17];
  const float* g1be = (const float*)d_in[18];
  const float* g2W  = (const float*)d_in[19];
  const float* g2b  = (const float*)d_in[20];
  const float* g2g  = (const float*)d_in[21];
  const float* g2be = (const float*)d_in[22];
  const float* g3W  = (const float*)d_in[23];
  const float* g3b  = (const float*)d_in[24];
  const float* g3g  = (const float*)d_in[25];
  const float* g3be = (const float*)d_in[26];
  const float* bn1g = (const float*)d_in[27];
  const float* bn1be= (const float*)d_in[28];
  const float* bn2g = (const float*)d_in[29];
  const float* bn2be= (const float*)d_in[30];
  const float* bn3g = (const float*)d_in[31];
  const float* bn3be= (const float*)d_in[32];
  const float* linW = (const float*)d_in[33];
  const float* linb = (const float*)d_in[34];
  const float* ling = (const float*)d_in[35];
  const float* linbe= (const float*)d_in[36];
  const float* h1W  = (const float*)d_in[37];
  const float* h1b  = (const float*)d_in[38];
  const float* h1g  = (const float*)d_in[39];
  const float* h1be = (const float*)d_in[40];
  const float* h2W  = (const float*)d_in[41];
  const float* h2b  = (const float*)d_in[42];
  const float* h2g  = (const float*)d_in[43];
  const float* h2be = (const float*)d_in[44];
  const float* outW = (const float*)d_in[45];
  const float* outb = (const float*)d_in[46];

  char* ws = (char*)d_ws;
  const size_t MB = 1024ull * 1024ull;
  // ---- stats area [0, 96 KiB): 12 slots of (sum 4K + sq 4K) ----
#define S(i) ((float*)(ws + (size_t)(i) * 8192))
#define Q(i) ((float*)(ws + (size_t)(i) * 8192 + 4096))
  // ---- small buffers [128 KiB, 1 MiB) ----
  float* o_     = (float*)(ws + 131072);
  float* yh1    = (float*)(ws + 131072 + 524288);
  float* yh2    = (float*)(ws + 131072 + 524288 + 131072);
  float* logits = (float*)(ws + 131072 + 524288 + 131072 + 65536);
  // ---- weights [1 MiB, 4 MiB) ----
  _Float16* ec2WtH16 = (_Float16*)(ws + 1 * MB);
  _Float16* ec2WtL16 = (_Float16*)(ws + 1 * MB + 8192);
  _Float16* ec3WtH16 = (_Float16*)(ws + 1 * MB + 16384);
  _Float16* ec3WtL16 = (_Float16*)(ws + 1 * MB + 24576);
  unsigned short* g1WtH  = (unsigned short*)(ws + 1 * MB + 32768);
  unsigned short* g1WtL  = (unsigned short*)(ws + 1 * MB + 40960);
  unsigned short* g2WtH  = (unsigned short*)(ws + 1 * MB + 49152);
  unsigned short* g2WtL  = (unsigned short*)(ws + 1 * MB + 65536);
  unsigned short* g3WtH  = (unsigned short*)(ws + 1 * MB + 81920);
  unsigned short* g3WtL  = (unsigned short*)(ws + 1 * MB + 147456);
  unsigned short* linWtH = (unsigned short*)(ws + 1 * MB + 212992);
  unsigned short* linWtL = (unsigned short*)(ws + 1 * MB + 212992 + 1048576);
  // ---- big region [4 MiB, 132 MiB) ----
  _Float16* y  = (_Float16*)(ws + 4 * MB);     // [E,64] fp16 (dead after x0max)
  float* ytemp = (float*)(ws + 4 * MB);        // GIN z, <=32 MiB
  float* agg   = (float*)(ws + 36 * MB);       // GIN agg, <=32 MiB
  unsigned short* hspH = (unsigned short*)(ws + 68 * MB);   // [N,512] bf16 hi
  _Float16* hl = (_Float16*)(ws + 4 * MB);     // [N,1024] fp16 during lin/pool
  // ---- h region [132 MiB, 196 MiB): [N,512] fp32 ----
  float* h = (float*)(ws + 132 * MB);
  // ---- CSR region [196 MiB, 201 MiB) ----
  int* row_ptr = (int*)(ws + 196 * MB);
  int* cnt     = (int*)(ws + 196 * MB + 140000);
  int* ssrc    = (int*)(ws + 197 * MB);
  int* sdst    = (int*)(ws + 199 * MB);

  const float invE = 1.f / E_EDGES;
  const float invN = 1.f / N_NODES;
  const float invB = 1.f / N_GRAPHS;

  hipMemsetAsync((void*)ws, 0, 12 * 8192, stream);
  hipMemsetAsync((void*)cnt, 0, 32768 * 4, stream);

  // ---------------- CSR build ----------------
  hist_kernel<<<2048, 256, 0, stream>>>(dstI, cnt);
  scan_kernel<<<1, 1024, 0, stream>>>(cnt, row_ptr);
  fill_kernel<<<2048, 256, 0, stream>>>(srcI, dstI, cnt, ssrc, sdst);

  // ---------------- weight prep ----------------
  wt16_all_kernel<<<32, 256, 0, stream>>>(ecW2, ec2WtH16, ec2WtL16, ecW3, ec3WtH16, ec3WtL16);
  wt_all_kernel<<<2224, 256, 0, stream>>>(g1W, g1WtH, g1WtL, g2W, g2WtH, g2WtL,
                                          g3W, g3WtH, g3WtL, linW, linWtH, linWtL);

  // ---------------- EdgeConv (fp16 y, in-place) ----------------
  ec1_kernel<<<1024, 256, 0, stream>>>(x, ssrc, sdst, ecW1, ecb1, y, S(0), Q(0));
  mfma_gemm_f16_kernel<<<E_EDGES / 128, 256, 0, stream>>>(
      y, S(0), Q(0), invE, ecg1, ecbe1, ec2WtH16, ec2WtL16, ecb2, y, S(1), Q(1));
  mfma_gemm_f16_kernel<<<E_EDGES / 128, 256, 0, stream>>>(
      y, S(1), Q(1), invE, ecg2, ecbe2, ec3WtH16, ec3WtL16, ecb3, y, S(2), Q(2));
  x0max_csr_kernel<<<N_NODES / 4, 256, 0, stream>>>(
      y, S(2), Q(2), invE, ecg3, ecbe3, row_ptr, h, hspH);

  // ---------------- GIN 1 ----------------
  gather_add_kernel<64><<<N_NODES / 4, 256, 0, stream>>>(h, 0, row_ptr, ssrc, agg);
  mfma_gemm_kernel<<<dim3(1, N_NODES / 128), 256, 0, stream>>>(
      h, 512, agg, 64, g1WtH, g1WtL, g1b, ytemp, 64, S(3), Q(3), N_NODES, 64, 64);
  act_stats_kernel<<<512, 256, 0, stream>>>(
      ytemp, S(3), Q(3), invN, g1g, g1be, S(4), Q(4), N_NODES * 64, 63);
  apply_bn_kernel<<<1024, 256, 0, stream>>>(
      ytemp, S(3), Q(3), invN, g1g, g1be, S(4), Q(4), bn1g, bn1be,
      h, hspH, 64, 6, 63, N_NODES * 64);

  // ---------------- GIN 2 ----------------
  gather_add_kernel<64><<<N_NODES / 4, 256, 0, stream>>>(h, 64, row_ptr, ssrc, agg);
  mfma_gemm_kernel<<<dim3(2, N_NODES / 128), 256, 0, stream>>>(
      h + 64, 512, agg, 64, g2WtH, g2WtL, g2b, ytemp, 128, S(5), Q(5), N_NODES, 64, 128);
  act_stats_kernel<<<512, 256, 0, stream>>>(
      ytemp, S(5), Q(5), invN, g2g, g2be, S(6), Q(6), N_NODES * 128, 127);
  apply_bn_kernel<<<1024, 256, 0, stream>>>(
      ytemp, S(5), Q(5), invN, g2g, g2be, S(6), Q(6), bn2g, bn2be,
      h, hspH, 128, 7, 127, N_NODES * 128);

  // ---------------- GIN 3 ----------------
  gather_add_kernel<128><<<N_NODES / 4, 256, 0, stream>>>(h, 128, row_ptr, ssrc, agg);
  mfma_gemm_kernel<<<dim3(4, N_NODES / 128), 256, 0, stream>>>(
      h + 128, 512, agg, 128, g3WtH, g3WtL, g3b, ytemp, 256, S(7), Q(7), N_NODES, 128, 256);
  act_stats_kernel<<<512, 256, 0, stream>>>(
      ytemp, S(7), Q(7), invN, g3g, g3be, S(8), Q(8), N_NODES * 256, 255);
  apply_bn_kernel<<<1024, 256, 0, stream>>>(
      ytemp, S(7), Q(7), invN, g3g, g3be, S(8), Q(8), bn3g, bn3be,
      h, hspH, 256, 8, 255, N_NODES * 256);

  // ---------------- lin (single-plane W) + pool ----------------
  mfma_gemm_ps_kernel<<<dim3(8, N_NODES / 128), 256, 0, stream>>>(
      hspH, linWtH, linb, hl, S(9), Q(9), 512, 1024);
  pool_kernel<<<dim3(64, 4), 256, 0, stream>>>(hl, S(9), Q(9), invN, ling, linbe, o_);

  // ---------------- head (K-split 4x) ----------------
  head_gemm_kernel<<<dim3(8, 64), 256, 0, stream>>>(
      o_, 2048, nullptr, nullptr, 0.f, nullptr, nullptr, h1W, h1b, yh1, 512, S(10), Q(10));
  head_gemm_kernel<<<dim3(4, 64), 256, 0, stream>>>(
      yh1, 512, S(10), Q(10), invB, h1g, h1be, h2W, h2b, yh2, 256, S(11), Q(11));
  head_gemm_kernel<<<dim3(1, 64), 256, 0, stream>>>(
      yh2, 256, S(11), Q(11), invB, h2g, h2be, outW, outb, logits, 40, nullptr, nullptr);
  lsm_kernel<<<64, 64, 0, stream>>>(logits, (float*)d_out);
#undef S
#undef Q
}

// Round 19
// 943.054 us; speedup vs baseline: 1.2389x; 1.1039x over previous
//
#include <hip/hip_runtime.h>
#include <math.h>

#define E_EDGES 524288
#define N_NODES 32768
#define N_GRAPHS 64
#define NPG 512

typedef unsigned long long u64;
using bf16x8 = __attribute__((ext_vector_type(8))) short;
using f16x8  = __attribute__((ext_vector_type(8))) _Float16;
using f32x4  = __attribute__((ext_vector_type(4))) float;

__device__ __forceinline__ unsigned short f2bf(float f) {
  unsigned int u = __float_as_uint(f);
  u += 0x7FFFu + ((u >> 16) & 1u);
  return (unsigned short)(u >> 16);
}
__device__ __forceinline__ float b2f(unsigned short s) {
  return __uint_as_float(((unsigned int)s) << 16);
}
// BN coeff from raw sums: s = g/sqrt(var+eps), b = be - m*s
__device__ __forceinline__ void bn_coeff(
    const float* __restrict__ pSum, const float* __restrict__ pSq, float invcnt,
    const float* __restrict__ g, const float* __restrict__ be, int c,
    float& s, float& b)
{
  float m = pSum[c] * invcnt;
  float v = pSq[c] * invcnt - m * m;
  float is = rsqrtf(v + 1e-5f);
  s = g[c] * is;
  b = fmaf(-m, s, be[c]);
}

// ================= CSR build (dst-sorted edge permutation) =================
__global__ __launch_bounds__(256) void hist_kernel(
    const int* __restrict__ dst, int* __restrict__ cnt)
{
  int e = blockIdx.x * 256 + threadIdx.x;
  atomicAdd(&cnt[dst[e]], 1);
}

__global__ __launch_bounds__(1024) void scan_kernel(
    int* __restrict__ cnt, int* __restrict__ row_ptr)
{
  __shared__ int s[1024];
  int t = threadIdx.x;
  int base = t * 32;
  int local[32];
  int acc = 0;
#pragma unroll
  for (int i = 0; i < 32; ++i) { local[i] = acc; acc += cnt[base + i]; }
  s[t] = acc;
  __syncthreads();
  for (int d = 1; d < 1024; d <<= 1) {
    int v = (t >= d) ? s[t - d] : 0;
    __syncthreads();
    s[t] += v;
    __syncthreads();
  }
  int off = t ? s[t - 1] : 0;
#pragma unroll
  for (int i = 0; i < 32; ++i) {
    int p = off + local[i];
    row_ptr[base + i] = p;
    cnt[base + i] = p;
  }
  if (t == 1023) row_ptr[32768] = off + acc;
}

__global__ __launch_bounds__(256) void fill_kernel(
    const int* __restrict__ src, const int* __restrict__ dst,
    int* __restrict__ pos, int* __restrict__ ssrc, int* __restrict__ sdst)
{
  int e = blockIdx.x * 256 + threadIdx.x;
  int d = dst[e];
  int p = atomicAdd(&pos[d], 1);
  ssrc[p] = src[e];
  sdst[p] = d;
}

// ---------------- merged weight transpose kernels ----------------
__global__ __launch_bounds__(256) void wt16_all_kernel(
    const float* __restrict__ W2, _Float16* __restrict__ H2, _Float16* __restrict__ L2,
    const float* __restrict__ W3, _Float16* __restrict__ H3, _Float16* __restrict__ L3)
{
  int b = blockIdx.x;
  const float* W = (b < 16) ? W2 : W3;
  _Float16* H = (b < 16) ? H2 : H3;
  _Float16* L = (b < 16) ? L2 : L3;
  int idx = (b & 15) * 256 + threadIdx.x;
  int n = idx >> 6, k = idx & 63;
  float w = W[k * 64 + n];
  _Float16 hi = (_Float16)w;
  H[idx] = hi;
  L[idx] = (_Float16)(w - (float)hi);
}

__global__ __launch_bounds__(256) void wt_all_kernel(
    const float* __restrict__ g1W, unsigned short* __restrict__ g1H, unsigned short* __restrict__ g1L,
    const float* __restrict__ g2W, unsigned short* __restrict__ g2H, unsigned short* __restrict__ g2L,
    const float* __restrict__ g3W, unsigned short* __restrict__ g3H, unsigned short* __restrict__ g3L,
    const float* __restrict__ lW,  unsigned short* __restrict__ lH,  unsigned short* __restrict__ lL)
{
  int b = blockIdx.x;
  const float* W; unsigned short *H, *L; int kshift, N, base;
  if (b < 16)       { W = g1W; H = g1H; L = g1L; kshift = 6; N = 64;   base = 0; }
  else if (b < 48)  { W = g2W; H = g2H; L = g2L; kshift = 6; N = 128;  base = 16; }
  else if (b < 176) { W = g3W; H = g3H; L = g3L; kshift = 7; N = 256;  base = 48; }
  else              { W = lW;  H = lH;  L = lL;  kshift = 9; N = 1024; base = 176; }
  int idx = (b - base) * 256 + threadIdx.x;
  int n = idx >> kshift;
  int k = idx & ((1 << kshift) - 1);
  float w = W[(u64)k * N + n];
  unsigned short hi = f2bf(w);
  H[idx] = hi;
  L[idx] = f2bf(w - b2f(hi));
}

// ----- EdgeConv layer 1: 4-edge ILP per wave iteration, fp16 out + stats -------
__global__ __launch_bounds__(256) void ec1_kernel(
    const float* __restrict__ x, const int* __restrict__ src, const int* __restrict__ dst,
    const float* __restrict__ W, const float* __restrict__ b,
    _Float16* __restrict__ y, float* __restrict__ sum, float* __restrict__ sq)
{
  __shared__ float Ws[512];
  __shared__ float bs[64];
  __shared__ float red[256];
  int tid = threadIdx.x;
  for (int i = tid; i < 512; i += 256) Ws[i] = W[i];
  if (tid < 64) bs[tid] = b[tid];
  __syncthreads();
  int c = tid & 63;
  int eslot = tid >> 6;
  float ls = 0.f, lq = 0.f;
  const float4* x4 = (const float4*)x;
  int stride = gridDim.x * 16;
  for (int e = blockIdx.x * 16 + eslot * 4; e < E_EDGES; e += stride) {
    int s0 = src[e],     s1 = src[e + 1], s2 = src[e + 2], s3 = src[e + 3];
    int d0 = dst[e],     d1 = dst[e + 1], d2 = dst[e + 2], d3 = dst[e + 3];
    float4 xi0 = x4[d0], xj0 = x4[s0];
    float4 xi1 = x4[d1], xj1 = x4[s1];
    float4 xi2 = x4[d2], xj2 = x4[s2];
    float4 xi3 = x4[d3], xj3 = x4[s3];
#pragma unroll
    for (int g = 0; g < 4; ++g) {
      float4 xi = (g == 0) ? xi0 : (g == 1) ? xi1 : (g == 2) ? xi2 : xi3;
      float4 xj = (g == 0) ? xj0 : (g == 1) ? xj1 : (g == 2) ? xj2 : xj3;
      float m[8] = {xi.x, xi.y, xi.z, xi.w,
                    xj.x - xi.x, xj.y - xi.y, xj.z - xi.z, xj.w - xi.w};
      float acc = bs[c];
#pragma unroll
      for (int k = 0; k < 8; ++k) acc = fmaf(m[k], Ws[k * 64 + c], acc);
      y[(u64)(e + g) * 64 + c] = (_Float16)acc;
      ls += acc; lq += acc * acc;
    }
  }
  red[tid] = ls; __syncthreads();
  if (tid < 64) atomicAdd(&sum[tid], red[tid] + red[tid + 64] + red[tid + 128] + red[tid + 192]);
  __syncthreads();
  red[tid] = lq; __syncthreads();
  if (tid < 64) atomicAdd(&sq[tid], red[tid] + red[tid + 64] + red[tid + 128] + red[tid + 192]);
}

// -------- fp16 MFMA GEMM for EC layers: Y = relu(A*s+b) @ Wt^T + bias ----------
// 256 rows/block, wave owns 64 rows (4 row-tiles): 8 A-loads in flight, 32 MFMAs.
__global__ __launch_bounds__(256) void mfma_gemm_f16_kernel(
    const _Float16* A,
    const float* __restrict__ pSum, const float* __restrict__ pSq, float invcnt,
    const float* __restrict__ g, const float* __restrict__ be,
    const _Float16* __restrict__ WtH, const _Float16* __restrict__ WtL,
    const float* __restrict__ bias,
    _Float16* Y,
    float* __restrict__ sum, float* __restrict__ sq)
{
  __shared__ _Float16 BsH[64][72];
  __shared__ _Float16 BsL[64][72];
  __shared__ _Float16 scL[64];
  __shared__ _Float16 shL[64];
  __shared__ float redY[64];
  __shared__ float redQ[64];
  int tid = threadIdx.x;
  int lane = tid & 63, wid = tid >> 6;
  int row0 = blockIdx.x * 256 + wid * 64;
  int m16 = lane & 15, quad = lane >> 4;

#pragma unroll
  for (int it = 0; it < 2; ++it) {
    int slot = tid + it * 256;
    int n = slot >> 3, cg = slot & 7;
    *(uint4*)&BsH[n][cg * 8] = *(const uint4*)(WtH + n * 64 + cg * 8);
    *(uint4*)&BsL[n][cg * 8] = *(const uint4*)(WtL + n * 64 + cg * 8);
  }
  if (tid < 64) {
    float s, b;
    bn_coeff(pSum, pSq, invcnt, g, be, tid, s, b);
    scL[tid] = (_Float16)s;
    shL[tid] = (_Float16)b;
  }
  __syncthreads();

  f16x8 af[4][2];
#pragma unroll
  for (int rt = 0; rt < 4; ++rt) {
    int grow = row0 + rt * 16 + m16;
    const _Float16* ap = A + (u64)grow * 64 + quad * 8;
#pragma unroll
    for (int ks2 = 0; ks2 < 2; ++ks2) {
      f16x8 a = *(const f16x8*)(ap + ks2 * 32);
      f16x8 s8 = *(const f16x8*)&scL[quad * 8 + ks2 * 32];
      f16x8 h8 = *(const f16x8*)&shL[quad * 8 + ks2 * 32];
      a = a * s8 + h8;
#pragma unroll
      for (int j = 0; j < 8; ++j) a[j] = (a[j] > (_Float16)0) ? a[j] : (_Float16)0;
      af[rt][ks2] = a;
    }
  }

  f32x4 acc[4][4];
#pragma unroll
  for (int i = 0; i < 4; ++i)
#pragma unroll
    for (int j = 0; j < 4; ++j) acc[i][j] = {0.f, 0.f, 0.f, 0.f};

#pragma unroll
  for (int ks2 = 0; ks2 < 2; ++ks2) {
#pragma unroll
    for (int ct = 0; ct < 4; ++ct) {
      f16x8 bh = *(const f16x8*)&BsH[ct * 16 + m16][ks2 * 32 + quad * 8];
      f16x8 bl = *(const f16x8*)&BsL[ct * 16 + m16][ks2 * 32 + quad * 8];
#pragma unroll
      for (int rt = 0; rt < 4; ++rt) {
        acc[rt][ct] = __builtin_amdgcn_mfma_f32_16x16x32_f16(af[rt][ks2], bh, acc[rt][ct], 0, 0, 0);
        acc[rt][ct] = __builtin_amdgcn_mfma_f32_16x16x32_f16(af[rt][ks2], bl, acc[rt][ct], 0, 0, 0);
      }
    }
  }

  float cys[4], cqs[4];
#pragma unroll
  for (int ct = 0; ct < 4; ++ct) {
    int col = ct * 16 + m16;
    float bcol = bias[col];
    float cy = 0.f, cq = 0.f;
#pragma unroll
    for (int rt = 0; rt < 4; ++rt) {
#pragma unroll
      for (int rg = 0; rg < 4; ++rg) {
        int row = row0 + rt * 16 + quad * 4 + rg;
        float v = acc[rt][ct][rg] + bcol;
        Y[(u64)row * 64 + col] = (_Float16)v;
        cy += v; cq += v * v;
      }
    }
    cys[ct] = cy; cqs[ct] = cq;
  }
#pragma unroll
  for (int ct = 0; ct < 4; ++ct) {
    cys[ct] += __shfl_xor(cys[ct], 16, 64); cys[ct] += __shfl_xor(cys[ct], 32, 64);
    cqs[ct] += __shfl_xor(cqs[ct], 16, 64); cqs[ct] += __shfl_xor(cqs[ct], 32, 64);
  }
  __syncthreads();
  if (tid < 64) { redY[tid] = 0.f; redQ[tid] = 0.f; }
  __syncthreads();
  if (quad == 0) {
#pragma unroll
    for (int ct = 0; ct < 4; ++ct) {
      atomicAdd(&redY[ct * 16 + m16], cys[ct]);
      atomicAdd(&redQ[ct * 16 + m16], cqs[ct]);
    }
  }
  __syncthreads();
  if (tid < 64) {
    atomicAdd(&sum[tid], redY[tid]);
    atomicAdd(&sq[tid], redQ[tid]);
  }
}

// ---------------- split-bf16 MFMA GEMM (fp32 A; gin layers) ----------------
__global__ __launch_bounds__(256) void mfma_gemm_kernel(
    const float* A, int lda,
    const float* __restrict__ Add, int ldadd,
    const unsigned short* __restrict__ Wt_hi, const unsigned short* __restrict__ Wt_lo,
    const float* __restrict__ bias,
    float* Y, int ldy,
    float* __restrict__ sum, float* __restrict__ sq,
    int M, int K, int N)
{
  __shared__ unsigned short BsH[64][72];
  __shared__ unsigned short BsL[64][72];
  __shared__ float redY[64];
  __shared__ float redQ[64];
  int tid = threadIdx.x;
  int lane = tid & 63, wid = tid >> 6;
  int row0 = blockIdx.y * 128 + wid * 32;
  int col0 = blockIdx.x * 64;
  int m16 = lane & 15, quad = lane >> 4;

  f32x4 acc[2][4];
#pragma unroll
  for (int i = 0; i < 2; ++i)
#pragma unroll
    for (int j = 0; j < 4; ++j) acc[i][j] = {0.f, 0.f, 0.f, 0.f};

  for (int k0 = 0; k0 < K; k0 += 64) {
    if (k0) __syncthreads();
#pragma unroll
    for (int it = 0; it < 2; ++it) {
      int slot = tid + it * 256;
      int n = slot >> 3, cg = slot & 7;
      u64 off = (u64)(col0 + n) * K + k0 + cg * 8;
      *(uint4*)&BsH[n][cg * 8] = *(const uint4*)(Wt_hi + off);
      *(uint4*)&BsL[n][cg * 8] = *(const uint4*)(Wt_lo + off);
    }
    __syncthreads();

    bf16x8 ah[2][2], al[2][2];
#pragma unroll
    for (int rt = 0; rt < 2; ++rt) {
      int grow = row0 + rt * 16 + m16;
      const float* ap = A + (u64)grow * lda + k0 + quad * 8;
      const float* addp = Add ? (Add + (u64)grow * ldadd + k0 + quad * 8) : nullptr;
#pragma unroll
      for (int ks2 = 0; ks2 < 2; ++ks2) {
        float4 v0 = *(const float4*)(ap + ks2 * 32);
        float4 v1 = *(const float4*)(ap + ks2 * 32 + 4);
        if (Add) {
          float4 a0 = *(const float4*)(addp + ks2 * 32);
          float4 a1 = *(const float4*)(addp + ks2 * 32 + 4);
          v0.x += a0.x; v0.y += a0.y; v0.z += a0.z; v0.w += a0.w;
          v1.x += a1.x; v1.y += a1.y; v1.z += a1.z; v1.w += a1.w;
        }
        float f[8] = {v0.x, v0.y, v0.z, v0.w, v1.x, v1.y, v1.z, v1.w};
        bf16x8 th, tl;
#pragma unroll
        for (int j = 0; j < 8; ++j) {
          unsigned short hi = f2bf(f[j]);
          th[j] = (short)hi;
          tl[j] = (short)f2bf(f[j] - b2f(hi));
        }
        ah[rt][ks2] = th;
        al[rt][ks2] = tl;
      }
    }

#pragma unroll
    for (int ks2 = 0; ks2 < 2; ++ks2) {
#pragma unroll
      for (int ct = 0; ct < 4; ++ct) {
        bf16x8 bh = *(const bf16x8*)&BsH[ct * 16 + m16][ks2 * 32 + quad * 8];
        bf16x8 bl = *(const bf16x8*)&BsL[ct * 16 + m16][ks2 * 32 + quad * 8];
#pragma unroll
        for (int rt = 0; rt < 2; ++rt) {
          acc[rt][ct] = __builtin_amdgcn_mfma_f32_16x16x32_bf16(ah[rt][ks2], bh, acc[rt][ct], 0, 0, 0);
          acc[rt][ct] = __builtin_amdgcn_mfma_f32_16x16x32_bf16(ah[rt][ks2], bl, acc[rt][ct], 0, 0, 0);
          acc[rt][ct] = __builtin_amdgcn_mfma_f32_16x16x32_bf16(al[rt][ks2], bh, acc[rt][ct], 0, 0, 0);
        }
      }
    }
  }

  float cys[4], cqs[4];
#pragma unroll
  for (int ct = 0; ct < 4; ++ct) {
    int col = col0 + ct * 16 + m16;
    float bcol = bias[col];
    float cy = 0.f, cq = 0.f;
#pragma unroll
    for (int rt = 0; rt < 2; ++rt) {
#pragma unroll
      for (int rg = 0; rg < 4; ++rg) {
        int row = row0 + rt * 16 + quad * 4 + rg;
        float v = acc[rt][ct][rg] + bcol;
        Y[(u64)row * ldy + col] = v;
        cy += v; cq += v * v;
      }
    }
    cys[ct] = cy; cqs[ct] = cq;
  }
#pragma unroll
  for (int ct = 0; ct < 4; ++ct) {
    cys[ct] += __shfl_xor(cys[ct], 16, 64); cys[ct] += __shfl_xor(cys[ct], 32, 64);
    cqs[ct] += __shfl_xor(cqs[ct], 16, 64); cqs[ct] += __shfl_xor(cqs[ct], 32, 64);
  }
  __syncthreads();
  if (tid < 64) { redY[tid] = 0.f; redQ[tid] = 0.f; }
  __syncthreads();
  if (quad == 0) {
#pragma unroll
    for (int ct = 0; ct < 4; ++ct) {
      atomicAdd(&redY[ct * 16 + m16], cys[ct]);
      atomicAdd(&redQ[ct * 16 + m16], cqs[ct]);
    }
  }
  __syncthreads();
  if (tid < 64) {
    atomicAdd(&sum[col0 + tid], redY[tid]);
    atomicAdd(&sq[col0 + tid], redQ[tid]);
  }
}

// ------- lin GEMM: bf16 A plane x bf16 W (single plane), 128-col, fp16 out -----
__global__ __launch_bounds__(256) void mfma_gemm_ps_kernel(
    const unsigned short* __restrict__ Ahi,
    const unsigned short* __restrict__ Wt_hi,
    const float* __restrict__ bias,
    _Float16* __restrict__ Y,
    float* __restrict__ sum, float* __restrict__ sq,
    int K, int N)
{
  __shared__ unsigned short BsH[128][72];
  __shared__ float redY[128];
  __shared__ float redQ[128];
  int tid = threadIdx.x;
  int lane = tid & 63, wid = tid >> 6;
  int row0 = blockIdx.y * 128 + wid * 32;
  int col0 = blockIdx.x * 128;
  int m16 = lane & 15, quad = lane >> 4;

  f32x4 acc[2][8];
#pragma unroll
  for (int i = 0; i < 2; ++i)
#pragma unroll
    for (int j = 0; j < 8; ++j) acc[i][j] = {0.f, 0.f, 0.f, 0.f};

  for (int k0 = 0; k0 < K; k0 += 64) {
    if (k0) __syncthreads();
#pragma unroll
    for (int it = 0; it < 4; ++it) {
      int slot = tid + it * 256;
      int n = slot >> 3, cg = slot & 7;
      u64 off = (u64)(col0 + n) * K + k0 + cg * 8;
      *(uint4*)&BsH[n][cg * 8] = *(const uint4*)(Wt_hi + off);
    }
    __syncthreads();

    bf16x8 ah[2][2];
#pragma unroll
    for (int rt = 0; rt < 2; ++rt) {
      int grow = row0 + rt * 16 + m16;
      u64 abase = (u64)grow * K + k0 + quad * 8;
#pragma unroll
      for (int ks2 = 0; ks2 < 2; ++ks2)
        ah[rt][ks2] = *(const bf16x8*)(Ahi + abase + ks2 * 32);
    }

#pragma unroll
    for (int ks2 = 0; ks2 < 2; ++ks2) {
#pragma unroll
      for (int ct = 0; ct < 8; ++ct) {
        bf16x8 bh = *(const bf16x8*)&BsH[ct * 16 + m16][ks2 * 32 + quad * 8];
#pragma unroll
        for (int rt = 0; rt < 2; ++rt) {
          acc[rt][ct] = __builtin_amdgcn_mfma_f32_16x16x32_bf16(ah[rt][ks2], bh, acc[rt][ct], 0, 0, 0);
        }
      }
    }
  }

  float cys[8], cqs[8];
#pragma unroll
  for (int ct = 0; ct < 8; ++ct) {
    int col = col0 + ct * 16 + m16;
    float bcol = bias[col];
    float cy = 0.f, cq = 0.f;
#pragma unroll
    for (int rt = 0; rt < 2; ++rt) {
#pragma unroll
      for (int rg = 0; rg < 4; ++rg) {
        int row = row0 + rt * 16 + quad * 4 + rg;
        float v = acc[rt][ct][rg] + bcol;
        Y[(u64)row * N + col] = (_Float16)v;
        cy += v; cq += v * v;
      }
    }
    cys[ct] = cy; cqs[ct] = cq;
  }
#pragma unroll
  for (int ct = 0; ct < 8; ++ct) {
    cys[ct] += __shfl_xor(cys[ct], 16, 64); cys[ct] += __shfl_xor(cys[ct], 32, 64);
    cqs[ct] += __shfl_xor(cqs[ct], 16, 64); cqs[ct] += __shfl_xor(cqs[ct], 32, 64);
  }
  __syncthreads();
  if (tid < 128) { redY[tid] = 0.f; redQ[tid] = 0.f; }
  __syncthreads();
  if (quad == 0) {
#pragma unroll
    for (int ct = 0; ct < 8; ++ct) {
      atomicAdd(&redY[ct * 16 + m16], cys[ct]);
      atomicAdd(&redQ[ct * 16 + m16], cqs[ct]);
    }
  }
  __syncthreads();
  if (tid < 128) {
    atomicAdd(&sum[col0 + tid], redY[tid]);
    atomicAdd(&sq[col0 + tid], redQ[tid]);
  }
}

// ---- head GEMM: K-split 4 ways; grid (ceil(Cout/64), 64 rows); 256 thr --------
__global__ __launch_bounds__(256) void head_gemm_kernel(
    const float* __restrict__ A, int K,
    const float* __restrict__ pSum, const float* __restrict__ pSq, float invcnt,
    const float* __restrict__ g, const float* __restrict__ be,
    const float* __restrict__ W, const float* __restrict__ bias,
    float* __restrict__ Y, int Cout,
    float* __restrict__ sum, float* __restrict__ sq)
{
  __shared__ float As[2048];
  __shared__ float part[4][64];
  int r = blockIdx.y;
  int tid = threadIdx.x;
  for (int k = tid; k < K; k += 256) {
    float v = A[(u64)r * K + k];
    if (pSum) {
      float s, b;
      bn_coeff(pSum, pSq, invcnt, g, be, k, s, b);
      v = fmaxf(fmaf(v, s, b), 0.f);
    }
    As[k] = v;
  }
  __syncthreads();
  int lane = tid & 63;
  int kc = tid >> 6;
  int c = blockIdx.x * 64 + lane;
  int kq = K >> 2;
  int kb = kc * kq, ke = kb + kq;
  float a0 = 0.f, a1 = 0.f, a2 = 0.f, a3 = 0.f;
  if (c < Cout) {
    for (int k = kb; k < ke; k += 4) {
      a0 = fmaf(As[k + 0], W[(u64)(k + 0) * Cout + c], a0);
      a1 = fmaf(As[k + 1], W[(u64)(k + 1) * Cout + c], a1);
      a2 = fmaf(As[k + 2], W[(u64)(k + 2) * Cout + c], a2);
      a3 = fmaf(As[k + 3], W[(u64)(k + 3) * Cout + c], a3);
    }
  }
  part[kc][lane] = (a0 + a1) + (a2 + a3);
  __syncthreads();
  if (tid < 64) {
    int cc = blockIdx.x * 64 + tid;
    if (cc < Cout) {
      float acc = bias[cc] + ((part[0][tid] + part[1][tid]) + (part[2][tid] + part[3][tid]));
      Y[(u64)r * Cout + cc] = acc;
      if (sum) { atomicAdd(&sum[cc], acc); atomicAdd(&sq[cc], acc * acc); }
    }
  }
}

// -------- stats-only pass: t = relu(z*s1+b1), accumulate sum/sq of t -----------
__global__ __launch_bounds__(256) void act_stats_kernel(
    const float* __restrict__ z,
    const float* __restrict__ pSum, const float* __restrict__ pSq, float invcnt,
    const float* __restrict__ g, const float* __restrict__ be,
    float* __restrict__ sum, float* __restrict__ sq, int total, int cmask)
{
  __shared__ float red[256];
  int tid = threadIdx.x;
  int c = tid & cmask;
  float s, b;
  bn_coeff(pSum, pSq, invcnt, g, be, c, s, b);
  float ls = 0.f, lq = 0.f;
  for (int idx = blockIdx.x * 256 + tid; idx < total; idx += gridDim.x * 256) {
    float v = fmaxf(fmaf(z[idx], s, b), 0.f);
    ls += v; lq += v * v;
  }
  red[tid] = ls; __syncthreads();
  if (tid <= cmask) {
    float t = 0.f;
    for (int k = tid; k < 256; k += cmask + 1) t += red[k];
    atomicAdd(&sum[tid], t);
  }
  __syncthreads();
  red[tid] = lq; __syncthreads();
  if (tid <= cmask) {
    float t = 0.f;
    for (int k = tid; k < 256; k += cmask + 1) t += red[k];
    atomicAdd(&sq[tid], t);
  }
}

// ------ recompute t from z, apply outer affine, write h + bf16 hi plane --------
__global__ __launch_bounds__(256) void apply_bn_kernel(
    const float* __restrict__ z,
    const float* __restrict__ iSum, const float* __restrict__ iSq, float invcnt,
    const float* __restrict__ ig, const float* __restrict__ ibe,
    const float* __restrict__ oSum, const float* __restrict__ oSq,
    const float* __restrict__ og, const float* __restrict__ obe,
    float* __restrict__ h, unsigned short* __restrict__ hspH,
    int off, int cshift, int cmask, int total)
{
  int tid = threadIdx.x;
  int c = tid & cmask;
  float s1, b1, s2, b2;
  bn_coeff(iSum, iSq, invcnt, ig, ibe, c, s1, b1);
  bn_coeff(oSum, oSq, invcnt, og, obe, c, s2, b2);
  for (int idx = blockIdx.x * 256 + tid; idx < total; idx += gridDim.x * 256) {
    int r = idx >> cshift;
    float t = fmaxf(fmaf(z[idx], s1, b1), 0.f);
    float v = fmaf(t, s2, b2);
    u64 o = (u64)r * 512 + off + (idx & cmask);
    h[o] = v;
    hspH[o] = f2bf(v);
  }
}

// ------------- EdgeConv segment_max via CSR + bf16 hi plane ----------------
__global__ __launch_bounds__(256) void x0max_csr_kernel(
    const _Float16* __restrict__ y3,
    const float* __restrict__ pSum, const float* __restrict__ pSq, float invcnt,
    const float* __restrict__ g, const float* __restrict__ be,
    const int* __restrict__ row_ptr, float* __restrict__ h,
    unsigned short* __restrict__ hspH)
{
  int n = blockIdx.x * 4 + (threadIdx.x >> 6);
  int lane = threadIdx.x & 63;
  int b = row_ptr[n], e = row_ptr[n + 1];
  float s, bb;
  bn_coeff(pSum, pSq, invcnt, g, be, lane, s, bb);
  float mx = 0.f;
  for (int i = b; i < e; ++i) {
    float v = fmaxf(fmaf((float)y3[(u64)i * 64 + lane], s, bb), 0.f);
    mx = fmaxf(mx, v);
  }
  u64 o = (u64)n * 512 + lane;
  h[o] = mx;
  hspH[o] = f2bf(mx);
}

// ------------- GIN neighbor-sum via CSR gather (wave per node, coalesced) ------
template<int COLS>
__global__ __launch_bounds__(256) void gather_add_kernel(
    const float* __restrict__ h, int off,
    const int* __restrict__ row_ptr, const int* __restrict__ ssrc,
    float* __restrict__ agg)
{
  int n = blockIdx.x * 4 + (threadIdx.x >> 6);
  int lane = threadIdx.x & 63;
  int b = row_ptr[n], e = row_ptr[n + 1];
  float a0 = 0.f, a1 = 0.f;
  for (int i = b; i < e; ++i) {
    const float* p = h + (u64)ssrc[i] * 512 + off + lane;
    a0 += p[0];
    if (COLS > 64) a1 += p[64];
  }
  float* q = agg + (u64)n * COLS + lane;
  q[0] = a0;
  if (COLS > 64) q[64] = a1;
}

// ---------------- graph pooling (hl fp16) ----------------
__global__ __launch_bounds__(256) void pool_kernel(
    const _Float16* __restrict__ hl,
    const float* __restrict__ pSum, const float* __restrict__ pSq, float invcnt,
    const float* __restrict__ g, const float* __restrict__ be,
    float* __restrict__ o)
{
  int gidx = blockIdx.x;
  int c = blockIdx.y * 256 + threadIdx.x;
  float s, b;
  bn_coeff(pSum, pSq, invcnt, g, be, c, s, b);
  const _Float16* p = hl + (u64)gidx * NPG * 1024 + c;
  float mx = 0.f, sm = 0.f;
  for (int n = 0; n < NPG; ++n) {
    float v = fmaxf(fmaf((float)p[(u64)n * 1024], s, b), 0.f);
    mx = fmaxf(mx, v);
    sm += v;
  }
  o[gidx * 2048 + c] = mx;
  o[gidx * 2048 + 1024 + c] = sm * (1.f / NPG);
}

// ---------------- log_softmax over 40 cols ----------------
__global__ void lsm_kernel(const float* __restrict__ logits, float* __restrict__ out)
{
  int r = blockIdx.x;
  int c = threadIdx.x;
  float v = (c < 40) ? logits[r * 40 + c] : -INFINITY;
  float m = v;
  for (int off = 32; off; off >>= 1) m = fmaxf(m, __shfl_xor(m, off, 64));
  float e = (c < 40) ? expf(v - m) : 0.f;
  float s = e;
  for (int off = 32; off; off >>= 1) s += __shfl_xor(s, off, 64);
  if (c < 40) out[r * 40 + c] = (v - m) - logf(s);
}

extern "C" void kernel_launch(void* const* d_in, const int* in_sizes, int n_in,
                              void* d_out, int out_size, void* d_ws, size_t ws_size,
                              hipStream_t stream)
{
  const float* x    = (const float*)d_in[0];
  const int*   ei   = (const int*)d_in[1];
  const int*   srcI = ei;
  const int*   dstI = ei + E_EDGES;
  const float* ecW1 = (const float*)d_in[3];
  const float* ecb1 = (const float*)d_in[4];
  const float* ecg1 = (const float*)d_in[5];
  const float* ecbe1= (const float*)d_in[6];
  const float* ecW2 = (const float*)d_in[7];
  const float* ecb2 = (const float*)d_in[8];
  const float* ecg2 = (const float*)d_in[9];
  const float* ecbe2= (const float*)d_in[10];
  const float* ecW3 = (const float*)d_in[11];
  const float* ecb3 = (const float*)d_in[12];
  const float* ecg3 = (const float*)d_in[13];
  const float* ecbe3= (const float*)d_in[14];
  const float* g1W  = (const float*)d_in[15];
  const float* g1b  = (const float*)d_in[16];
  const float* g1g  = (const float*)d_in[17];
  const float* g1be = (const float*)d_in[18];
  const float* g2W  = (const float*)d_in[19];
  const float* g2b  = (const float*)d_in[20];
  const float* g2g  = (const float*)d_in[21];
  const float* g2be = (const float*)d_in[22];
  const float* g3W  = (const float*)d_in[23];
  const float* g3b  = (const float*)d_in[24];
  const float* g3g  = (const float*)d_in[25];
  const float* g3be = (const float*)d_in[26];
  const float* bn1g = (const float*)d_in[27];
  const float* bn1be= (const float*)d_in[28];
  const float* bn2g = (const float*)d_in[29];
  const float* bn2be= (const float*)d_in[30];
  const float* bn3g = (const float*)d_in[31];
  const float* bn3be= (const float*)d_in[32];
  const float* linW = (const float*)d_in[33];
  const float* linb = (const float*)d_in[34];
  const float* ling = (const float*)d_in[35];
  const float* linbe= (const float*)d_in[36];
  const float* h1W  = (const float*)d_in[37];
  const float* h1b  = (const float*)d_in[38];
  const float* h1g  = (const float*)d_in[39];
  const float* h1be = (const float*)d_in[40];
  const float* h2W  = (const float*)d_in[41];
  const float* h2b  = (const float*)d_in[42];
  const float* h2g  = (const float*)d_in[43];
  const float* h2be = (const float*)d_in[44];
  const float* outW = (const float*)d_in[45];
  const float* outb = (const float*)d_in[46];

  char* ws = (char*)d_ws;
  const size_t MB = 1024ull * 1024ull;
  // ---- stats area [0, 96 KiB): 12 slots of (sum 4K + sq 4K) ----
#define S(i) ((float*)(ws + (size_t)(i) * 8192))
#define Q(i) ((float*)(ws + (size_t)(i) * 8192 + 4096))
  // ---- small buffers [128 KiB, 1 MiB) ----
  float* o_     = (float*)(ws + 131072);
  float* yh1    = (float*)(ws + 131072 + 524288);
  float* yh2    = (float*)(ws + 131072 + 524288 + 131072);
  float* logits = (float*)(ws + 131072 + 524288 + 131072 + 65536);
  // ---- weights [1 MiB, 4 MiB) ----
  _Float16* ec2WtH16 = (_Float16*)(ws + 1 * MB);
  _Float16* ec2WtL16 = (_Float16*)(ws + 1 * MB + 8192);
  _Float16* ec3WtH16 = (_Float16*)(ws + 1 * MB + 16384);
  _Float16* ec3WtL16 = (_Float16*)(ws + 1 * MB + 24576);
  unsigned short* g1WtH  = (unsigned short*)(ws + 1 * MB + 32768);
  unsigned short* g1WtL  = (unsigned short*)(ws + 1 * MB + 40960);
  unsigned short* g2WtH  = (unsigned short*)(ws + 1 * MB + 49152);
  unsigned short* g2WtL  = (unsigned short*)(ws + 1 * MB + 65536);
  unsigned short* g3WtH  = (unsigned short*)(ws + 1 * MB + 81920);
  unsigned short* g3WtL  = (unsigned short*)(ws + 1 * MB + 147456);
  unsigned short* linWtH = (unsigned short*)(ws + 1 * MB + 212992);
  unsigned short* linWtL = (unsigned short*)(ws + 1 * MB + 212992 + 1048576);
  // ---- big region [4 MiB, 132 MiB) ----
  _Float16* y  = (_Float16*)(ws + 4 * MB);     // [E,64] fp16 (dead after x0max)
  float* ytemp = (float*)(ws + 4 * MB);        // GIN z, <=32 MiB
  float* agg   = (float*)(ws + 36 * MB);       // GIN agg, <=32 MiB
  unsigned short* hspH = (unsigned short*)(ws + 68 * MB);   // [N,512] bf16 hi
  _Float16* hl = (_Float16*)(ws + 4 * MB);     // [N,1024] fp16 during lin/pool
  // ---- h region [132 MiB, 196 MiB): [N,512] fp32 ----
  float* h = (float*)(ws + 132 * MB);
  // ---- CSR region [196 MiB, 201 MiB) ----
  int* row_ptr = (int*)(ws + 196 * MB);
  int* cnt     = (int*)(ws + 196 * MB + 140000);
  int* ssrc    = (int*)(ws + 197 * MB);
  int* sdst    = (int*)(ws + 199 * MB);

  const float invE = 1.f / E_EDGES;
  const float invN = 1.f / N_NODES;
  const float invB = 1.f / N_GRAPHS;

  hipMemsetAsync((void*)ws, 0, 12 * 8192, stream);
  hipMemsetAsync((void*)cnt, 0, 32768 * 4, stream);

  // ---------------- CSR build ----------------
  hist_kernel<<<2048, 256, 0, stream>>>(dstI, cnt);
  scan_kernel<<<1, 1024, 0, stream>>>(cnt, row_ptr);
  fill_kernel<<<2048, 256, 0, stream>>>(srcI, dstI, cnt, ssrc, sdst);

  // ---------------- weight prep ----------------
  wt16_all_kernel<<<32, 256, 0, stream>>>(ecW2, ec2WtH16, ec2WtL16, ecW3, ec3WtH16, ec3WtL16);
  wt_all_kernel<<<2224, 256, 0, stream>>>(g1W, g1WtH, g1WtL, g2W, g2WtH, g2WtL,
                                          g3W, g3WtH, g3WtL, linW, linWtH, linWtL);

  // ---------------- EdgeConv (fp16 y, in-place) ----------------
  ec1_kernel<<<1024, 256, 0, stream>>>(x, ssrc, sdst, ecW1, ecb1, y, S(0), Q(0));
  mfma_gemm_f16_kernel<<<E_EDGES / 256, 256, 0, stream>>>(
      y, S(0), Q(0), invE, ecg1, ecbe1, ec2WtH16, ec2WtL16, ecb2, y, S(1), Q(1));
  mfma_gemm_f16_kernel<<<E_EDGES / 256, 256, 0, stream>>>(
      y, S(1), Q(1), invE, ecg2, ecbe2, ec3WtH16, ec3WtL16, ecb3, y, S(2), Q(2));
  x0max_csr_kernel<<<N_NODES / 4, 256, 0, stream>>>(
      y, S(2), Q(2), invE, ecg3, ecbe3, row_ptr, h, hspH);

  // ---------------- GIN 1 ----------------
  gather_add_kernel<64><<<N_NODES / 4, 256, 0, stream>>>(h, 0, row_ptr, ssrc, agg);
  mfma_gemm_kernel<<<dim3(1, N_NODES / 128), 256, 0, stream>>>(
      h, 512, agg, 64, g1WtH, g1WtL, g1b, ytemp, 64, S(3), Q(3), N_NODES, 64, 64);
  act_stats_kernel<<<512, 256, 0, stream>>>(
      ytemp, S(3), Q(3), invN, g1g, g1be, S(4), Q(4), N_NODES * 64, 63);
  apply_bn_kernel<<<1024, 256, 0, stream>>>(
      ytemp, S(3), Q(3), invN, g1g, g1be, S(4), Q(4), bn1g, bn1be,
      h, hspH, 64, 6, 63, N_NODES * 64);

  // ---------------- GIN 2 ----------------
  gather_add_kernel<64><<<N_NODES / 4, 256, 0, stream>>>(h, 64, row_ptr, ssrc, agg);
  mfma_gemm_kernel<<<dim3(2, N_NODES / 128), 256, 0, stream>>>(
      h + 64, 512, agg, 64, g2WtH, g2WtL, g2b, ytemp, 128, S(5), Q(5), N_NODES, 64, 128);
  act_stats_kernel<<<512, 256, 0, stream>>>(
      ytemp, S(5), Q(5), invN, g2g, g2be, S(6), Q(6), N_NODES * 128, 127);
  apply_bn_kernel<<<1024, 256, 0, stream>>>(
      ytemp, S(5), Q(5), invN, g2g, g2be, S(6), Q(6), bn2g, bn2be,
      h, hspH, 128, 7, 127, N_NODES * 128);

  // ---------------- GIN 3 ----------------
  gather_add_kernel<128><<<N_NODES / 4, 256, 0, stream>>>(h, 128, row_ptr, ssrc, agg);
  mfma_gemm_kernel<<<dim3(4, N_NODES / 128), 256, 0, stream>>>(
      h + 128, 512, agg, 128, g3WtH, g3WtL, g3b, ytemp, 256, S(7), Q(7), N_NODES, 128, 256);
  act_stats_kernel<<<512, 256, 0, stream>>>(
      ytemp, S(7), Q(7), invN, g3g, g3be, S(8), Q(8), N_NODES * 256, 255);
  apply_bn_kernel<<<1024, 256, 0, stream>>>(
      ytemp, S(7), Q(7), invN, g3g, g3be, S(8), Q(8), bn3g, bn3be,
      h, hspH, 256, 8, 255, N_NODES * 256);

  // ---------------- lin (single-plane W) + pool ----------------
  mfma_gemm_ps_kernel<<<dim3(8, N_NODES / 128), 256, 0, stream>>>(
      hspH, linWtH, linb, hl, S(9), Q(9), 512, 1024);
  pool_kernel<<<dim3(64, 4), 256, 0, stream>>>(hl, S(9), Q(9), invN, ling, linbe, o_);

  // ---------------- head (K-split 4x) ----------------
  head_gemm_kernel<<<dim3(8, 64), 256, 0, stream>>>(
      o_, 2048, nullptr, nullptr, 0.f, nullptr, nullptr, h1W, h1b, yh1, 512, S(10), Q(10));
  head_gemm_kernel<<<dim3(4, 64), 256, 0, stream>>>(
      yh1, 512, S(10), Q(10), invB, h1g, h1be, h2W, h2b, yh2, 256, S(11), Q(11));
  head_gemm_kernel<<<dim3(1, 64), 256, 0, stream>>>(
      yh2, 256, S(11), Q(11), invB, h2g, h2be, outW, outb, logits, 40, nullptr, nullptr);
  lsm_kernel<<<64, 64, 0, stream>>>(logits, (float*)d_out);
#undef S
#undef Q
}